// Round 1
// baseline (1577.261 us; speedup 1.0000x reference)
//
#include <hip/hip_runtime.h>
#include <math.h>

#define B_ 4
#define N_ 2048
#define D_ 512
#define H_ 8
#define HD_ 64
#define MLP_H_ 2048
#define SCALE_ 0.125f
#define EPS_ 1e-5f

// ---------------- LayerNorm: one block per row, D=512, 256 threads ----------------
__global__ __launch_bounds__(256) void ln_kernel(
    const float* __restrict__ x, const float* __restrict__ g,
    const float* __restrict__ b, float* __restrict__ o)
{
  __shared__ float red[8];
  int row = blockIdx.x;
  int tid = threadIdx.x;
  const float* xr = x + (size_t)row * D_;
  float v0 = xr[tid], v1 = xr[tid + 256];
  float s = v0 + v1;
  #pragma unroll
  for (int off = 32; off > 0; off >>= 1) s += __shfl_xor(s, off, 64);
  if ((tid & 63) == 0) red[tid >> 6] = s;
  __syncthreads();
  float mean = (red[0] + red[1] + red[2] + red[3]) * (1.0f / D_);
  float d0 = v0 - mean, d1 = v1 - mean;
  float vs = d0 * d0 + d1 * d1;
  #pragma unroll
  for (int off = 32; off > 0; off >>= 1) vs += __shfl_xor(vs, off, 64);
  if ((tid & 63) == 0) red[4 + (tid >> 6)] = vs;
  __syncthreads();
  float var = (red[4] + red[5] + red[6] + red[7]) * (1.0f / D_);
  float r = rsqrtf(var + EPS_);
  float* orow = o + (size_t)row * D_;
  orow[tid]       = d0 * r * g[tid] + b[tid];
  orow[tid + 256] = d1 * r * g[tid + 256] + b[tid + 256];
}

// ---------------- Generic fp32 GEMM: C[M,N] = A[M,K] @ W[K,N] (+bias)(+act)(+res) ----
// 64x64 tile, 256 threads, 4x4 micro-tile, K-tile 16.
// act: 0 = none, 1 = exact GELU
#define GT 64
#define GKT 16
__global__ __launch_bounds__(256) void gemm_kernel(
    const float* __restrict__ A, const float* __restrict__ W,
    const float* __restrict__ bias, const float* __restrict__ res,
    float* __restrict__ C, int M, int K, int N, int act)
{
  __shared__ float As[GKT][GT];   // [k][m]
  __shared__ float Ws[GKT][GT];   // [k][n]
  int tid = threadIdx.x;
  int tx = tid & 15, ty = tid >> 4;
  int m0 = blockIdx.y * GT, n0 = blockIdx.x * GT;
  float acc[4][4] = {};
  for (int k0 = 0; k0 < K; k0 += GKT) {
    {
      int r  = tid >> 2;           // row within tile 0..63
      int kk = (tid & 3) << 2;     // 0,4,8,12
      const float4 a = *(const float4*)(A + (size_t)(m0 + r) * K + k0 + kk);
      As[kk+0][r] = a.x; As[kk+1][r] = a.y; As[kk+2][r] = a.z; As[kk+3][r] = a.w;
    }
    {
      int n  = tid & 63;
      int kb = tid >> 6;           // 0..3
      #pragma unroll
      for (int rr = 0; rr < 4; rr++)
        Ws[kb + (rr << 2)][n] = W[(size_t)(k0 + kb + (rr << 2)) * N + n0 + n];
    }
    __syncthreads();
    #pragma unroll
    for (int kk = 0; kk < GKT; kk++) {
      float4 a = *(const float4*)&As[kk][ty << 2];
      float4 b = *(const float4*)&Ws[kk][tx << 2];
      acc[0][0] += a.x*b.x; acc[0][1] += a.x*b.y; acc[0][2] += a.x*b.z; acc[0][3] += a.x*b.w;
      acc[1][0] += a.y*b.x; acc[1][1] += a.y*b.y; acc[1][2] += a.y*b.z; acc[1][3] += a.y*b.w;
      acc[2][0] += a.z*b.x; acc[2][1] += a.z*b.y; acc[2][2] += a.z*b.z; acc[2][3] += a.z*b.w;
      acc[3][0] += a.w*b.x; acc[3][1] += a.w*b.y; acc[3][2] += a.w*b.z; acc[3][3] += a.w*b.w;
    }
    __syncthreads();
  }
  int col = n0 + (tx << 2);
  float4 bb = make_float4(0.f, 0.f, 0.f, 0.f);
  if (bias) bb = *(const float4*)(bias + col);
  #pragma unroll
  for (int i = 0; i < 4; i++) {
    int row = m0 + (ty << 2) + i;
    float4 c;
    c.x = acc[i][0] + bb.x; c.y = acc[i][1] + bb.y;
    c.z = acc[i][2] + bb.z; c.w = acc[i][3] + bb.w;
    if (act == 1) {
      c.x = 0.5f * c.x * (1.f + erff(c.x * 0.70710678118f));
      c.y = 0.5f * c.y * (1.f + erff(c.y * 0.70710678118f));
      c.z = 0.5f * c.z * (1.f + erff(c.z * 0.70710678118f));
      c.w = 0.5f * c.w * (1.f + erff(c.w * 0.70710678118f));
    }
    if (res) {
      float4 rr = *(const float4*)(res + (size_t)row * N + col);
      c.x += rr.x; c.y += rr.y; c.z += rr.z; c.w += rr.w;
    }
    *(float4*)(C + (size_t)row * N + col) = c;
  }
}

// ---------------- Flash attention with elevation bias ----------------
// qkv layout: [B, N, 3, H, HD] flat; out: [B, N, D] with channel = h*HD + d
// Block: (b, h, 64-query tile). 256 threads. TK=64 key tiles, online softmax.
// Thread mapping: qg = tid/16 owns rows qi..qi+3 (qi = 4*qg); kg = tid%16.
// S phase: thread computes s[4 rows][kj = kg + 16j]; PV: d-slice = 4*kg.
#define TQ 64
#define TK 64
#define QS_STR 68   // pad: conflict-free strided row reads
#define PS_STR 66

__global__ __launch_bounds__(256) void attn_kernel(
    const float* __restrict__ qkv, const float* __restrict__ elev,
    const float* __restrict__ alpha_p, float* __restrict__ out)
{
  __shared__ float Qs[TQ][QS_STR];
  __shared__ float Ks[TK][QS_STR];
  __shared__ float Vs[TK][QS_STR];
  __shared__ float Ps[TQ][PS_STR];
  int b = blockIdx.z, h = blockIdx.y;
  int q0 = blockIdx.x * TQ;
  int tid = threadIdx.x;
  int qg = tid >> 4;
  int kg = tid & 15;
  int qi = qg << 2;
  float alpha = alpha_p[0];

  for (int i = tid; i < TQ * HD_ / 4; i += 256) {
    int r  = i >> 4;
    int dd = (i & 15) << 2;
    const float4 v = *(const float4*)&qkv[((size_t)b * N_ + q0 + r) * (3 * D_) + h * HD_ + dd];
    *(float4*)&Qs[r][dd] = v;
  }
  float eq[4];
  #pragma unroll
  for (int i = 0; i < 4; i++) eq[i] = elev[b * N_ + q0 + qi + i];
  float mrow[4], lrow[4];
  #pragma unroll
  for (int i = 0; i < 4; i++) { mrow[i] = -3.0e38f; lrow[i] = 0.f; }
  float O[4][4] = {};
  __syncthreads();

  for (int k0 = 0; k0 < N_; k0 += TK) {
    for (int i = tid; i < TK * HD_ / 4; i += 256) {
      int r  = i >> 4;
      int dd = (i & 15) << 2;
      size_t base = ((size_t)b * N_ + k0 + r) * (3 * D_) + h * HD_ + dd;
      *(float4*)&Ks[r][dd] = *(const float4*)&qkv[base + D_];
      *(float4*)&Vs[r][dd] = *(const float4*)&qkv[base + 2 * D_];
    }
    __syncthreads();

    // ---- S = Q K^T (4 rows x 4 strided cols per thread) ----
    float s[4][4] = {};
    #pragma unroll
    for (int dk = 0; dk < HD_; dk += 4) {
      float4 a0 = *(const float4*)&Qs[qi + 0][dk];
      float4 a1 = *(const float4*)&Qs[qi + 1][dk];
      float4 a2 = *(const float4*)&Qs[qi + 2][dk];
      float4 a3 = *(const float4*)&Qs[qi + 3][dk];
      float4 b0 = *(const float4*)&Ks[kg][dk];
      float4 b1 = *(const float4*)&Ks[kg + 16][dk];
      float4 b2 = *(const float4*)&Ks[kg + 32][dk];
      float4 b3 = *(const float4*)&Ks[kg + 48][dk];
      s[0][0] += a0.x*b0.x + a0.y*b0.y + a0.z*b0.z + a0.w*b0.w;
      s[0][1] += a0.x*b1.x + a0.y*b1.y + a0.z*b1.z + a0.w*b1.w;
      s[0][2] += a0.x*b2.x + a0.y*b2.y + a0.z*b2.z + a0.w*b2.w;
      s[0][3] += a0.x*b3.x + a0.y*b3.y + a0.z*b3.z + a0.w*b3.w;
      s[1][0] += a1.x*b0.x + a1.y*b0.y + a1.z*b0.z + a1.w*b0.w;
      s[1][1] += a1.x*b1.x + a1.y*b1.y + a1.z*b1.z + a1.w*b1.w;
      s[1][2] += a1.x*b2.x + a1.y*b2.y + a1.z*b2.z + a1.w*b2.w;
      s[1][3] += a1.x*b3.x + a1.y*b3.y + a1.z*b3.z + a1.w*b3.w;
      s[2][0] += a2.x*b0.x + a2.y*b0.y + a2.z*b0.z + a2.w*b0.w;
      s[2][1] += a2.x*b1.x + a2.y*b1.y + a2.z*b1.z + a2.w*b1.w;
      s[2][2] += a2.x*b2.x + a2.y*b2.y + a2.z*b2.z + a2.w*b2.w;
      s[2][3] += a2.x*b3.x + a2.y*b3.y + a2.z*b3.z + a2.w*b3.w;
      s[3][0] += a3.x*b0.x + a3.y*b0.y + a3.z*b0.z + a3.w*b0.w;
      s[3][1] += a3.x*b1.x + a3.y*b1.y + a3.z*b1.z + a3.w*b1.w;
      s[3][2] += a3.x*b2.x + a3.y*b2.y + a3.z*b2.z + a3.w*b2.w;
      s[3][3] += a3.x*b3.x + a3.y*b3.y + a3.z*b3.z + a3.w*b3.w;
    }

    // ---- elevation bias + online softmax (per 16-lane row group) ----
    float ekv[4];
    #pragma unroll
    for (int j = 0; j < 4; j++) ekv[j] = elev[b * N_ + k0 + kg + 16 * j];
    #pragma unroll
    for (int i = 0; i < 4; i++) {
      float rmax = -3.0e38f;
      #pragma unroll
      for (int j = 0; j < 4; j++) {
        float ed = (ekv[j] - eq[i]) * 0.001f;
        float bias = fminf(fmaxf(-alpha * fmaxf(ed, 0.f), -10.f), 0.f);
        float sv = s[i][j] * SCALE_ + bias;
        s[i][j] = sv;
        rmax = fmaxf(rmax, sv);
      }
      #pragma unroll
      for (int off = 1; off < 16; off <<= 1) rmax = fmaxf(rmax, __shfl_xor(rmax, off, 64));
      float mnew = fmaxf(mrow[i], rmax);
      float corr = __expf(mrow[i] - mnew);
      float psum = 0.f;
      #pragma unroll
      for (int j = 0; j < 4; j++) {
        float p = __expf(s[i][j] - mnew);
        s[i][j] = p;
        psum += p;
      }
      #pragma unroll
      for (int off = 1; off < 16; off <<= 1) psum += __shfl_xor(psum, off, 64);
      mrow[i] = mnew;
      lrow[i] = lrow[i] * corr + psum;
      #pragma unroll
      for (int j = 0; j < 4; j++) Ps[qi + i][kg + 16 * j] = s[i][j];
      #pragma unroll
      for (int d = 0; d < 4; d++) O[i][d] *= corr;
    }
    __syncthreads();  // Ps visible across waves (belt & braces; group is wave-local)

    // ---- O += P @ V  (thread: rows qi..qi+3, d-slice 4*kg) ----
    int d0 = kg << 2;
    #pragma unroll
    for (int kk = 0; kk < TK; kk++) {
      float4 v = *(const float4*)&Vs[kk][d0];
      #pragma unroll
      for (int i = 0; i < 4; i++) {
        float p = Ps[qi + i][kk];
        O[i][0] += p * v.x; O[i][1] += p * v.y; O[i][2] += p * v.z; O[i][3] += p * v.w;
      }
    }
    __syncthreads();
  }

  #pragma unroll
  for (int i = 0; i < 4; i++) {
    float inv = 1.0f / lrow[i];
    float4 c = make_float4(O[i][0] * inv, O[i][1] * inv, O[i][2] * inv, O[i][3] * inv);
    *(float4*)&out[((size_t)b * N_ + q0 + qi + i) * D_ + h * HD_ + (kg << 2)] = c;
  }
}

extern "C" void kernel_launch(void* const* d_in, const int* in_sizes, int n_in,
                              void* d_out, int out_size, void* d_ws, size_t ws_size,
                              hipStream_t stream) {
  const float* x      = (const float*)d_in[0];
  const float* elev   = (const float*)d_in[1];
  const float* ln1_g  = (const float*)d_in[2];
  const float* ln1_b  = (const float*)d_in[3];
  const float* qkv_w  = (const float*)d_in[4];
  const float* alpha  = (const float*)d_in[5];
  const float* proj_w = (const float*)d_in[6];
  const float* proj_b = (const float*)d_in[7];
  const float* ln2_g  = (const float*)d_in[8];
  const float* ln2_b  = (const float*)d_in[9];
  const float* fc1_w  = (const float*)d_in[10];
  const float* fc1_b  = (const float*)d_in[11];
  const float* fc2_w  = (const float*)d_in[12];
  const float* fc2_b  = (const float*)d_in[13];
  float* out = (float*)d_out;

  const size_t HB = (size_t)B_ * N_ * D_;   // 4,194,304 floats
  float* ws     = (float*)d_ws;
  float* buf0   = ws;            // h (LN1 out) -> later attn_out -> later h2
  float* qkvb   = ws + HB;       // [HB, 4HB)
  float* xres   = ws + 4 * HB;   // [4HB, 5HB)
  float* mlp    = ws + 5 * HB;   // [5HB, 9HB)

  const int rows = B_ * N_;      // 8192

  // LN1
  ln_kernel<<<rows, 256, 0, stream>>>(x, ln1_g, ln1_b, buf0);
  // QKV = h @ qkv_w  [8192 x 1536]
  gemm_kernel<<<dim3((3 * D_) / GT, rows / GT), 256, 0, stream>>>(
      buf0, qkv_w, nullptr, nullptr, qkvb, rows, D_, 3 * D_, 0);
  // attention -> buf0 (overwrites h, which is now dead)
  attn_kernel<<<dim3(N_ / TQ, H_, B_), 256, 0, stream>>>(qkvb, elev, alpha, buf0);
  // xres = x + attn_out @ proj_w + proj_b
  gemm_kernel<<<dim3(D_ / GT, rows / GT), 256, 0, stream>>>(
      buf0, proj_w, proj_b, x, xres, rows, D_, D_, 0);
  // LN2 -> buf0
  ln_kernel<<<rows, 256, 0, stream>>>(xres, ln2_g, ln2_b, buf0);
  // mlp = gelu(h2 @ fc1_w + fc1_b)
  gemm_kernel<<<dim3(MLP_H_ / GT, rows / GT), 256, 0, stream>>>(
      buf0, fc1_w, fc1_b, nullptr, mlp, rows, D_, MLP_H_, 1);
  // out = xres + mlp @ fc2_w + fc2_b
  gemm_kernel<<<dim3(D_ / GT, rows / GT), 256, 0, stream>>>(
      mlp, fc2_w, fc2_b, xres, out, rows, MLP_H_, D_, 0);
}

// Round 2
// 1078.239 us; speedup vs baseline: 1.4628x; 1.4628x over previous
//
#include <hip/hip_runtime.h>
#include <math.h>

typedef unsigned short u16;
typedef unsigned int u32;

#define B_ 4
#define N_ 2048
#define D_ 512
#define H_ 8
#define HD_ 64
#define MLP_H_ 2048
#define SCALE_ 0.125f
#define EPS_ 1e-5f

// ---------- bf16 split helpers ----------
__device__ __forceinline__ u16 bf16_rne(float x) {
  u32 u = __float_as_uint(x);
  u32 r = (u + 0x7FFFu + ((u >> 16) & 1u)) >> 16;
  return (u16)r;
}
__device__ __forceinline__ void bf16_split(float x, u16& h, u16& l) {
  h = bf16_rne(x);
  float hf = __uint_as_float(((u32)h) << 16);
  l = bf16_rne(x - hf);
}

// ---------------- LayerNorm (unchanged) ----------------
__global__ __launch_bounds__(256) void ln_kernel(
    const float* __restrict__ x, const float* __restrict__ g,
    const float* __restrict__ b, float* __restrict__ o)
{
  __shared__ float red[8];
  int row = blockIdx.x;
  int tid = threadIdx.x;
  const float* xr = x + (size_t)row * D_;
  float v0 = xr[tid], v1 = xr[tid + 256];
  float s = v0 + v1;
  #pragma unroll
  for (int off = 32; off > 0; off >>= 1) s += __shfl_xor(s, off, 64);
  if ((tid & 63) == 0) red[tid >> 6] = s;
  __syncthreads();
  float mean = (red[0] + red[1] + red[2] + red[3]) * (1.0f / D_);
  float d0 = v0 - mean, d1 = v1 - mean;
  float vs = d0 * d0 + d1 * d1;
  #pragma unroll
  for (int off = 32; off > 0; off >>= 1) vs += __shfl_xor(vs, off, 64);
  if ((tid & 63) == 0) red[4 + (tid >> 6)] = vs;
  __syncthreads();
  float var = (red[4] + red[5] + red[6] + red[7]) * (1.0f / D_);
  float r = rsqrtf(var + EPS_);
  float* orow = o + (size_t)row * D_;
  orow[tid]       = d0 * r * g[tid] + b[tid];
  orow[tid + 256] = d1 * r * g[tid + 256] + b[tid + 256];
}

// ---------------- Weight split+transpose: W[K,N] f32 -> Thi/Tlo[N,K] bf16 ----------------
__global__ __launch_bounds__(256) void wsplit_kernel(
    const float* __restrict__ W, u16* __restrict__ Thi, u16* __restrict__ Tlo,
    int K, int N)
{
  __shared__ float tile[64][65];
  int n0 = blockIdx.x * 64, k0 = blockIdx.y * 64;
  int c = threadIdx.x & 63, r4 = threadIdx.x >> 6;
  #pragma unroll
  for (int i = 0; i < 16; i++) {
    int r = r4 + i * 4;
    tile[r][c] = W[(size_t)(k0 + r) * N + n0 + c];
  }
  __syncthreads();
  #pragma unroll
  for (int i = 0; i < 16; i++) {
    int rn = r4 + i * 4;
    float v = tile[c][rn];
    u16 h, l; bf16_split(v, h, l);
    size_t o = (size_t)(n0 + rn) * K + k0 + c;
    Thi[o] = h; Tlo[o] = l;
  }
}

// ---------------- split-bf16 MFMA GEMM ----------------
// C[M,N] = A[M,K] @ W[K,N] (+bias)(+gelu)(+res), W pre-split transposed [N,K].
// A either f32 (on-the-fly split) or pre-split bf16 hi/lo [M,K].
// 128x128 tile, 256 threads (4 waves, 2x2), 16x16x32 bf16 MFMA, BK=32.
#define BM 128
#define BN 128
#define BK 32

typedef __attribute__((ext_vector_type(8))) short bfrag;
typedef __attribute__((ext_vector_type(4))) float ffrag;

#define LDS_AS(p) ((__attribute__((address_space(3))) void*)(p))
#define GLB_AS(p) ((const __attribute__((address_space(1))) void*)(p))

// stage a 128x32 u16 tile (8KB, rows k-contiguous) from src[R,ld] at (r0,k0)
__device__ __forceinline__ void stage_u16_tile(const u16* __restrict__ src, int ld,
                                               int r0, int k0, u16* lds,
                                               int lane, int wave)
{
  #pragma unroll
  for (int i = 0; i < 2; i++) {
    int seg = wave * 2048 + i * 1024;   // bytes within tile
    int f = seg + lane * 16;
    int row = f >> 6;                   // 64 B per row
    int ko = (f & 63) >> 1;             // ushort offset within row
    const u16* g = src + (size_t)(r0 + row) * ld + k0 + ko;
    __builtin_amdgcn_global_load_lds(GLB_AS(g), LDS_AS((char*)lds + seg), 16, 0, 0);
  }
}

__global__ __launch_bounds__(256) void gemm_split_kernel(
    const float* __restrict__ Af,
    const u16* __restrict__ Ahi, const u16* __restrict__ Alo,
    const u16* __restrict__ Whi, const u16* __restrict__ Wlo,
    const float* __restrict__ bias, const float* __restrict__ res,
    float* __restrict__ Cf, u16* __restrict__ Ohi, u16* __restrict__ Olo,
    int M, int K, int N, int act)
{
  __shared__ __align__(16) u16 As_hi[BM * BK];
  __shared__ __align__(16) u16 As_lo[BM * BK];
  __shared__ __align__(16) u16 Bs_hi[BN * BK];
  __shared__ __align__(16) u16 Bs_lo[BN * BK];

  int tid = threadIdx.x;
  int lane = tid & 63, wave = tid >> 6;
  int wm = wave >> 1, wn = wave & 1;
  int ln = lane & 15, quad = lane >> 4;
  int m0 = blockIdx.y * BM, n0 = blockIdx.x * BN;

  ffrag acc[4][4] = {};

  for (int k0 = 0; k0 < K; k0 += BK) {
    // ---- stage A ----
    if (Af) {
      int r = tid >> 1, h = tid & 1;
      const float* g = Af + (size_t)(m0 + r) * K + k0 + h * 16;
      float xs[16];
      *(float4*)(xs + 0)  = *(const float4*)(g + 0);
      *(float4*)(xs + 4)  = *(const float4*)(g + 4);
      *(float4*)(xs + 8)  = *(const float4*)(g + 8);
      *(float4*)(xs + 12) = *(const float4*)(g + 12);
      u32 ph[8], pl[8];
      #pragma unroll
      for (int j = 0; j < 8; j++) {
        u16 h0, l0, h1, l1;
        bf16_split(xs[2 * j], h0, l0);
        bf16_split(xs[2 * j + 1], h1, l1);
        ph[j] = (u32)h0 | ((u32)h1 << 16);
        pl[j] = (u32)l0 | ((u32)l1 << 16);
      }
      u16* da = As_hi + r * 32 + h * 16;
      *(uint4*)(da)     = make_uint4(ph[0], ph[1], ph[2], ph[3]);
      *(uint4*)(da + 8) = make_uint4(ph[4], ph[5], ph[6], ph[7]);
      u16* dl = As_lo + r * 32 + h * 16;
      *(uint4*)(dl)     = make_uint4(pl[0], pl[1], pl[2], pl[3]);
      *(uint4*)(dl + 8) = make_uint4(pl[4], pl[5], pl[6], pl[7]);
    } else {
      stage_u16_tile(Ahi, K, m0, k0, As_hi, lane, wave);
      stage_u16_tile(Alo, K, m0, k0, As_lo, lane, wave);
    }
    // ---- stage W (pre-split, [N,K]) ----
    stage_u16_tile(Whi, K, n0, k0, Bs_hi, lane, wave);
    stage_u16_tile(Wlo, K, n0, k0, Bs_lo, lane, wave);
    __syncthreads();

    // ---- fragments + MFMA ----
    bfrag ah[4], al[4], bh[4], bl[4];
    #pragma unroll
    for (int t = 0; t < 4; t++) {
      int ao = (wm * 64 + t * 16 + ln) * 32 + quad * 8;
      int bo = (wn * 64 + t * 16 + ln) * 32 + quad * 8;
      ah[t] = *(const bfrag*)(As_hi + ao);
      al[t] = *(const bfrag*)(As_lo + ao);
      bh[t] = *(const bfrag*)(Bs_hi + bo);
      bl[t] = *(const bfrag*)(Bs_lo + bo);
    }
    #pragma unroll
    for (int ti = 0; ti < 4; ti++) {
      #pragma unroll
      for (int tj = 0; tj < 4; tj++) {
        acc[ti][tj] = __builtin_amdgcn_mfma_f32_16x16x32_bf16(ah[ti], bh[tj], acc[ti][tj], 0, 0, 0);
        acc[ti][tj] = __builtin_amdgcn_mfma_f32_16x16x32_bf16(ah[ti], bl[tj], acc[ti][tj], 0, 0, 0);
        acc[ti][tj] = __builtin_amdgcn_mfma_f32_16x16x32_bf16(al[ti], bh[tj], acc[ti][tj], 0, 0, 0);
      }
    }
    __syncthreads();
  }

  // ---- epilogue ----
  #pragma unroll
  for (int tj = 0; tj < 4; tj++) {
    int col = n0 + wn * 64 + tj * 16 + ln;
    float bv = bias ? bias[col] : 0.f;
    #pragma unroll
    for (int ti = 0; ti < 4; ti++) {
      int rw = m0 + wm * 64 + ti * 16 + quad * 4;
      #pragma unroll
      for (int r = 0; r < 4; r++) {
        float y = acc[ti][tj][r] + bv;
        if (act) y = 0.5f * y * (1.f + erff(y * 0.70710678118654752f));
        if (res) y += res[(size_t)(rw + r) * N + col];
        if (Cf) Cf[(size_t)(rw + r) * N + col] = y;
        if (Ohi) {
          u16 hh, ll; bf16_split(y, hh, ll);
          Ohi[(size_t)(rw + r) * N + col] = hh;
          Olo[(size_t)(rw + r) * N + col] = ll;
        }
      }
    }
  }
}

// ---------------- Flash attention with elevation bias (unchanged, fp32) ----------------
#define TQ 64
#define TK 64
#define QS_STR 68
#define PS_STR 66

__global__ __launch_bounds__(256) void attn_kernel(
    const float* __restrict__ qkv, const float* __restrict__ elev,
    const float* __restrict__ alpha_p, float* __restrict__ out)
{
  __shared__ float Qs[TQ][QS_STR];
  __shared__ float Ks[TK][QS_STR];
  __shared__ float Vs[TK][QS_STR];
  __shared__ float Ps[TQ][PS_STR];
  int b = blockIdx.z, h = blockIdx.y;
  int q0 = blockIdx.x * TQ;
  int tid = threadIdx.x;
  int qg = tid >> 4;
  int kg = tid & 15;
  int qi = qg << 2;
  float alpha = alpha_p[0];

  for (int i = tid; i < TQ * HD_ / 4; i += 256) {
    int r  = i >> 4;
    int dd = (i & 15) << 2;
    const float4 v = *(const float4*)&qkv[((size_t)b * N_ + q0 + r) * (3 * D_) + h * HD_ + dd];
    *(float4*)&Qs[r][dd] = v;
  }
  float eq[4];
  #pragma unroll
  for (int i = 0; i < 4; i++) eq[i] = elev[b * N_ + q0 + qi + i];
  float mrow[4], lrow[4];
  #pragma unroll
  for (int i = 0; i < 4; i++) { mrow[i] = -3.0e38f; lrow[i] = 0.f; }
  float O[4][4] = {};
  __syncthreads();

  for (int k0 = 0; k0 < N_; k0 += TK) {
    for (int i = tid; i < TK * HD_ / 4; i += 256) {
      int r  = i >> 4;
      int dd = (i & 15) << 2;
      size_t base = ((size_t)b * N_ + k0 + r) * (3 * D_) + h * HD_ + dd;
      *(float4*)&Ks[r][dd] = *(const float4*)&qkv[base + D_];
      *(float4*)&Vs[r][dd] = *(const float4*)&qkv[base + 2 * D_];
    }
    __syncthreads();

    float s[4][4] = {};
    #pragma unroll
    for (int dk = 0; dk < HD_; dk += 4) {
      float4 a0 = *(const float4*)&Qs[qi + 0][dk];
      float4 a1 = *(const float4*)&Qs[qi + 1][dk];
      float4 a2 = *(const float4*)&Qs[qi + 2][dk];
      float4 a3 = *(const float4*)&Qs[qi + 3][dk];
      float4 b0 = *(const float4*)&Ks[kg][dk];
      float4 b1 = *(const float4*)&Ks[kg + 16][dk];
      float4 b2 = *(const float4*)&Ks[kg + 32][dk];
      float4 b3 = *(const float4*)&Ks[kg + 48][dk];
      s[0][0] += a0.x*b0.x + a0.y*b0.y + a0.z*b0.z + a0.w*b0.w;
      s[0][1] += a0.x*b1.x + a0.y*b1.y + a0.z*b1.z + a0.w*b1.w;
      s[0][2] += a0.x*b2.x + a0.y*b2.y + a0.z*b2.z + a0.w*b2.w;
      s[0][3] += a0.x*b3.x + a0.y*b3.y + a0.z*b3.z + a0.w*b3.w;
      s[1][0] += a1.x*b0.x + a1.y*b0.y + a1.z*b0.z + a1.w*b0.w;
      s[1][1] += a1.x*b1.x + a1.y*b1.y + a1.z*b1.z + a1.w*b1.w;
      s[1][2] += a1.x*b2.x + a1.y*b2.y + a1.z*b2.z + a1.w*b2.w;
      s[1][3] += a1.x*b3.x + a1.y*b3.y + a1.z*b3.z + a1.w*b3.w;
      s[2][0] += a2.x*b0.x + a2.y*b0.y + a2.z*b0.z + a2.w*b0.w;
      s[2][1] += a2.x*b1.x + a2.y*b1.y + a2.z*b1.z + a2.w*b1.w;
      s[2][2] += a2.x*b2.x + a2.y*b2.y + a2.z*b2.z + a2.w*b2.w;
      s[2][3] += a2.x*b3.x + a2.y*b3.y + a2.z*b3.z + a2.w*b3.w;
      s[3][0] += a3.x*b0.x + a3.y*b0.y + a3.z*b0.z + a3.w*b0.w;
      s[3][1] += a3.x*b1.x + a3.y*b1.y + a3.z*b1.z + a3.w*b1.w;
      s[3][2] += a3.x*b2.x + a3.y*b2.y + a3.z*b2.z + a3.w*b2.w;
      s[3][3] += a3.x*b3.x + a3.y*b3.y + a3.z*b3.z + a3.w*b3.w;
    }

    float ekv[4];
    #pragma unroll
    for (int j = 0; j < 4; j++) ekv[j] = elev[b * N_ + k0 + kg + 16 * j];
    #pragma unroll
    for (int i = 0; i < 4; i++) {
      float rmax = -3.0e38f;
      #pragma unroll
      for (int j = 0; j < 4; j++) {
        float ed = (ekv[j] - eq[i]) * 0.001f;
        float bias = fminf(fmaxf(-alpha * fmaxf(ed, 0.f), -10.f), 0.f);
        float sv = s[i][j] * SCALE_ + bias;
        s[i][j] = sv;
        rmax = fmaxf(rmax, sv);
      }
      #pragma unroll
      for (int off = 1; off < 16; off <<= 1) rmax = fmaxf(rmax, __shfl_xor(rmax, off, 64));
      float mnew = fmaxf(mrow[i], rmax);
      float corr = __expf(mrow[i] - mnew);
      float psum = 0.f;
      #pragma unroll
      for (int j = 0; j < 4; j++) {
        float p = __expf(s[i][j] - mnew);
        s[i][j] = p;
        psum += p;
      }
      #pragma unroll
      for (int off = 1; off < 16; off <<= 1) psum += __shfl_xor(psum, off, 64);
      mrow[i] = mnew;
      lrow[i] = lrow[i] * corr + psum;
      #pragma unroll
      for (int j = 0; j < 4; j++) Ps[qi + i][kg + 16 * j] = s[i][j];
      #pragma unroll
      for (int d = 0; d < 4; d++) O[i][d] *= corr;
    }
    __syncthreads();

    int d0 = kg << 2;
    #pragma unroll
    for (int kk = 0; kk < TK; kk++) {
      float4 v = *(const float4*)&Vs[kk][d0];
      #pragma unroll
      for (int i = 0; i < 4; i++) {
        float p = Ps[qi + i][kk];
        O[i][0] += p * v.x; O[i][1] += p * v.y; O[i][2] += p * v.z; O[i][3] += p * v.w;
      }
    }
    __syncthreads();
  }

  #pragma unroll
  for (int i = 0; i < 4; i++) {
    float inv = 1.0f / lrow[i];
    float4 c = make_float4(O[i][0] * inv, O[i][1] * inv, O[i][2] * inv, O[i][3] * inv);
    *(float4*)&out[((size_t)b * N_ + q0 + qi + i) * D_ + h * HD_ + (kg << 2)] = c;
  }
}

extern "C" void kernel_launch(void* const* d_in, const int* in_sizes, int n_in,
                              void* d_out, int out_size, void* d_ws, size_t ws_size,
                              hipStream_t stream) {
  const float* x      = (const float*)d_in[0];
  const float* elev   = (const float*)d_in[1];
  const float* ln1_g  = (const float*)d_in[2];
  const float* ln1_b  = (const float*)d_in[3];
  const float* qkv_w  = (const float*)d_in[4];
  const float* alpha  = (const float*)d_in[5];
  const float* proj_w = (const float*)d_in[6];
  const float* proj_b = (const float*)d_in[7];
  const float* ln2_g  = (const float*)d_in[8];
  const float* ln2_b  = (const float*)d_in[9];
  const float* fc1_w  = (const float*)d_in[10];
  const float* fc1_b  = (const float*)d_in[11];
  const float* fc2_w  = (const float*)d_in[12];
  const float* fc2_b  = (const float*)d_in[13];
  float* out = (float*)d_out;

  const size_t HBf = (size_t)B_ * N_ * D_;        // 4,194,304
  const size_t MLPE = (size_t)B_ * N_ * MLP_H_;   // 16,777,216

  char* p = (char*)d_ws;
  float* buf0 = (float*)p;                 p += HBf * 4;          // 16.8 MB
  char* pq = p;                                                   // overlap region
  float* qkv    = (float*)pq;                                     // 50.3 MB (dead after attn)
  u16*   mlp_hi = (u16*)pq;                                       // 33.6 MB
  u16*   mlp_lo = (u16*)(pq + MLPE * 2);                          // 33.6 MB
  p = pq + MLPE * 4;                                              // 67.1 MB region
  float* xres = (float*)p;                 p += HBf * 4;          // 16.8 MB
  u16* qw_hi = (u16*)p;  p += (size_t)D_ * 3 * D_ * 2;
  u16* qw_lo = (u16*)p;  p += (size_t)D_ * 3 * D_ * 2;
  u16* pw_hi = (u16*)p;  p += (size_t)D_ * D_ * 2;
  u16* pw_lo = (u16*)p;  p += (size_t)D_ * D_ * 2;
  u16* f1_hi = (u16*)p;  p += (size_t)D_ * MLP_H_ * 2;
  u16* f1_lo = (u16*)p;  p += (size_t)D_ * MLP_H_ * 2;
  u16* f2_hi = (u16*)p;  p += (size_t)MLP_H_ * D_ * 2;
  u16* f2_lo = (u16*)p;  p += (size_t)MLP_H_ * D_ * 2;

  const int rows = B_ * N_;   // 8192

  // weight split+transpose (per call; weights restored by harness each launch)
  wsplit_kernel<<<dim3(3 * D_ / 64, D_ / 64), 256, 0, stream>>>(qkv_w, qw_hi, qw_lo, D_, 3 * D_);
  wsplit_kernel<<<dim3(D_ / 64, D_ / 64), 256, 0, stream>>>(proj_w, pw_hi, pw_lo, D_, D_);
  wsplit_kernel<<<dim3(MLP_H_ / 64, D_ / 64), 256, 0, stream>>>(fc1_w, f1_hi, f1_lo, D_, MLP_H_);
  wsplit_kernel<<<dim3(D_ / 64, MLP_H_ / 64), 256, 0, stream>>>(fc2_w, f2_hi, f2_lo, MLP_H_, D_);

  // LN1
  ln_kernel<<<rows, 256, 0, stream>>>(x, ln1_g, ln1_b, buf0);
  // qkv = h @ qkv_w
  gemm_split_kernel<<<dim3(3 * D_ / BN, rows / BM), 256, 0, stream>>>(
      buf0, nullptr, nullptr, qw_hi, qw_lo, nullptr, nullptr,
      qkv, nullptr, nullptr, rows, D_, 3 * D_, 0);
  // attention -> buf0
  attn_kernel<<<dim3(N_ / TQ, H_, B_), 256, 0, stream>>>(qkv, elev, alpha, buf0);
  // xres = x + attn @ proj_w + proj_b
  gemm_split_kernel<<<dim3(D_ / BN, rows / BM), 256, 0, stream>>>(
      buf0, nullptr, nullptr, pw_hi, pw_lo, proj_b, x,
      xres, nullptr, nullptr, rows, D_, D_, 0);
  // LN2 -> buf0
  ln_kernel<<<rows, 256, 0, stream>>>(xres, ln2_g, ln2_b, buf0);
  // mlp_hi/lo = split(gelu(h2 @ fc1_w + fc1_b))
  gemm_split_kernel<<<dim3(MLP_H_ / BN, rows / BM), 256, 0, stream>>>(
      buf0, nullptr, nullptr, f1_hi, f1_lo, fc1_b, nullptr,
      nullptr, mlp_hi, mlp_lo, rows, D_, MLP_H_, 1);
  // out = xres + mlp @ fc2_w + fc2_b
  gemm_split_kernel<<<dim3(D_ / BN, rows / BM), 256, 0, stream>>>(
      nullptr, mlp_hi, mlp_lo, f2_hi, f2_lo, fc2_b, xres,
      out, nullptr, nullptr, rows, MLP_H_, D_, 0);
}

// Round 3
// 646.605 us; speedup vs baseline: 2.4393x; 1.6675x over previous
//
#include <hip/hip_runtime.h>
#include <math.h>

typedef unsigned short u16;
typedef unsigned int u32;

#define B_ 4
#define N_ 2048
#define D_ 512
#define H_ 8
#define HD_ 64
#define MLP_H_ 2048
#define SCALE_ 0.125f
#define EPS_ 1e-5f

// ---------- bf16 split helpers ----------
__device__ __forceinline__ u16 bf16_rne(float x) {
  u32 u = __float_as_uint(x);
  u32 r = (u + 0x7FFFu + ((u >> 16) & 1u)) >> 16;
  return (u16)r;
}
__device__ __forceinline__ void bf16_split(float x, u16& h, u16& l) {
  h = bf16_rne(x);
  float hf = __uint_as_float(((u32)h) << 16);
  l = bf16_rne(x - hf);
}

typedef __attribute__((ext_vector_type(8))) short bfrag;
typedef __attribute__((ext_vector_type(4))) float ffrag;

#define LDS_AS(p) ((__attribute__((address_space(3))) void*)(p))
#define GLB_AS(p) ((const __attribute__((address_space(1))) void*)(p))

// ---------------- LayerNorm ----------------
__global__ __launch_bounds__(256) void ln_kernel(
    const float* __restrict__ x, const float* __restrict__ g,
    const float* __restrict__ b, float* __restrict__ o)
{
  __shared__ float red[8];
  int row = blockIdx.x;
  int tid = threadIdx.x;
  const float* xr = x + (size_t)row * D_;
  float v0 = xr[tid], v1 = xr[tid + 256];
  float s = v0 + v1;
  #pragma unroll
  for (int off = 32; off > 0; off >>= 1) s += __shfl_xor(s, off, 64);
  if ((tid & 63) == 0) red[tid >> 6] = s;
  __syncthreads();
  float mean = (red[0] + red[1] + red[2] + red[3]) * (1.0f / D_);
  float d0 = v0 - mean, d1 = v1 - mean;
  float vs = d0 * d0 + d1 * d1;
  #pragma unroll
  for (int off = 32; off > 0; off >>= 1) vs += __shfl_xor(vs, off, 64);
  if ((tid & 63) == 0) red[4 + (tid >> 6)] = vs;
  __syncthreads();
  float var = (red[4] + red[5] + red[6] + red[7]) * (1.0f / D_);
  float r = rsqrtf(var + EPS_);
  float* orow = o + (size_t)row * D_;
  orow[tid]       = d0 * r * g[tid] + b[tid];
  orow[tid + 256] = d1 * r * g[tid + 256] + b[tid + 256];
}

// ---------------- Weight split+transpose: W[K,N] f32 -> Thi/Tlo[N,K] bf16 ----------------
__global__ __launch_bounds__(256) void wsplit_kernel(
    const float* __restrict__ W, u16* __restrict__ Thi, u16* __restrict__ Tlo,
    int K, int N)
{
  __shared__ float tile[64][65];
  int n0 = blockIdx.x * 64, k0 = blockIdx.y * 64;
  int c = threadIdx.x & 63, r4 = threadIdx.x >> 6;
  #pragma unroll
  for (int i = 0; i < 16; i++) {
    int r = r4 + i * 4;
    tile[r][c] = W[(size_t)(k0 + r) * N + n0 + c];
  }
  __syncthreads();
  #pragma unroll
  for (int i = 0; i < 16; i++) {
    int rn = r4 + i * 4;
    float v = tile[c][rn];
    u16 h, l; bf16_split(v, h, l);
    size_t o = (size_t)(n0 + rn) * K + k0 + c;
    Thi[o] = h; Tlo[o] = l;
  }
}

// ---------------- split-bf16 MFMA GEMM (as round 2) ----------------
#define BM 128
#define BN 128
#define BK 32

__device__ __forceinline__ void stage_u16_tile(const u16* __restrict__ src, int ld,
                                               int r0, int k0, u16* lds,
                                               int lane, int wave)
{
  #pragma unroll
  for (int i = 0; i < 2; i++) {
    int seg = wave * 2048 + i * 1024;
    int f = seg + lane * 16;
    int row = f >> 6;
    int ko = (f & 63) >> 1;
    const u16* g = src + (size_t)(r0 + row) * ld + k0 + ko;
    __builtin_amdgcn_global_load_lds(GLB_AS(g), LDS_AS((char*)lds + seg), 16, 0, 0);
  }
}

__global__ __launch_bounds__(256) void gemm_split_kernel(
    const float* __restrict__ Af,
    const u16* __restrict__ Ahi, const u16* __restrict__ Alo,
    const u16* __restrict__ Whi, const u16* __restrict__ Wlo,
    const float* __restrict__ bias, const float* __restrict__ res,
    float* __restrict__ Cf, u16* __restrict__ Ohi, u16* __restrict__ Olo,
    int M, int K, int N, int act)
{
  __shared__ __align__(16) u16 As_hi[BM * BK];
  __shared__ __align__(16) u16 As_lo[BM * BK];
  __shared__ __align__(16) u16 Bs_hi[BN * BK];
  __shared__ __align__(16) u16 Bs_lo[BN * BK];

  int tid = threadIdx.x;
  int lane = tid & 63, wave = tid >> 6;
  int wm = wave >> 1, wn = wave & 1;
  int ln = lane & 15, quad = lane >> 4;
  int m0 = blockIdx.y * BM, n0 = blockIdx.x * BN;

  ffrag acc[4][4] = {};

  for (int k0 = 0; k0 < K; k0 += BK) {
    if (Af) {
      int r = tid >> 1, h = tid & 1;
      const float* g = Af + (size_t)(m0 + r) * K + k0 + h * 16;
      float xs[16];
      *(float4*)(xs + 0)  = *(const float4*)(g + 0);
      *(float4*)(xs + 4)  = *(const float4*)(g + 4);
      *(float4*)(xs + 8)  = *(const float4*)(g + 8);
      *(float4*)(xs + 12) = *(const float4*)(g + 12);
      u32 ph[8], pl[8];
      #pragma unroll
      for (int j = 0; j < 8; j++) {
        u16 h0, l0, h1, l1;
        bf16_split(xs[2 * j], h0, l0);
        bf16_split(xs[2 * j + 1], h1, l1);
        ph[j] = (u32)h0 | ((u32)h1 << 16);
        pl[j] = (u32)l0 | ((u32)l1 << 16);
      }
      u16* da = As_hi + r * 32 + h * 16;
      *(uint4*)(da)     = make_uint4(ph[0], ph[1], ph[2], ph[3]);
      *(uint4*)(da + 8) = make_uint4(ph[4], ph[5], ph[6], ph[7]);
      u16* dl = As_lo + r * 32 + h * 16;
      *(uint4*)(dl)     = make_uint4(pl[0], pl[1], pl[2], pl[3]);
      *(uint4*)(dl + 8) = make_uint4(pl[4], pl[5], pl[6], pl[7]);
    } else {
      stage_u16_tile(Ahi, K, m0, k0, As_hi, lane, wave);
      stage_u16_tile(Alo, K, m0, k0, As_lo, lane, wave);
    }
    stage_u16_tile(Whi, K, n0, k0, Bs_hi, lane, wave);
    stage_u16_tile(Wlo, K, n0, k0, Bs_lo, lane, wave);
    __syncthreads();

    bfrag ah[4], al[4], bh[4], bl[4];
    #pragma unroll
    for (int t = 0; t < 4; t++) {
      int ao = (wm * 64 + t * 16 + ln) * 32 + quad * 8;
      int bo = (wn * 64 + t * 16 + ln) * 32 + quad * 8;
      ah[t] = *(const bfrag*)(As_hi + ao);
      al[t] = *(const bfrag*)(As_lo + ao);
      bh[t] = *(const bfrag*)(Bs_hi + bo);
      bl[t] = *(const bfrag*)(Bs_lo + bo);
    }
    #pragma unroll
    for (int ti = 0; ti < 4; ti++) {
      #pragma unroll
      for (int tj = 0; tj < 4; tj++) {
        acc[ti][tj] = __builtin_amdgcn_mfma_f32_16x16x32_bf16(ah[ti], bh[tj], acc[ti][tj], 0, 0, 0);
        acc[ti][tj] = __builtin_amdgcn_mfma_f32_16x16x32_bf16(ah[ti], bl[tj], acc[ti][tj], 0, 0, 0);
        acc[ti][tj] = __builtin_amdgcn_mfma_f32_16x16x32_bf16(al[ti], bh[tj], acc[ti][tj], 0, 0, 0);
      }
    }
    __syncthreads();
  }

  #pragma unroll
  for (int tj = 0; tj < 4; tj++) {
    int col = n0 + wn * 64 + tj * 16 + ln;
    float bv = bias ? bias[col] : 0.f;
    #pragma unroll
    for (int ti = 0; ti < 4; ti++) {
      int rw = m0 + wm * 64 + ti * 16 + quad * 4;
      #pragma unroll
      for (int r = 0; r < 4; r++) {
        float y = acc[ti][tj][r] + bv;
        if (act) y = 0.5f * y * (1.f + erff(y * 0.70710678118654752f));
        if (res) y += res[(size_t)(rw + r) * N + col];
        if (Cf) Cf[(size_t)(rw + r) * N + col] = y;
        if (Ohi) {
          u16 hh, ll; bf16_split(y, hh, ll);
          Ohi[(size_t)(rw + r) * N + col] = hh;
          Olo[(size_t)(rw + r) * N + col] = ll;
        }
      }
    }
  }
}

// ---------------- V transpose: qkv split [B,N,3,H,HD] -> Vt [B,H,HD,N] ----------------
__global__ __launch_bounds__(256) void vtrans_kernel(
    const u16* __restrict__ qh, const u16* __restrict__ ql,
    u16* __restrict__ vth, u16* __restrict__ vtl)
{
  __shared__ u16 Th[64][72];
  __shared__ u16 Tl[64][72];
  int b = blockIdx.z, h = blockIdx.y, n0 = blockIdx.x * 64;
  int t = threadIdx.x;
  int nr = t >> 2, ds = (t & 3) * 16;
  size_t src = ((size_t)(b * N_ + n0 + nr)) * 1536 + 1024 + h * 64 + ds;
  *(uint4*)&Th[nr][ds]     = *(const uint4*)(qh + src);
  *(uint4*)&Th[nr][ds + 8] = *(const uint4*)(qh + src + 8);
  *(uint4*)&Tl[nr][ds]     = *(const uint4*)(ql + src);
  *(uint4*)&Tl[nr][ds + 8] = *(const uint4*)(ql + src + 8);
  __syncthreads();
  int dr = t >> 2, ns = (t & 3) * 16;
  u16 oh[16], ol[16];
  #pragma unroll
  for (int j = 0; j < 16; j++) { oh[j] = Th[ns + j][dr]; ol[j] = Tl[ns + j][dr]; }
  size_t dst = ((size_t)((b * H_ + h) * 64 + dr)) * N_ + n0 + ns;
  *(uint4*)(vth + dst)     = *(uint4*)(oh);
  *(uint4*)(vth + dst + 8) = *(uint4*)(oh + 8);
  *(uint4*)(vtl + dst)     = *(uint4*)(ol);
  *(uint4*)(vtl + dst + 8) = *(uint4*)(ol + 8);
}

// ---------------- MFMA flash attention with elevation bias ----------------
// Block: (b, h, 64-query tile), 4 waves; wave w owns 16 queries.
// LDS tiles chunk-layout [c(=k32-chunk)][row][32 u16].
__device__ __forceinline__ void stage_tile64(const u16* __restrict__ gbase, size_t rstride,
                                             u16* lds, int wave, int lane)
{
  #pragma unroll
  for (int i = 0; i < 2; i++) {
    int seg = wave * 2 + i;            // 0..7, 1KB each
    int U = seg * 512 + lane * 8;      // u16 index within 8KB tile
    int c = U >> 11;
    int row = (U >> 5) & 63;
    int k = U & 31;
    const u16* g = gbase + (size_t)row * rstride + c * 32 + k;
    __builtin_amdgcn_global_load_lds(GLB_AS(g), LDS_AS((char*)lds + seg * 1024), 16, 0, 0);
  }
}

__global__ __launch_bounds__(256) void attn_mfma_kernel(
    const u16* __restrict__ qkh, const u16* __restrict__ qkl,
    const u16* __restrict__ vth, const u16* __restrict__ vtl,
    const float* __restrict__ elev, const float* __restrict__ alpha_p,
    float* __restrict__ out)
{
  __shared__ __align__(16) u16 Kh[4096];
  __shared__ __align__(16) u16 Kl[4096];
  __shared__ __align__(16) u16 Vh[4096];
  __shared__ __align__(16) u16 Vl[4096];
  __shared__ __align__(16) float Pf[4 * 16 * 68];

  int b = blockIdx.z, h = blockIdx.y;
  int q0 = blockIdx.x * 64;
  int tid = threadIdx.x;
  int lane = tid & 63, wq = tid >> 6;
  int ln = lane & 15, quad = lane >> 4;
  float alpha = alpha_p[0];

  // ---- stage Q (reuse Kh/Kl buffers), extract fragments ----
  const u16* qbase_h = qkh + (size_t)(b * N_ + q0) * 1536 + h * 64;
  const u16* qbase_l = qkl + (size_t)(b * N_ + q0) * 1536 + h * 64;
  stage_tile64(qbase_h, 1536, Kh, wq, lane);
  stage_tile64(qbase_l, 1536, Kl, wq, lane);
  __syncthreads();
  bfrag qh[2], ql[2];
  #pragma unroll
  for (int c = 0; c < 2; c++) {
    int idx = c * 2048 + (wq * 16 + ln) * 32 + quad * 8;
    qh[c] = *(const bfrag*)(Kh + idx);
    ql[c] = *(const bfrag*)(Kl + idx);
  }
  __syncthreads();   // done reading Q before K staging overwrites

  float eq[4];
  #pragma unroll
  for (int r = 0; r < 4; r++) eq[r] = elev[b * N_ + q0 + wq * 16 + quad * 4 + r];

  float m_i[4], l_i[4];
  #pragma unroll
  for (int r = 0; r < 4; r++) { m_i[r] = -3.0e38f; l_i[r] = 0.f; }
  ffrag O[4] = {};

  const u16* kbase_h = qkh + (size_t)b * N_ * 1536 + 512 + h * 64;
  const u16* kbase_l = qkl + (size_t)b * N_ * 1536 + 512 + h * 64;
  const u16* vbase_h = vth + (size_t)(b * H_ + h) * 64 * N_;
  const u16* vbase_l = vtl + (size_t)(b * H_ + h) * 64 * N_;
  int pfb = wq * (16 * 68);

  for (int k0 = 0; k0 < N_; k0 += 64) {
    stage_tile64(kbase_h + (size_t)k0 * 1536, 1536, Kh, wq, lane);
    stage_tile64(kbase_l + (size_t)k0 * 1536, 1536, Kl, wq, lane);
    stage_tile64(vbase_h + k0, N_, Vh, wq, lane);
    stage_tile64(vbase_l + k0, N_, Vl, wq, lane);
    __syncthreads();

    // ---- S = Q K^T : 4 key-subtiles of 16 ----
    ffrag S[4];
    #pragma unroll
    for (int kt = 0; kt < 4; kt++) {
      ffrag s = {0.f, 0.f, 0.f, 0.f};
      #pragma unroll
      for (int c = 0; c < 2; c++) {
        int idx = c * 2048 + (kt * 16 + ln) * 32 + quad * 8;
        bfrag kh = *(const bfrag*)(Kh + idx);
        bfrag kl = *(const bfrag*)(Kl + idx);
        s = __builtin_amdgcn_mfma_f32_16x16x32_bf16(qh[c], kh, s, 0, 0, 0);
        s = __builtin_amdgcn_mfma_f32_16x16x32_bf16(qh[c], kl, s, 0, 0, 0);
        s = __builtin_amdgcn_mfma_f32_16x16x32_bf16(ql[c], kh, s, 0, 0, 0);
      }
      S[kt] = s;
    }

    // ---- bias + online softmax (rows quad*4+r, cols kt*16+ln) ----
    float ekv[4];
    #pragma unroll
    for (int kt = 0; kt < 4; kt++) ekv[kt] = elev[b * N_ + k0 + kt * 16 + ln];
    float corr[4];
    #pragma unroll
    for (int r = 0; r < 4; r++) {
      float v[4], rmax = -3.0e38f;
      #pragma unroll
      for (int kt = 0; kt < 4; kt++) {
        float ed = (ekv[kt] - eq[r]) * 0.001f;
        float bias = fminf(fmaxf(-alpha * fmaxf(ed, 0.f), -10.f), 0.f);
        float sv = S[kt][r] * SCALE_ + bias;
        v[kt] = sv;
        rmax = fmaxf(rmax, sv);
      }
      #pragma unroll
      for (int off = 1; off < 16; off <<= 1) rmax = fmaxf(rmax, __shfl_xor(rmax, off, 64));
      float mnew = fmaxf(m_i[r], rmax);
      corr[r] = __expf(m_i[r] - mnew);
      float psum = 0.f;
      #pragma unroll
      for (int kt = 0; kt < 4; kt++) {
        float p = __expf(v[kt] - mnew);
        psum += p;
        Pf[pfb + (quad * 4 + r) * 68 + kt * 16 + ln] = p;
      }
      #pragma unroll
      for (int off = 1; off < 16; off <<= 1) psum += __shfl_xor(psum, off, 64);
      m_i[r] = mnew;
      l_i[r] = l_i[r] * corr[r] + psum;
    }
    #pragma unroll
    for (int dt = 0; dt < 4; dt++)
      #pragma unroll
      for (int r = 0; r < 4; r++) O[dt][r] *= corr[r];

    // ---- P fragments (A-layout) from per-wave LDS scratch ----
    bfrag ph[2], pl[2];
    #pragma unroll
    for (int c = 0; c < 2; c++) {
      float pv[8];
      int idx = pfb + ln * 68 + c * 32 + quad * 8;
      *(float4*)(pv)     = *(const float4*)&Pf[idx];
      *(float4*)(pv + 4) = *(const float4*)&Pf[idx + 4];
      #pragma unroll
      for (int j = 0; j < 8; j++) {
        u16 hh, ll; bf16_split(pv[j], hh, ll);
        ph[c][j] = (short)hh; pl[c][j] = (short)ll;
      }
    }

    // ---- O += P V : 4 d-subtiles of 16 ----
    #pragma unroll
    for (int dt = 0; dt < 4; dt++) {
      ffrag o = O[dt];
      #pragma unroll
      for (int c = 0; c < 2; c++) {
        int idx = c * 2048 + (dt * 16 + ln) * 32 + quad * 8;
        bfrag vh = *(const bfrag*)(Vh + idx);
        bfrag vl = *(const bfrag*)(Vl + idx);
        o = __builtin_amdgcn_mfma_f32_16x16x32_bf16(ph[c], vh, o, 0, 0, 0);
        o = __builtin_amdgcn_mfma_f32_16x16x32_bf16(pl[c], vh, o, 0, 0, 0);
        o = __builtin_amdgcn_mfma_f32_16x16x32_bf16(ph[c], vl, o, 0, 0, 0);
      }
      O[dt] = o;
    }
    __syncthreads();
  }

  float inv[4];
  #pragma unroll
  for (int r = 0; r < 4; r++) inv[r] = 1.0f / l_i[r];
  #pragma unroll
  for (int dt = 0; dt < 4; dt++) {
    #pragma unroll
    for (int r = 0; r < 4; r++) {
      int row = q0 + wq * 16 + quad * 4 + r;
      out[((size_t)(b * N_ + row)) * D_ + h * 64 + dt * 16 + ln] = O[dt][r] * inv[r];
    }
  }
}

extern "C" void kernel_launch(void* const* d_in, const int* in_sizes, int n_in,
                              void* d_out, int out_size, void* d_ws, size_t ws_size,
                              hipStream_t stream) {
  const float* x      = (const float*)d_in[0];
  const float* elev   = (const float*)d_in[1];
  const float* ln1_g  = (const float*)d_in[2];
  const float* ln1_b  = (const float*)d_in[3];
  const float* qkv_w  = (const float*)d_in[4];
  const float* alpha  = (const float*)d_in[5];
  const float* proj_w = (const float*)d_in[6];
  const float* proj_b = (const float*)d_in[7];
  const float* ln2_g  = (const float*)d_in[8];
  const float* ln2_b  = (const float*)d_in[9];
  const float* fc1_w  = (const float*)d_in[10];
  const float* fc1_b  = (const float*)d_in[11];
  const float* fc2_w  = (const float*)d_in[12];
  const float* fc2_b  = (const float*)d_in[13];
  float* out = (float*)d_out;

  const size_t HBf   = (size_t)B_ * N_ * D_;        // 4,194,304
  const size_t QKVE  = (size_t)B_ * N_ * 3 * D_;    // 12,582,912
  const size_t MLPE  = (size_t)B_ * N_ * MLP_H_;    // 16,777,216

  char* p = (char*)d_ws;
  float* buf0 = (float*)p;                 p += HBf * 4;          // 16.8 MB
  char* region = p;                        p += MLPE * 4;         // 67.1 MB (qkv split | mlp split)
  u16* qkvh   = (u16*)region;
  u16* qkvl   = (u16*)(region + QKVE * 2);
  u16* mlp_hi = (u16*)region;
  u16* mlp_lo = (u16*)(region + MLPE * 2);
  u16* vth  = (u16*)p;  p += HBf * 2;                             // 8.4 MB
  u16* vtl  = (u16*)p;  p += HBf * 2;                             // 8.4 MB
  float* xres = (float*)p;                 p += HBf * 4;          // 16.8 MB
  u16* qw_hi = (u16*)p;  p += (size_t)D_ * 3 * D_ * 2;
  u16* qw_lo = (u16*)p;  p += (size_t)D_ * 3 * D_ * 2;
  u16* pw_hi = (u16*)p;  p += (size_t)D_ * D_ * 2;
  u16* pw_lo = (u16*)p;  p += (size_t)D_ * D_ * 2;
  u16* f1_hi = (u16*)p;  p += (size_t)D_ * MLP_H_ * 2;
  u16* f1_lo = (u16*)p;  p += (size_t)D_ * MLP_H_ * 2;
  u16* f2_hi = (u16*)p;  p += (size_t)MLP_H_ * D_ * 2;
  u16* f2_lo = (u16*)p;  p += (size_t)MLP_H_ * D_ * 2;

  const int rows = B_ * N_;   // 8192

  wsplit_kernel<<<dim3(3 * D_ / 64, D_ / 64), 256, 0, stream>>>(qkv_w, qw_hi, qw_lo, D_, 3 * D_);
  wsplit_kernel<<<dim3(D_ / 64, D_ / 64), 256, 0, stream>>>(proj_w, pw_hi, pw_lo, D_, D_);
  wsplit_kernel<<<dim3(MLP_H_ / 64, D_ / 64), 256, 0, stream>>>(fc1_w, f1_hi, f1_lo, D_, MLP_H_);
  wsplit_kernel<<<dim3(D_ / 64, MLP_H_ / 64), 256, 0, stream>>>(fc2_w, f2_hi, f2_lo, MLP_H_, D_);

  // LN1
  ln_kernel<<<rows, 256, 0, stream>>>(x, ln1_g, ln1_b, buf0);
  // qkv (split bf16 out)
  gemm_split_kernel<<<dim3(3 * D_ / BN, rows / BM), 256, 0, stream>>>(
      buf0, nullptr, nullptr, qw_hi, qw_lo, nullptr, nullptr,
      nullptr, qkvh, qkvl, rows, D_, 3 * D_, 0);
  // V transpose -> [B,H,HD,N]
  vtrans_kernel<<<dim3(N_ / 64, H_, B_), 256, 0, stream>>>(qkvh, qkvl, vth, vtl);
  // attention -> buf0
  attn_mfma_kernel<<<dim3(N_ / 64, H_, B_), 256, 0, stream>>>(
      qkvh, qkvl, vth, vtl, elev, alpha, buf0);
  // xres = x + attn @ proj_w + proj_b
  gemm_split_kernel<<<dim3(D_ / BN, rows / BM), 256, 0, stream>>>(
      buf0, nullptr, nullptr, pw_hi, pw_lo, proj_b, x,
      xres, nullptr, nullptr, rows, D_, D_, 0);
  // LN2 -> buf0
  ln_kernel<<<rows, 256, 0, stream>>>(xres, ln2_g, ln2_b, buf0);
  // mlp = split(gelu(h2 @ fc1 + b1))
  gemm_split_kernel<<<dim3(MLP_H_ / BN, rows / BM), 256, 0, stream>>>(
      buf0, nullptr, nullptr, f1_hi, f1_lo, fc1_b, nullptr,
      nullptr, mlp_hi, mlp_lo, rows, D_, MLP_H_, 1);
  // out = xres + mlp @ fc2 + b2
  gemm_split_kernel<<<dim3(D_ / BN, rows / BM), 256, 0, stream>>>(
      nullptr, mlp_hi, mlp_lo, f2_hi, f2_lo, fc2_b, xres,
      out, nullptr, nullptr, rows, MLP_H_, D_, 0);
}

// Round 4
// 626.157 us; speedup vs baseline: 2.5190x; 1.0327x over previous
//
#include <hip/hip_runtime.h>
#include <math.h>

typedef unsigned short u16;
typedef unsigned int u32;

#define B_ 4
#define N_ 2048
#define D_ 512
#define H_ 8
#define HD_ 64
#define MLP_H_ 2048
#define EPS_ 1e-5f
#define C2_ 14.426950408889634f          // 10/ln2
#define QSCALE_ 0.1803368801111204f      // 0.125/ln2
#define EL2_ 0.0014426950408889634f      // 1/(1000*ln2)

// ---------- bf16 helpers ----------
__device__ __forceinline__ u16 bf16_rne(float x) {
  u32 u = __float_as_uint(x);
  u32 r = (u + 0x7FFFu + ((u >> 16) & 1u)) >> 16;
  return (u16)r;
}
__device__ __forceinline__ void bf16_split(float x, u16& h, u16& l) {
  h = bf16_rne(x);
  float hf = __uint_as_float(((u32)h) << 16);
  l = bf16_rne(x - hf);
}

typedef __attribute__((ext_vector_type(8))) short bfrag;
typedef __attribute__((ext_vector_type(4))) float ffrag;

#define LDS_AS(p) ((__attribute__((address_space(3))) void*)(p))
#define GLB_AS(p) ((const __attribute__((address_space(1))) void*)(p))

// ---------------- LayerNorm ----------------
__global__ __launch_bounds__(256) void ln_kernel(
    const float* __restrict__ x, const float* __restrict__ g,
    const float* __restrict__ b, float* __restrict__ o)
{
  __shared__ float red[8];
  int row = blockIdx.x;
  int tid = threadIdx.x;
  const float* xr = x + (size_t)row * D_;
  float v0 = xr[tid], v1 = xr[tid + 256];
  float s = v0 + v1;
  #pragma unroll
  for (int off = 32; off > 0; off >>= 1) s += __shfl_xor(s, off, 64);
  if ((tid & 63) == 0) red[tid >> 6] = s;
  __syncthreads();
  float mean = (red[0] + red[1] + red[2] + red[3]) * (1.0f / D_);
  float d0 = v0 - mean, d1 = v1 - mean;
  float vs = d0 * d0 + d1 * d1;
  #pragma unroll
  for (int off = 32; off > 0; off >>= 1) vs += __shfl_xor(vs, off, 64);
  if ((tid & 63) == 0) red[4 + (tid >> 6)] = vs;
  __syncthreads();
  float var = (red[4] + red[5] + red[6] + red[7]) * (1.0f / D_);
  float r = rsqrtf(var + EPS_);
  float* orow = o + (size_t)row * D_;
  orow[tid]       = d0 * r * g[tid] + b[tid];
  orow[tid + 256] = d1 * r * g[tid + 256] + b[tid + 256];
}

// ---------------- elevation pre-scale: e2 = elev * alpha/(1000*ln2) ----------------
__global__ __launch_bounds__(256) void e2_kernel(
    const float* __restrict__ elev, const float* __restrict__ alpha,
    float* __restrict__ e2)
{
  int i = blockIdx.x * 256 + threadIdx.x;
  e2[i] = elev[i] * (alpha[0] * EL2_);
}

// ---------------- Weight split+transpose: W[K,N] f32 -> Thi/Tlo[N,K] bf16 ----------------
__global__ __launch_bounds__(256) void wsplit_kernel(
    const float* __restrict__ W, u16* __restrict__ Thi, u16* __restrict__ Tlo,
    int K, int N)
{
  __shared__ float tile[64][65];
  int n0 = blockIdx.x * 64, k0 = blockIdx.y * 64;
  int c = threadIdx.x & 63, r4 = threadIdx.x >> 6;
  #pragma unroll
  for (int i = 0; i < 16; i++) {
    int r = r4 + i * 4;
    tile[r][c] = W[(size_t)(k0 + r) * N + n0 + c];
  }
  __syncthreads();
  #pragma unroll
  for (int i = 0; i < 16; i++) {
    int rn = r4 + i * 4;
    float v = tile[c][rn];
    u16 h, l; bf16_split(v, h, l);
    size_t o = (size_t)(n0 + rn) * K + k0 + c;
    Thi[o] = h; Tlo[o] = l;
  }
}

// ---------------- split-bf16 MFMA GEMM with XOR-swizzled LDS ----------------
// phys 16B-chunk of (row r, logical chunk c) = r*4 + (c ^ ((r>>1)&3))
#define BM 128
#define BN 128
#define BK 32

__device__ __forceinline__ void stage_u16_tile(const u16* __restrict__ src, int ld,
                                               int r0, int k0, u16* lds,
                                               int lane, int wave)
{
  #pragma unroll
  for (int i = 0; i < 2; i++) {
    int seg = wave * 2 + i;
    int chunk = seg * 64 + lane;              // phys 16B chunk 0..511
    int r = chunk >> 2;
    int c = (chunk & 3) ^ ((r >> 1) & 3);     // logical chunk
    const u16* g = src + (size_t)(r0 + r) * ld + k0 + c * 8;
    __builtin_amdgcn_global_load_lds(GLB_AS(g), LDS_AS((char*)lds + seg * 1024), 16, 0, 0);
  }
}

__global__ __launch_bounds__(256) void gemm_split_kernel(
    const float* __restrict__ Af,
    const u16* __restrict__ Ahi, const u16* __restrict__ Alo,
    const u16* __restrict__ Whi, const u16* __restrict__ Wlo,
    const float* __restrict__ bias, const float* __restrict__ res,
    float* __restrict__ Cf, u16* __restrict__ Ohi, u16* __restrict__ Olo,
    int M, int K, int N, int act, int qcols)
{
  __shared__ __align__(16) u16 As_hi[BM * BK];
  __shared__ __align__(16) u16 As_lo[BM * BK];
  __shared__ __align__(16) u16 Bs_hi[BN * BK];
  __shared__ __align__(16) u16 Bs_lo[BN * BK];

  int tid = threadIdx.x;
  int lane = tid & 63, wave = tid >> 6;
  int wm = wave >> 1, wn = wave & 1;
  int ln = lane & 15, quad = lane >> 4;
  int m0 = blockIdx.y * BM, n0 = blockIdx.x * BN;

  ffrag acc[4][4] = {};

  for (int k0 = 0; k0 < K; k0 += BK) {
    if (Af) {
      int r = tid >> 1, hh = tid & 1;
      const float* g = Af + (size_t)(m0 + r) * K + k0 + hh * 16;
      float xs[16];
      *(float4*)(xs + 0)  = *(const float4*)(g + 0);
      *(float4*)(xs + 4)  = *(const float4*)(g + 4);
      *(float4*)(xs + 8)  = *(const float4*)(g + 8);
      *(float4*)(xs + 12) = *(const float4*)(g + 12);
      u32 ph[8], pl[8];
      #pragma unroll
      for (int j = 0; j < 8; j++) {
        u16 h0, l0, h1, l1;
        bf16_split(xs[2 * j], h0, l0);
        bf16_split(xs[2 * j + 1], h1, l1);
        ph[j] = (u32)h0 | ((u32)h1 << 16);
        pl[j] = (u32)l0 | ((u32)l1 << 16);
      }
      int f = (r >> 1) & 3;
      int c0 = (2 * hh) ^ f, c1 = (2 * hh + 1) ^ f;
      u16* da = As_hi + r * 32;
      *(uint4*)(da + c0 * 8) = make_uint4(ph[0], ph[1], ph[2], ph[3]);
      *(uint4*)(da + c1 * 8) = make_uint4(ph[4], ph[5], ph[6], ph[7]);
      u16* dl = As_lo + r * 32;
      *(uint4*)(dl + c0 * 8) = make_uint4(pl[0], pl[1], pl[2], pl[3]);
      *(uint4*)(dl + c1 * 8) = make_uint4(pl[4], pl[5], pl[6], pl[7]);
    } else {
      stage_u16_tile(Ahi, K, m0, k0, As_hi, lane, wave);
      stage_u16_tile(Alo, K, m0, k0, As_lo, lane, wave);
    }
    stage_u16_tile(Whi, K, n0, k0, Bs_hi, lane, wave);
    stage_u16_tile(Wlo, K, n0, k0, Bs_lo, lane, wave);
    __syncthreads();

    bfrag ah[4], al[4], bh[4], bl[4];
    #pragma unroll
    for (int t = 0; t < 4; t++) {
      int Ra = wm * 64 + t * 16 + ln;
      int Rb = wn * 64 + t * 16 + ln;
      int ao = Ra * 32 + ((quad ^ ((Ra >> 1) & 3)) * 8);
      int bo = Rb * 32 + ((quad ^ ((Rb >> 1) & 3)) * 8);
      ah[t] = *(const bfrag*)(As_hi + ao);
      al[t] = *(const bfrag*)(As_lo + ao);
      bh[t] = *(const bfrag*)(Bs_hi + bo);
      bl[t] = *(const bfrag*)(Bs_lo + bo);
    }
    #pragma unroll
    for (int ti = 0; ti < 4; ti++) {
      #pragma unroll
      for (int tj = 0; tj < 4; tj++) {
        acc[ti][tj] = __builtin_amdgcn_mfma_f32_16x16x32_bf16(ah[ti], bh[tj], acc[ti][tj], 0, 0, 0);
        acc[ti][tj] = __builtin_amdgcn_mfma_f32_16x16x32_bf16(ah[ti], bl[tj], acc[ti][tj], 0, 0, 0);
        acc[ti][tj] = __builtin_amdgcn_mfma_f32_16x16x32_bf16(al[ti], bh[tj], acc[ti][tj], 0, 0, 0);
      }
    }
    __syncthreads();
  }

  #pragma unroll
  for (int tj = 0; tj < 4; tj++) {
    int col = n0 + wn * 64 + tj * 16 + ln;
    float bv = bias ? bias[col] : 0.f;
    float cs = (col < qcols) ? QSCALE_ : 1.0f;
    #pragma unroll
    for (int ti = 0; ti < 4; ti++) {
      int rw = m0 + wm * 64 + ti * 16 + quad * 4;
      #pragma unroll
      for (int r = 0; r < 4; r++) {
        float y = acc[ti][tj][r] + bv;
        if (act) y = 0.5f * y * (1.f + erff(y * 0.70710678118654752f));
        if (res) y += res[(size_t)(rw + r) * N + col];
        if (Cf) Cf[(size_t)(rw + r) * N + col] = y;
        if (Ohi) {
          y *= cs;
          u16 hh, ll; bf16_split(y, hh, ll);
          Ohi[(size_t)(rw + r) * N + col] = hh;
          Olo[(size_t)(rw + r) * N + col] = ll;
        }
      }
    }
  }
}

// ---------------- V transpose: qkv split [B,N,3,H,HD] -> Vt [B,H,HD,N] ----------------
__global__ __launch_bounds__(256) void vtrans_kernel(
    const u16* __restrict__ qh, const u16* __restrict__ ql,
    u16* __restrict__ vth, u16* __restrict__ vtl)
{
  __shared__ u16 Th[64][72];
  __shared__ u16 Tl[64][72];
  int b = blockIdx.z, h = blockIdx.y, n0 = blockIdx.x * 64;
  int t = threadIdx.x;
  int nr = t >> 2, ds = (t & 3) * 16;
  size_t src = ((size_t)(b * N_ + n0 + nr)) * 1536 + 1024 + h * 64 + ds;
  *(uint4*)&Th[nr][ds]     = *(const uint4*)(qh + src);
  *(uint4*)&Th[nr][ds + 8] = *(const uint4*)(qh + src + 8);
  *(uint4*)&Tl[nr][ds]     = *(const uint4*)(ql + src);
  *(uint4*)&Tl[nr][ds + 8] = *(const uint4*)(ql + src + 8);
  __syncthreads();
  int dr = t >> 2, ns = (t & 3) * 16;
  u16 oh[16], ol[16];
  #pragma unroll
  for (int j = 0; j < 16; j++) { oh[j] = Th[ns + j][dr]; ol[j] = Tl[ns + j][dr]; }
  size_t dst = ((size_t)((b * H_ + h) * 64 + dr)) * N_ + n0 + ns;
  *(uint4*)(vth + dst)     = *(uint4*)(oh);
  *(uint4*)(vth + dst + 8) = *(uint4*)(oh + 8);
  *(uint4*)(vtl + dst)     = *(uint4*)(ol);
  *(uint4*)(vtl + dst + 8) = *(uint4*)(ol + 8);
}

// ---------------- MFMA flash attention, S-transposed formulation ----------------
// Block: (b, h, 128-query tile), 4 waves x 32 queries (2 subtiles of 16).
// S^T = mfma(A=K, B=Q) -> thread owns q=ln, keys quad*4+r per kt.
// O^T = mfma(A=Vt, B=P^T) -> D[d][q].
// 64-row LDS tiles: two 4KB halves (d/key chunk), swizzled chunks.
__device__ __forceinline__ void stage_tile64(const u16* __restrict__ gbase, size_t rstride,
                                             u16* lds, int wave, int lane)
{
  #pragma unroll
  for (int i = 0; i < 2; i++) {
    int seg = wave * 2 + i;
    int chunk = seg * 64 + lane;            // phys chunk 0..511
    int ch = chunk >> 8;                    // 32-elem half
    int pc = chunk & 255;
    int r = pc >> 2;
    int q = (pc & 3) ^ ((r >> 1) & 3);
    const u16* g = gbase + (size_t)r * rstride + ch * 32 + q * 8;
    __builtin_amdgcn_global_load_lds(GLB_AS(g), LDS_AS((char*)lds + seg * 1024), 16, 0, 0);
  }
}

__device__ __forceinline__ int frag_off(int c, int R, int quad) {
  return c * 2048 + R * 32 + ((quad ^ ((R >> 1) & 3)) * 8);   // u16 units
}

__global__ __launch_bounds__(256) void attn_mfma_kernel(
    const u16* __restrict__ qkh, const u16* __restrict__ qkl,
    const u16* __restrict__ vth, const u16* __restrict__ vtl,
    const float* __restrict__ e2, float* __restrict__ out)
{
  __shared__ __align__(16) u16 Kh[4096];
  __shared__ __align__(16) u16 Kl[4096];
  __shared__ __align__(16) u16 Vh[4096];
  __shared__ __align__(16) u16 Vl[4096];
  __shared__ __align__(16) u16 Pw[4][32][72];   // per-wave P^T (bf16), [q][key]

  int b = blockIdx.z, h = blockIdx.y;
  int q0 = blockIdx.x * 128;
  int tid = threadIdx.x;
  int lane = tid & 63, wq = tid >> 6;
  int ln = lane & 15, quad = lane >> 4;

  // ---- stage Q (128 rows: 0-63 in Kh/Kl, 64-127 in Vh/Vl) ----
  const u16* qb_h = qkh + ((size_t)(b * N_ + q0)) * 1536 + h * 64;
  const u16* qb_l = qkl + ((size_t)(b * N_ + q0)) * 1536 + h * 64;
  stage_tile64(qb_h, 1536, Kh, wq, lane);
  stage_tile64(qb_h + (size_t)64 * 1536, 1536, Vh, wq, lane);
  stage_tile64(qb_l, 1536, Kl, wq, lane);
  stage_tile64(qb_l + (size_t)64 * 1536, 1536, Vl, wq, lane);
  __syncthreads();

  bfrag qfh[2][2], qfl[2][2];
  {
    const u16* QH = (wq < 2) ? Kh : Vh;
    const u16* QL = (wq < 2) ? Kl : Vl;
    #pragma unroll
    for (int qs = 0; qs < 2; qs++) {
      int R = (wq & 1) * 32 + qs * 16 + ln;
      #pragma unroll
      for (int c = 0; c < 2; c++) {
        int off = frag_off(c, R, quad);
        qfh[qs][c] = *(const bfrag*)(QH + off);
        qfl[qs][c] = *(const bfrag*)(QL + off);
      }
    }
  }
  __syncthreads();

  float e2q[2];
  #pragma unroll
  for (int qs = 0; qs < 2; qs++)
    e2q[qs] = e2[b * N_ + q0 + wq * 32 + qs * 16 + ln];

  float m_i[2] = {-3.0e38f, -3.0e38f}, l_i[2] = {0.f, 0.f};
  ffrag O[2][4] = {};

  const u16* kb_h = qkh + (size_t)b * N_ * 1536 + 512 + h * 64;
  const u16* kb_l = qkl + (size_t)b * N_ * 1536 + 512 + h * 64;
  const u16* vb_h = vth + (size_t)(b * H_ + h) * 64 * N_;
  const u16* vb_l = vtl + (size_t)(b * H_ + h) * 64 * N_;
  const float* e2k = e2 + b * N_;

  for (int k0 = 0; k0 < N_; k0 += 64) {
    stage_tile64(kb_h + (size_t)k0 * 1536, 1536, Kh, wq, lane);
    stage_tile64(kb_l + (size_t)k0 * 1536, 1536, Kl, wq, lane);
    stage_tile64(vb_h + k0, N_, Vh, wq, lane);
    stage_tile64(vb_l + k0, N_, Vl, wq, lane);
    __syncthreads();

    // ---- S^T = K Q^T : per kt, both q-subtiles (K frags transient) ----
    ffrag S0[4], S1[4];
    #pragma unroll
    for (int kt = 0; kt < 4; kt++) {
      ffrag s0 = {0.f, 0.f, 0.f, 0.f}, s1 = {0.f, 0.f, 0.f, 0.f};
      #pragma unroll
      for (int c = 0; c < 2; c++) {
        int off = frag_off(c, kt * 16 + ln, quad);
        bfrag kh = *(const bfrag*)(Kh + off);
        bfrag kl = *(const bfrag*)(Kl + off);
        s0 = __builtin_amdgcn_mfma_f32_16x16x32_bf16(kh, qfh[0][c], s0, 0, 0, 0);
        s0 = __builtin_amdgcn_mfma_f32_16x16x32_bf16(kh, qfl[0][c], s0, 0, 0, 0);
        s0 = __builtin_amdgcn_mfma_f32_16x16x32_bf16(kl, qfh[0][c], s0, 0, 0, 0);
        s1 = __builtin_amdgcn_mfma_f32_16x16x32_bf16(kh, qfh[1][c], s1, 0, 0, 0);
        s1 = __builtin_amdgcn_mfma_f32_16x16x32_bf16(kh, qfl[1][c], s1, 0, 0, 0);
        s1 = __builtin_amdgcn_mfma_f32_16x16x32_bf16(kl, qfh[1][c], s1, 0, 0, 0);
      }
      S0[kt] = s0; S1[kt] = s1;
    }

    // elevation for this thread's 16 keys (shared by both q-subtiles)
    float4 ek[4];
    #pragma unroll
    for (int kt = 0; kt < 4; kt++)
      ek[kt] = *(const float4*)&e2k[k0 + kt * 16 + quad * 4];

    // ---- online softmax per q-subtile (log2 domain) ----
    #pragma unroll
    for (int qs = 0; qs < 2; qs++) {
      ffrag* S = qs ? S1 : S0;
      float p[4][4];
      float mx = -3.0e38f;
      #pragma unroll
      for (int kt = 0; kt < 4; kt++) {
        #pragma unroll
        for (int r = 0; r < 4; r++) {
          float d = (&ek[kt].x)[r] - e2q[qs];
          d = fminf(fmaxf(d, 0.f), C2_);
          float sv = S[kt][r] - d;
          p[kt][r] = sv;
          mx = fmaxf(mx, sv);
        }
      }
      mx = fmaxf(mx, __shfl_xor(mx, 16, 64));
      mx = fmaxf(mx, __shfl_xor(mx, 32, 64));
      float mnew = fmaxf(m_i[qs], mx);
      float corr = exp2f(m_i[qs] - mnew);
      float ps = 0.f;
      #pragma unroll
      for (int kt = 0; kt < 4; kt++) {
        #pragma unroll
        for (int r = 0; r < 4; r++) {
          float pv = exp2f(p[kt][r] - mnew);
          p[kt][r] = pv;
          ps += pv;
        }
      }
      ps += __shfl_xor(ps, 16, 64);
      ps += __shfl_xor(ps, 32, 64);
      m_i[qs] = mnew;
      l_i[qs] = l_i[qs] * corr + ps;
      #pragma unroll
      for (int dt = 0; dt < 4; dt++) O[qs][dt] *= corr;
      // write P^T (bf16) to per-wave LDS: row q, cols = this thread's keys
      int row = qs * 16 + ln;
      #pragma unroll
      for (int kt = 0; kt < 4; kt++) {
        u32 w0 = (u32)bf16_rne(p[kt][0]) | ((u32)bf16_rne(p[kt][1]) << 16);
        u32 w1 = (u32)bf16_rne(p[kt][2]) | ((u32)bf16_rne(p[kt][3]) << 16);
        *(uint2*)&Pw[wq][row][kt * 16 + quad * 4] = make_uint2(w0, w1);
      }
    }

    // ---- P fragments (wave-local, no barrier needed) ----
    bfrag pf[2][2];
    #pragma unroll
    for (int qs = 0; qs < 2; qs++)
      #pragma unroll
      for (int c = 0; c < 2; c++)
        pf[qs][c] = *(const bfrag*)&Pw[wq][qs * 16 + ln][c * 32 + quad * 8];

    // ---- O^T += Vt P^T ----
    #pragma unroll
    for (int dt = 0; dt < 4; dt++) {
      bfrag vfh[2], vfl[2];
      #pragma unroll
      for (int c = 0; c < 2; c++) {
        int off = frag_off(c, dt * 16 + ln, quad);
        vfh[c] = *(const bfrag*)(Vh + off);
        vfl[c] = *(const bfrag*)(Vl + off);
      }
      #pragma unroll
      for (int qs = 0; qs < 2; qs++) {
        ffrag o = O[qs][dt];
        #pragma unroll
        for (int c = 0; c < 2; c++) {
          o = __builtin_amdgcn_mfma_f32_16x16x32_bf16(vfh[c], pf[qs][c], o, 0, 0, 0);
          o = __builtin_amdgcn_mfma_f32_16x16x32_bf16(vfl[c], pf[qs][c], o, 0, 0, 0);
        }
        O[qs][dt] = o;
      }
    }
    __syncthreads();
  }

  #pragma unroll
  for (int qs = 0; qs < 2; qs++) {
    float inv = 1.0f / l_i[qs];
    int row = q0 + wq * 32 + qs * 16 + ln;
    #pragma unroll
    for (int dt = 0; dt < 4; dt++) {
      float4 v = make_float4(O[qs][dt][0] * inv, O[qs][dt][1] * inv,
                             O[qs][dt][2] * inv, O[qs][dt][3] * inv);
      *(float4*)&out[((size_t)(b * N_ + row)) * D_ + h * 64 + dt * 16 + quad * 4] = v;
    }
  }
}

extern "C" void kernel_launch(void* const* d_in, const int* in_sizes, int n_in,
                              void* d_out, int out_size, void* d_ws, size_t ws_size,
                              hipStream_t stream) {
  const float* x      = (const float*)d_in[0];
  const float* elev   = (const float*)d_in[1];
  const float* ln1_g  = (const float*)d_in[2];
  const float* ln1_b  = (const float*)d_in[3];
  const float* qkv_w  = (const float*)d_in[4];
  const float* alpha  = (const float*)d_in[5];
  const float* proj_w = (const float*)d_in[6];
  const float* proj_b = (const float*)d_in[7];
  const float* ln2_g  = (const float*)d_in[8];
  const float* ln2_b  = (const float*)d_in[9];
  const float* fc1_w  = (const float*)d_in[10];
  const float* fc1_b  = (const float*)d_in[11];
  const float* fc2_w  = (const float*)d_in[12];
  const float* fc2_b  = (const float*)d_in[13];
  float* out = (float*)d_out;

  const size_t HBf   = (size_t)B_ * N_ * D_;        // 4,194,304
  const size_t QKVE  = (size_t)B_ * N_ * 3 * D_;    // 12,582,912
  const size_t MLPE  = (size_t)B_ * N_ * MLP_H_;    // 16,777,216

  char* p = (char*)d_ws;
  float* buf0 = (float*)p;                 p += HBf * 4;
  char* region = p;                        p += MLPE * 4;         // qkv split | mlp split
  u16* qkvh   = (u16*)region;
  u16* qkvl   = (u16*)(region + QKVE * 2);
  u16* mlp_hi = (u16*)region;
  u16* mlp_lo = (u16*)(region + MLPE * 2);
  u16* vth  = (u16*)p;  p += HBf * 2;
  u16* vtl  = (u16*)p;  p += HBf * 2;
  float* xres = (float*)p;                 p += HBf * 4;
  u16* qw_hi = (u16*)p;  p += (size_t)D_ * 3 * D_ * 2;
  u16* qw_lo = (u16*)p;  p += (size_t)D_ * 3 * D_ * 2;
  u16* pw_hi = (u16*)p;  p += (size_t)D_ * D_ * 2;
  u16* pw_lo = (u16*)p;  p += (size_t)D_ * D_ * 2;
  u16* f1_hi = (u16*)p;  p += (size_t)D_ * MLP_H_ * 2;
  u16* f1_lo = (u16*)p;  p += (size_t)D_ * MLP_H_ * 2;
  u16* f2_hi = (u16*)p;  p += (size_t)MLP_H_ * D_ * 2;
  u16* f2_lo = (u16*)p;  p += (size_t)MLP_H_ * D_ * 2;
  float* e2  = (float*)p; p += (size_t)B_ * N_ * 4;

  const int rows = B_ * N_;   // 8192

  wsplit_kernel<<<dim3(3 * D_ / 64, D_ / 64), 256, 0, stream>>>(qkv_w, qw_hi, qw_lo, D_, 3 * D_);
  wsplit_kernel<<<dim3(D_ / 64, D_ / 64), 256, 0, stream>>>(proj_w, pw_hi, pw_lo, D_, D_);
  wsplit_kernel<<<dim3(MLP_H_ / 64, D_ / 64), 256, 0, stream>>>(fc1_w, f1_hi, f1_lo, D_, MLP_H_);
  wsplit_kernel<<<dim3(D_ / 64, MLP_H_ / 64), 256, 0, stream>>>(fc2_w, f2_hi, f2_lo, MLP_H_, D_);
  e2_kernel<<<rows / 256, 256, 0, stream>>>(elev, alpha, e2);

  // LN1
  ln_kernel<<<rows, 256, 0, stream>>>(x, ln1_g, ln1_b, buf0);
  // qkv (split bf16 out; Q columns pre-scaled by 0.125/ln2)
  gemm_split_kernel<<<dim3(3 * D_ / BN, rows / BM), 256, 0, stream>>>(
      buf0, nullptr, nullptr, qw_hi, qw_lo, nullptr, nullptr,
      nullptr, qkvh, qkvl, rows, D_, 3 * D_, 0, D_);
  // V transpose -> [B,H,HD,N]
  vtrans_kernel<<<dim3(N_ / 64, H_, B_), 256, 0, stream>>>(qkvh, qkvl, vth, vtl);
  // attention -> buf0
  attn_mfma_kernel<<<dim3(N_ / 128, H_, B_), 256, 0, stream>>>(
      qkvh, qkvl, vth, vtl, e2, buf0);
  // xres = x + attn @ proj_w + proj_b
  gemm_split_kernel<<<dim3(D_ / BN, rows / BM), 256, 0, stream>>>(
      buf0, nullptr, nullptr, pw_hi, pw_lo, proj_b, x,
      xres, nullptr, nullptr, rows, D_, D_, 0, 0);
  // LN2 -> buf0
  ln_kernel<<<rows, 256, 0, stream>>>(xres, ln2_g, ln2_b, buf0);
  // mlp = split(gelu(h2 @ fc1 + b1))
  gemm_split_kernel<<<dim3(MLP_H_ / BN, rows / BM), 256, 0, stream>>>(
      buf0, nullptr, nullptr, f1_hi, f1_lo, fc1_b, nullptr,
      nullptr, mlp_hi, mlp_lo, rows, D_, MLP_H_, 1, 0);
  // out = xres + mlp @ fc2 + b2
  gemm_split_kernel<<<dim3(D_ / BN, rows / BM), 256, 0, stream>>>(
      nullptr, mlp_hi, mlp_lo, f2_hi, f2_lo, fc2_b, xres,
      out, nullptr, nullptr, rows, MLP_H_, D_, 0, 0);
}

// Round 5
// 529.797 us; speedup vs baseline: 2.9771x; 1.1819x over previous
//
#include <hip/hip_runtime.h>
#include <math.h>

typedef unsigned short u16;
typedef unsigned int u32;

#define B_ 4
#define N_ 2048
#define D_ 512
#define H_ 8
#define HD_ 64
#define MLP_H_ 2048
#define EPS_ 1e-5f
#define C2_ 14.426950408889634f          // 10/ln2
#define QSCALE_ 0.1803368801111204f      // 0.125/ln2
#define EL2_ 0.0014426950408889634f      // 1/(1000*ln2)

// ---------- bf16 helpers ----------
__device__ __forceinline__ u16 bf16_rne(float x) {
  u32 u = __float_as_uint(x);
  u32 r = (u + 0x7FFFu + ((u >> 16) & 1u)) >> 16;
  return (u16)r;
}
__device__ __forceinline__ void bf16_split(float x, u16& h, u16& l) {
  h = bf16_rne(x);
  float hf = __uint_as_float(((u32)h) << 16);
  l = bf16_rne(x - hf);
}

typedef __attribute__((ext_vector_type(8))) short bfrag;
typedef __attribute__((ext_vector_type(4))) float ffrag;

#define LDS_AS(p) ((__attribute__((address_space(3))) void*)(p))
#define GLB_AS(p) ((const __attribute__((address_space(1))) void*)(p))

// ---------------- LayerNorm ----------------
__global__ __launch_bounds__(256) void ln_kernel(
    const float* __restrict__ x, const float* __restrict__ g,
    const float* __restrict__ b, float* __restrict__ o)
{
  __shared__ float red[8];
  int row = blockIdx.x;
  int tid = threadIdx.x;
  const float* xr = x + (size_t)row * D_;
  float v0 = xr[tid], v1 = xr[tid + 256];
  float s = v0 + v1;
  #pragma unroll
  for (int off = 32; off > 0; off >>= 1) s += __shfl_xor(s, off, 64);
  if ((tid & 63) == 0) red[tid >> 6] = s;
  __syncthreads();
  float mean = (red[0] + red[1] + red[2] + red[3]) * (1.0f / D_);
  float d0 = v0 - mean, d1 = v1 - mean;
  float vs = d0 * d0 + d1 * d1;
  #pragma unroll
  for (int off = 32; off > 0; off >>= 1) vs += __shfl_xor(vs, off, 64);
  if ((tid & 63) == 0) red[4 + (tid >> 6)] = vs;
  __syncthreads();
  float var = (red[4] + red[5] + red[6] + red[7]) * (1.0f / D_);
  float r = rsqrtf(var + EPS_);
  float* orow = o + (size_t)row * D_;
  orow[tid]       = d0 * r * g[tid] + b[tid];
  orow[tid + 256] = d1 * r * g[tid + 256] + b[tid + 256];
}

// ---------------- elevation pre-scale ----------------
__global__ __launch_bounds__(256) void e2_kernel(
    const float* __restrict__ elev, const float* __restrict__ alpha,
    float* __restrict__ e2)
{
  int i = blockIdx.x * 256 + threadIdx.x;
  e2[i] = elev[i] * (alpha[0] * EL2_);
}

// ---------------- Weight split+transpose ----------------
__global__ __launch_bounds__(256) void wsplit_kernel(
    const float* __restrict__ W, u16* __restrict__ Thi, u16* __restrict__ Tlo,
    int K, int N)
{
  __shared__ float tile[64][65];
  int n0 = blockIdx.x * 64, k0 = blockIdx.y * 64;
  int c = threadIdx.x & 63, r4 = threadIdx.x >> 6;
  #pragma unroll
  for (int i = 0; i < 16; i++) {
    int r = r4 + i * 4;
    tile[r][c] = W[(size_t)(k0 + r) * N + n0 + c];
  }
  __syncthreads();
  #pragma unroll
  for (int i = 0; i < 16; i++) {
    int rn = r4 + i * 4;
    float v = tile[c][rn];
    u16 h, l; bf16_split(v, h, l);
    size_t o = (size_t)(n0 + rn) * K + k0 + c;
    Thi[o] = h; Tlo[o] = l;
  }
}

// ---------------- split-bf16 MFMA GEMM with XOR-swizzled LDS ----------------
#define BM 128
#define BN 128
#define BK 32

__device__ __forceinline__ void stage_u16_tile(const u16* __restrict__ src, int ld,
                                               int r0, int k0, u16* lds,
                                               int lane, int wave)
{
  #pragma unroll
  for (int i = 0; i < 2; i++) {
    int seg = wave * 2 + i;
    int chunk = seg * 64 + lane;
    int r = chunk >> 2;
    int c = (chunk & 3) ^ ((r >> 1) & 3);
    const u16* g = src + (size_t)(r0 + r) * ld + k0 + c * 8;
    __builtin_amdgcn_global_load_lds(GLB_AS(g), LDS_AS((char*)lds + seg * 1024), 16, 0, 0);
  }
}

__global__ __launch_bounds__(256) void gemm_split_kernel(
    const float* __restrict__ Af,
    const u16* __restrict__ Ahi, const u16* __restrict__ Alo,
    const u16* __restrict__ Whi, const u16* __restrict__ Wlo,
    const float* __restrict__ bias, const float* __restrict__ res,
    float* __restrict__ Cf, u16* __restrict__ Ohi, u16* __restrict__ Olo,
    int M, int K, int N, int act, int qcols)
{
  __shared__ __align__(16) u16 As_hi[BM * BK];
  __shared__ __align__(16) u16 As_lo[BM * BK];
  __shared__ __align__(16) u16 Bs_hi[BN * BK];
  __shared__ __align__(16) u16 Bs_lo[BN * BK];

  int tid = threadIdx.x;
  int lane = tid & 63, wave = tid >> 6;
  int wm = wave >> 1, wn = wave & 1;
  int ln = lane & 15, quad = lane >> 4;
  int m0 = blockIdx.y * BM, n0 = blockIdx.x * BN;

  ffrag acc[4][4] = {};

  for (int k0 = 0; k0 < K; k0 += BK) {
    if (Af) {
      int r = tid >> 1, hh = tid & 1;
      const float* g = Af + (size_t)(m0 + r) * K + k0 + hh * 16;
      float xs[16];
      *(float4*)(xs + 0)  = *(const float4*)(g + 0);
      *(float4*)(xs + 4)  = *(const float4*)(g + 4);
      *(float4*)(xs + 8)  = *(const float4*)(g + 8);
      *(float4*)(xs + 12) = *(const float4*)(g + 12);
      u32 ph[8], pl[8];
      #pragma unroll
      for (int j = 0; j < 8; j++) {
        u16 h0, l0, h1, l1;
        bf16_split(xs[2 * j], h0, l0);
        bf16_split(xs[2 * j + 1], h1, l1);
        ph[j] = (u32)h0 | ((u32)h1 << 16);
        pl[j] = (u32)l0 | ((u32)l1 << 16);
      }
      int f = (r >> 1) & 3;
      int c0 = (2 * hh) ^ f, c1 = (2 * hh + 1) ^ f;
      u16* da = As_hi + r * 32;
      *(uint4*)(da + c0 * 8) = make_uint4(ph[0], ph[1], ph[2], ph[3]);
      *(uint4*)(da + c1 * 8) = make_uint4(ph[4], ph[5], ph[6], ph[7]);
      u16* dl = As_lo + r * 32;
      *(uint4*)(dl + c0 * 8) = make_uint4(pl[0], pl[1], pl[2], pl[3]);
      *(uint4*)(dl + c1 * 8) = make_uint4(pl[4], pl[5], pl[6], pl[7]);
    } else {
      stage_u16_tile(Ahi, K, m0, k0, As_hi, lane, wave);
      stage_u16_tile(Alo, K, m0, k0, As_lo, lane, wave);
    }
    stage_u16_tile(Whi, K, n0, k0, Bs_hi, lane, wave);
    stage_u16_tile(Wlo, K, n0, k0, Bs_lo, lane, wave);
    __syncthreads();

    bfrag ah[4], al[4], bh[4], bl[4];
    #pragma unroll
    for (int t = 0; t < 4; t++) {
      int Ra = wm * 64 + t * 16 + ln;
      int Rb = wn * 64 + t * 16 + ln;
      int ao = Ra * 32 + ((quad ^ ((Ra >> 1) & 3)) * 8);
      int bo = Rb * 32 + ((quad ^ ((Rb >> 1) & 3)) * 8);
      ah[t] = *(const bfrag*)(As_hi + ao);
      al[t] = *(const bfrag*)(As_lo + ao);
      bh[t] = *(const bfrag*)(Bs_hi + bo);
      bl[t] = *(const bfrag*)(Bs_lo + bo);
    }
    #pragma unroll
    for (int ti = 0; ti < 4; ti++) {
      #pragma unroll
      for (int tj = 0; tj < 4; tj++) {
        acc[ti][tj] = __builtin_amdgcn_mfma_f32_16x16x32_bf16(ah[ti], bh[tj], acc[ti][tj], 0, 0, 0);
        acc[ti][tj] = __builtin_amdgcn_mfma_f32_16x16x32_bf16(ah[ti], bl[tj], acc[ti][tj], 0, 0, 0);
        acc[ti][tj] = __builtin_amdgcn_mfma_f32_16x16x32_bf16(al[ti], bh[tj], acc[ti][tj], 0, 0, 0);
      }
    }
    __syncthreads();
  }

  #pragma unroll
  for (int tj = 0; tj < 4; tj++) {
    int col = n0 + wn * 64 + tj * 16 + ln;
    float bv = bias ? bias[col] : 0.f;
    float cs = (col < qcols) ? QSCALE_ : 1.0f;
    bool store_lo = (qcols == 0) || (col < qcols);   // K/V columns: hi only
    #pragma unroll
    for (int ti = 0; ti < 4; ti++) {
      int rw = m0 + wm * 64 + ti * 16 + quad * 4;
      #pragma unroll
      for (int r = 0; r < 4; r++) {
        float y = acc[ti][tj][r] + bv;
        if (act) y = 0.5f * y * (1.f + erff(y * 0.70710678118654752f));
        if (res) y += res[(size_t)(rw + r) * N + col];
        if (Cf) Cf[(size_t)(rw + r) * N + col] = y;
        if (Ohi) {
          y *= cs;
          u16 hh, ll; bf16_split(y, hh, ll);
          Ohi[(size_t)(rw + r) * N + col] = hh;
          if (store_lo) Olo[(size_t)(rw + r) * N + col] = ll;
        }
      }
    }
  }
}

// ---------------- V transpose (hi only): qkv hi [B,N,3,H,HD] -> Vt [B,H,HD,N] ----------------
__global__ __launch_bounds__(256) void vtrans_kernel(
    const u16* __restrict__ qh, u16* __restrict__ vth)
{
  __shared__ u16 Th[64][72];
  int b = blockIdx.z, h = blockIdx.y, n0 = blockIdx.x * 64;
  int t = threadIdx.x;
  int nr = t >> 2, ds = (t & 3) * 16;
  size_t src = ((size_t)(b * N_ + n0 + nr)) * 1536 + 1024 + h * 64 + ds;
  *(uint4*)&Th[nr][ds]     = *(const uint4*)(qh + src);
  *(uint4*)&Th[nr][ds + 8] = *(const uint4*)(qh + src + 8);
  __syncthreads();
  int dr = t >> 2, ns = (t & 3) * 16;
  u16 oh[16];
  #pragma unroll
  for (int j = 0; j < 16; j++) oh[j] = Th[ns + j][dr];
  size_t dst = ((size_t)((b * H_ + h) * 64 + dr)) * N_ + n0 + ns;
  *(uint4*)(vth + dst)     = *(uint4*)(oh);
  *(uint4*)(vth + dst + 8) = *(uint4*)(oh + 8);
}

// ---------------- MFMA flash attention, S-transposed, K/V single-bf16 ----------------
// Block: (b, h, 64-query tile), 4 waves x 16 queries. Grid 1024.
// QK: 2 MFMA (kh*qh + kh*ql); PV: 1 MFMA (vh*p).
__device__ __forceinline__ void stage_tile64(const u16* __restrict__ gbase, size_t rstride,
                                             u16* lds, int wave, int lane)
{
  #pragma unroll
  for (int i = 0; i < 2; i++) {
    int seg = wave * 2 + i;
    int chunk = seg * 64 + lane;            // phys chunk 0..511
    int ch = chunk >> 8;                    // 32-elem half
    int pc = chunk & 255;
    int r = pc >> 2;
    int q = (pc & 3) ^ ((r >> 1) & 3);
    const u16* g = gbase + (size_t)r * rstride + ch * 32 + q * 8;
    __builtin_amdgcn_global_load_lds(GLB_AS(g), LDS_AS((char*)lds + seg * 1024), 16, 0, 0);
  }
}

__device__ __forceinline__ int frag_off(int c, int R, int quad) {
  return c * 2048 + R * 32 + ((quad ^ ((R >> 1) & 3)) * 8);   // u16 units
}

__global__ __launch_bounds__(256) void attn_mfma_kernel(
    const u16* __restrict__ qkh, const u16* __restrict__ qkl,
    const u16* __restrict__ vth,
    const float* __restrict__ e2, float* __restrict__ out)
{
  __shared__ __align__(16) u16 Kh[4096];        // K tile (or Q-hi staging)
  __shared__ __align__(16) u16 Vh[4096];        // V tile (or Q-lo staging)
  __shared__ __align__(16) u16 Pw[4][16][72];   // per-wave P^T bf16 [q][key]

  int b = blockIdx.z, h = blockIdx.y;
  int q0 = blockIdx.x * 64;
  int tid = threadIdx.x;
  int lane = tid & 63, wq = tid >> 6;
  int ln = lane & 15, quad = lane >> 4;

  // ---- stage Q: hi -> Kh, lo -> Vh ----
  const u16* qb_h = qkh + ((size_t)(b * N_ + q0)) * 1536 + h * 64;
  const u16* qb_l = qkl + ((size_t)(b * N_ + q0)) * 1536 + h * 64;
  stage_tile64(qb_h, 1536, Kh, wq, lane);
  stage_tile64(qb_l, 1536, Vh, wq, lane);
  __syncthreads();

  bfrag qfh[2], qfl[2];
  #pragma unroll
  for (int c = 0; c < 2; c++) {
    int off = frag_off(c, wq * 16 + ln, quad);
    qfh[c] = *(const bfrag*)(Kh + off);
    qfl[c] = *(const bfrag*)(Vh + off);
  }
  __syncthreads();

  float e2q = e2[b * N_ + q0 + wq * 16 + ln];
  float m_i = -3.0e38f, l_i = 0.f;
  ffrag O[4] = {};

  const u16* kb_h = qkh + (size_t)b * N_ * 1536 + 512 + h * 64;
  const u16* vb_h = vth + (size_t)(b * H_ + h) * 64 * N_;
  const float* e2k = e2 + b * N_;

  for (int k0 = 0; k0 < N_; k0 += 64) {
    stage_tile64(kb_h + (size_t)k0 * 1536, 1536, Kh, wq, lane);
    stage_tile64(vb_h + k0, N_, Vh, wq, lane);
    __syncthreads();

    // ---- S^T = K (Qh+Ql)^T ----
    ffrag S[4];
    #pragma unroll
    for (int kt = 0; kt < 4; kt++) {
      ffrag s = {0.f, 0.f, 0.f, 0.f};
      #pragma unroll
      for (int c = 0; c < 2; c++) {
        bfrag kf = *(const bfrag*)(Kh + frag_off(c, kt * 16 + ln, quad));
        s = __builtin_amdgcn_mfma_f32_16x16x32_bf16(kf, qfh[c], s, 0, 0, 0);
        s = __builtin_amdgcn_mfma_f32_16x16x32_bf16(kf, qfl[c], s, 0, 0, 0);
      }
      S[kt] = s;
    }

    // ---- bias + online softmax (thread: query ln, keys kt*16+quad*4+r) ----
    float4 ek[4];
    #pragma unroll
    for (int kt = 0; kt < 4; kt++)
      ek[kt] = *(const float4*)&e2k[k0 + kt * 16 + quad * 4];

    float p[4][4];
    float mx = -3.0e38f;
    #pragma unroll
    for (int kt = 0; kt < 4; kt++) {
      #pragma unroll
      for (int r = 0; r < 4; r++) {
        float d = (&ek[kt].x)[r] - e2q;
        d = fminf(fmaxf(d, 0.f), C2_);
        float sv = S[kt][r] - d;
        p[kt][r] = sv;
        mx = fmaxf(mx, sv);
      }
    }
    mx = fmaxf(mx, __shfl_xor(mx, 16, 64));
    mx = fmaxf(mx, __shfl_xor(mx, 32, 64));
    float mnew = fmaxf(m_i, mx);
    float corr = exp2f(m_i - mnew);
    float ps = 0.f;
    #pragma unroll
    for (int kt = 0; kt < 4; kt++) {
      #pragma unroll
      for (int r = 0; r < 4; r++) {
        float pv = exp2f(p[kt][r] - mnew);
        p[kt][r] = pv;
        ps += pv;
      }
    }
    ps += __shfl_xor(ps, 16, 64);
    ps += __shfl_xor(ps, 32, 64);
    m_i = mnew;
    l_i = l_i * corr + ps;
    #pragma unroll
    for (int dt = 0; dt < 4; dt++) O[dt] *= corr;

    // write P^T bf16: row = q (ln), cols = this thread's 16 keys
    #pragma unroll
    for (int kt = 0; kt < 4; kt++) {
      u32 w0 = (u32)bf16_rne(p[kt][0]) | ((u32)bf16_rne(p[kt][1]) << 16);
      u32 w1 = (u32)bf16_rne(p[kt][2]) | ((u32)bf16_rne(p[kt][3]) << 16);
      *(uint2*)&Pw[wq][ln][kt * 16 + quad * 4] = make_uint2(w0, w1);
    }

    // ---- P fragments (wave-local) ----
    bfrag pf[2];
    #pragma unroll
    for (int c = 0; c < 2; c++)
      pf[c] = *(const bfrag*)&Pw[wq][ln][c * 32 + quad * 8];

    // ---- O^T += Vt P^T ----
    #pragma unroll
    for (int dt = 0; dt < 4; dt++) {
      ffrag o = O[dt];
      #pragma unroll
      for (int c = 0; c < 2; c++) {
        bfrag vf = *(const bfrag*)(Vh + frag_off(c, dt * 16 + ln, quad));
        o = __builtin_amdgcn_mfma_f32_16x16x32_bf16(vf, pf[c], o, 0, 0, 0);
      }
      O[dt] = o;
    }
    __syncthreads();
  }

  float inv = 1.0f / l_i;
  int row = q0 + wq * 16 + ln;
  #pragma unroll
  for (int dt = 0; dt < 4; dt++) {
    float4 v = make_float4(O[dt][0] * inv, O[dt][1] * inv,
                           O[dt][2] * inv, O[dt][3] * inv);
    *(float4*)&out[((size_t)(b * N_ + row)) * D_ + h * 64 + dt * 16 + quad * 4] = v;
  }
}

extern "C" void kernel_launch(void* const* d_in, const int* in_sizes, int n_in,
                              void* d_out, int out_size, void* d_ws, size_t ws_size,
                              hipStream_t stream) {
  const float* x      = (const float*)d_in[0];
  const float* elev   = (const float*)d_in[1];
  const float* ln1_g  = (const float*)d_in[2];
  const float* ln1_b  = (const float*)d_in[3];
  const float* qkv_w  = (const float*)d_in[4];
  const float* alpha  = (const float*)d_in[5];
  const float* proj_w = (const float*)d_in[6];
  const float* proj_b = (const float*)d_in[7];
  const float* ln2_g  = (const float*)d_in[8];
  const float* ln2_b  = (const float*)d_in[9];
  const float* fc1_w  = (const float*)d_in[10];
  const float* fc1_b  = (const float*)d_in[11];
  const float* fc2_w  = (const float*)d_in[12];
  const float* fc2_b  = (const float*)d_in[13];
  float* out = (float*)d_out;

  const size_t HBf   = (size_t)B_ * N_ * D_;        // 4,194,304
  const size_t QKVE  = (size_t)B_ * N_ * 3 * D_;    // 12,582,912
  const size_t MLPE  = (size_t)B_ * N_ * MLP_H_;    // 16,777,216

  char* p = (char*)d_ws;
  float* buf0 = (float*)p;                 p += HBf * 4;
  char* region = p;                        p += MLPE * 4;         // qkv split | mlp split
  u16* qkvh   = (u16*)region;
  u16* qkvl   = (u16*)(region + QKVE * 2);
  u16* mlp_hi = (u16*)region;
  u16* mlp_lo = (u16*)(region + MLPE * 2);
  u16* vth  = (u16*)p;  p += HBf * 2;
  float* xres = (float*)p;                 p += HBf * 4;
  u16* qw_hi = (u16*)p;  p += (size_t)D_ * 3 * D_ * 2;
  u16* qw_lo = (u16*)p;  p += (size_t)D_ * 3 * D_ * 2;
  u16* pw_hi = (u16*)p;  p += (size_t)D_ * D_ * 2;
  u16* pw_lo = (u16*)p;  p += (size_t)D_ * D_ * 2;
  u16* f1_hi = (u16*)p;  p += (size_t)D_ * MLP_H_ * 2;
  u16* f1_lo = (u16*)p;  p += (size_t)D_ * MLP_H_ * 2;
  u16* f2_hi = (u16*)p;  p += (size_t)MLP_H_ * D_ * 2;
  u16* f2_lo = (u16*)p;  p += (size_t)MLP_H_ * D_ * 2;
  float* e2  = (float*)p; p += (size_t)B_ * N_ * 4;

  const int rows = B_ * N_;   // 8192

  wsplit_kernel<<<dim3(3 * D_ / 64, D_ / 64), 256, 0, stream>>>(qkv_w, qw_hi, qw_lo, D_, 3 * D_);
  wsplit_kernel<<<dim3(D_ / 64, D_ / 64), 256, 0, stream>>>(proj_w, pw_hi, pw_lo, D_, D_);
  wsplit_kernel<<<dim3(MLP_H_ / 64, D_ / 64), 256, 0, stream>>>(fc1_w, f1_hi, f1_lo, D_, MLP_H_);
  wsplit_kernel<<<dim3(D_ / 64, MLP_H_ / 64), 256, 0, stream>>>(fc2_w, f2_hi, f2_lo, MLP_H_, D_);
  e2_kernel<<<rows / 256, 256, 0, stream>>>(elev, alpha, e2);

  // LN1
  ln_kernel<<<rows, 256, 0, stream>>>(x, ln1_g, ln1_b, buf0);
  // qkv (split bf16 out; Q cols pre-scaled by 0.125/ln2; K/V cols hi-only)
  gemm_split_kernel<<<dim3(3 * D_ / BN, rows / BM), 256, 0, stream>>>(
      buf0, nullptr, nullptr, qw_hi, qw_lo, nullptr, nullptr,
      nullptr, qkvh, qkvl, rows, D_, 3 * D_, 0, D_);
  // V transpose (hi) -> [B,H,HD,N]
  vtrans_kernel<<<dim3(N_ / 64, H_, B_), 256, 0, stream>>>(qkvh, vth);
  // attention -> buf0
  attn_mfma_kernel<<<dim3(N_ / 64, H_, B_), 256, 0, stream>>>(
      qkvh, qkvl, vth, e2, buf0);
  // xres = x + attn @ proj_w + proj_b
  gemm_split_kernel<<<dim3(D_ / BN, rows / BM), 256, 0, stream>>>(
      buf0, nullptr, nullptr, pw_hi, pw_lo, proj_b, x,
      xres, nullptr, nullptr, rows, D_, D_, 0, 0);
  // LN2 -> buf0
  ln_kernel<<<rows, 256, 0, stream>>>(xres, ln2_g, ln2_b, buf0);
  // mlp = split(gelu(h2 @ fc1 + b1))
  gemm_split_kernel<<<dim3(MLP_H_ / BN, rows / BM), 256, 0, stream>>>(
      buf0, nullptr, nullptr, f1_hi, f1_lo, fc1_b, nullptr,
      nullptr, mlp_hi, mlp_lo, rows, D_, MLP_H_, 1, 0);
  // out = xres + mlp @ fc2 + b2
  gemm_split_kernel<<<dim3(D_ / BN, rows / BM), 256, 0, stream>>>(
      nullptr, mlp_hi, mlp_lo, f2_hi, f2_lo, fc2_b, xres,
      out, nullptr, nullptr, rows, MLP_H_, D_, 0, 0);
}

// Round 6
// 454.457 us; speedup vs baseline: 3.4707x; 1.1658x over previous
//
#include <hip/hip_runtime.h>
#include <math.h>

typedef unsigned short u16;
typedef unsigned int u32;

#define B_ 4
#define N_ 2048
#define D_ 512
#define H_ 8
#define HD_ 64
#define MLP_H_ 2048
#define EPS_ 1e-5f
#define C2_ 14.426950408889634f          // 10/ln2
#define QSCALE_ 0.1803368801111204f      // 0.125/ln2
#define EL2_ 0.0014426950408889634f      // 1/(1000*ln2)

// ---------- fast exp2 ----------
#if __has_builtin(__builtin_amdgcn_exp2f)
#define EXP2(x) __builtin_amdgcn_exp2f(x)
#else
#define EXP2(x) exp2f(x)
#endif

// ---------- bf16 helpers ----------
__device__ __forceinline__ u16 bf16_rne(float x) {
  u32 u = __float_as_uint(x);
  u32 r = (u + 0x7FFFu + ((u >> 16) & 1u)) >> 16;
  return (u16)r;
}
#if __has_builtin(__builtin_amdgcn_cvt_pk_bf16_f32)
typedef __bf16 bf2_t __attribute__((ext_vector_type(2)));
__device__ __forceinline__ u32 pk_bf16(float a, float b) {
  bf2_t v = __builtin_amdgcn_cvt_pk_bf16_f32(a, b);
  u32 r; __builtin_memcpy(&r, &v, 4); return r;
}
#else
__device__ __forceinline__ u32 pk_bf16(float a, float b) {
  return (u32)bf16_rne(a) | ((u32)bf16_rne(b) << 16);
}
#endif
__device__ __forceinline__ void bf16_split(float x, u16& h, u16& l) {
  h = bf16_rne(x);
  float hf = __uint_as_float(((u32)h) << 16);
  l = bf16_rne(x - hf);
}

typedef __attribute__((ext_vector_type(8))) short bfrag;
typedef __attribute__((ext_vector_type(4))) float ffrag;

#define LDS_AS(p) ((__attribute__((address_space(3))) void*)(p))
#define GLB_AS(p) ((const __attribute__((address_space(1))) void*)(p))

// ---------------- LayerNorm ----------------
__global__ __launch_bounds__(256) void ln_kernel(
    const float* __restrict__ x, const float* __restrict__ g,
    const float* __restrict__ b, float* __restrict__ o)
{
  __shared__ float red[8];
  int row = blockIdx.x;
  int tid = threadIdx.x;
  const float* xr = x + (size_t)row * D_;
  float v0 = xr[tid], v1 = xr[tid + 256];
  float s = v0 + v1;
  #pragma unroll
  for (int off = 32; off > 0; off >>= 1) s += __shfl_xor(s, off, 64);
  if ((tid & 63) == 0) red[tid >> 6] = s;
  __syncthreads();
  float mean = (red[0] + red[1] + red[2] + red[3]) * (1.0f / D_);
  float d0 = v0 - mean, d1 = v1 - mean;
  float vs = d0 * d0 + d1 * d1;
  #pragma unroll
  for (int off = 32; off > 0; off >>= 1) vs += __shfl_xor(vs, off, 64);
  if ((tid & 63) == 0) red[4 + (tid >> 6)] = vs;
  __syncthreads();
  float var = (red[4] + red[5] + red[6] + red[7]) * (1.0f / D_);
  float r = rsqrtf(var + EPS_);
  float* orow = o + (size_t)row * D_;
  orow[tid]       = d0 * r * g[tid] + b[tid];
  orow[tid + 256] = d1 * r * g[tid + 256] + b[tid + 256];
}

// ---------------- elevation pre-scale ----------------
__global__ __launch_bounds__(256) void e2_kernel(
    const float* __restrict__ elev, const float* __restrict__ alpha,
    float* __restrict__ e2)
{
  int i = blockIdx.x * 256 + threadIdx.x;
  e2[i] = elev[i] * (alpha[0] * EL2_);
}

// ---------------- Weight split+transpose (lo optional) ----------------
__global__ __launch_bounds__(256) void wsplit_kernel(
    const float* __restrict__ W, u16* __restrict__ Thi, u16* __restrict__ Tlo,
    int K, int N)
{
  __shared__ float tile[64][65];
  int n0 = blockIdx.x * 64, k0 = blockIdx.y * 64;
  int c = threadIdx.x & 63, r4 = threadIdx.x >> 6;
  #pragma unroll
  for (int i = 0; i < 16; i++) {
    int r = r4 + i * 4;
    tile[r][c] = W[(size_t)(k0 + r) * N + n0 + c];
  }
  __syncthreads();
  #pragma unroll
  for (int i = 0; i < 16; i++) {
    int rn = r4 + i * 4;
    float v = tile[c][rn];
    size_t o = (size_t)(n0 + rn) * K + k0 + c;
    if (Tlo) {
      u16 h, l; bf16_split(v, h, l);
      Thi[o] = h; Tlo[o] = l;
    } else {
      Thi[o] = bf16_rne(v);
    }
  }
}

// ---------------- templated MFMA GEMM, XOR-swizzled LDS ----------------
// TERMS: 1 = A(bf16)*W(bf16), 2 = A(bf16)*(Whi+Wlo)
template<int ROWS>
__device__ __forceinline__ void stage_tileT(const u16* __restrict__ src, int ld,
                                            int r0, int k0, u16* lds, int lane, int wave)
{
  #pragma unroll
  for (int i = 0; i < ROWS / 64; i++) {
    int seg = wave * (ROWS / 64) + i;
    int chunk = seg * 64 + lane;
    int r = chunk >> 2;
    int c = (chunk & 3) ^ ((r >> 1) & 3);
    const u16* g = src + (size_t)(r0 + r) * ld + k0 + c * 8;
    __builtin_amdgcn_global_load_lds(GLB_AS(g), LDS_AS((char*)lds + seg * 1024), 16, 0, 0);
  }
}

template<int TBM, int TBN, int WR, int WC, int TERMS>
__global__ __launch_bounds__(256) void gemm_tpl(
    const float* __restrict__ Af, const u16* __restrict__ Ahi,
    const u16* __restrict__ Whi, const u16* __restrict__ Wlo,
    const float* __restrict__ bias, const float* __restrict__ res,
    float* __restrict__ Cf, u16* __restrict__ Ohi, u16* __restrict__ Olo,
    int M, int K, int N, int act, int qcols)
{
  constexpr int MF = TBM / (WR * 16);
  constexpr int NF = TBN / (WC * 16);
  __shared__ __align__(16) u16 As_hi[TBM * 32];
  __shared__ __align__(16) u16 Bs_hi[TBN * 32];
  __shared__ __align__(16) u16 Bs_lo[(TERMS >= 2) ? TBN * 32 : 8];

  int tid = threadIdx.x;
  int lane = tid & 63, wave = tid >> 6;
  int wr = wave / WC, wc = wave % WC;
  int ln = lane & 15, quad = lane >> 4;
  int m0 = blockIdx.y * TBM, n0 = blockIdx.x * TBN;

  ffrag acc[MF][NF] = {};

  for (int k0 = 0; k0 < K; k0 += 32) {
    if (Af) {
      if constexpr (TBM == 128) {
        int r = tid >> 1, hh = tid & 1;
        const float* g = Af + (size_t)(m0 + r) * K + k0 + hh * 16;
        float xs[16];
        *(float4*)(xs + 0)  = *(const float4*)(g + 0);
        *(float4*)(xs + 4)  = *(const float4*)(g + 4);
        *(float4*)(xs + 8)  = *(const float4*)(g + 8);
        *(float4*)(xs + 12) = *(const float4*)(g + 12);
        u32 ph[8];
        #pragma unroll
        for (int j = 0; j < 8; j++) ph[j] = pk_bf16(xs[2 * j], xs[2 * j + 1]);
        int f = (r >> 1) & 3;
        int c0 = (2 * hh) ^ f, c1 = (2 * hh + 1) ^ f;
        u16* da = As_hi + r * 32;
        *(uint4*)(da + c0 * 8) = make_uint4(ph[0], ph[1], ph[2], ph[3]);
        *(uint4*)(da + c1 * 8) = make_uint4(ph[4], ph[5], ph[6], ph[7]);
      } else {  // TBM == 64
        int r = tid >> 2, qd = tid & 3;
        const float* g = Af + (size_t)(m0 + r) * K + k0 + qd * 8;
        float xs[8];
        *(float4*)(xs + 0) = *(const float4*)(g + 0);
        *(float4*)(xs + 4) = *(const float4*)(g + 4);
        u32 ph[4];
        #pragma unroll
        for (int j = 0; j < 4; j++) ph[j] = pk_bf16(xs[2 * j], xs[2 * j + 1]);
        int c0 = qd ^ ((r >> 1) & 3);
        *(uint4*)(As_hi + r * 32 + c0 * 8) = make_uint4(ph[0], ph[1], ph[2], ph[3]);
      }
    } else {
      stage_tileT<TBM>(Ahi, K, m0, k0, As_hi, lane, wave);
    }
    stage_tileT<TBN>(Whi, K, n0, k0, Bs_hi, lane, wave);
    if constexpr (TERMS >= 2) stage_tileT<TBN>(Wlo, K, n0, k0, Bs_lo, lane, wave);
    __syncthreads();

    bfrag ah[MF], bh[NF], bl[NF];
    #pragma unroll
    for (int t = 0; t < MF; t++) {
      int Ra = wr * (TBM / WR) + t * 16 + ln;
      ah[t] = *(const bfrag*)(As_hi + Ra * 32 + ((quad ^ ((Ra >> 1) & 3)) * 8));
    }
    #pragma unroll
    for (int u = 0; u < NF; u++) {
      int Rb = wc * (TBN / WC) + u * 16 + ln;
      int bo = Rb * 32 + ((quad ^ ((Rb >> 1) & 3)) * 8);
      bh[u] = *(const bfrag*)(Bs_hi + bo);
      if constexpr (TERMS >= 2) bl[u] = *(const bfrag*)(Bs_lo + bo);
    }
    #pragma unroll
    for (int ti = 0; ti < MF; ti++) {
      #pragma unroll
      for (int tj = 0; tj < NF; tj++) {
        acc[ti][tj] = __builtin_amdgcn_mfma_f32_16x16x32_bf16(ah[ti], bh[tj], acc[ti][tj], 0, 0, 0);
        if constexpr (TERMS >= 2)
          acc[ti][tj] = __builtin_amdgcn_mfma_f32_16x16x32_bf16(ah[ti], bl[tj], acc[ti][tj], 0, 0, 0);
      }
    }
    __syncthreads();
  }

  #pragma unroll
  for (int tj = 0; tj < NF; tj++) {
    int col = n0 + wc * (TBN / WC) + tj * 16 + ln;
    float bv = bias ? bias[col] : 0.f;
    float cs = (col < qcols) ? QSCALE_ : 1.0f;
    bool store_lo = (col < qcols);
    #pragma unroll
    for (int ti = 0; ti < MF; ti++) {
      int rw = m0 + wr * (TBM / WR) + ti * 16 + quad * 4;
      #pragma unroll
      for (int r = 0; r < 4; r++) {
        float y = acc[ti][tj][r] + bv;
        if (act) y = 0.5f * y * (1.f + erff(y * 0.70710678118654752f));
        if (res) y += res[(size_t)(rw + r) * N + col];
        if (Cf) Cf[(size_t)(rw + r) * N + col] = y;
        if (Ohi) {
          y *= cs;
          if (Olo && store_lo) {
            u16 hh, ll; bf16_split(y, hh, ll);
            Ohi[(size_t)(rw + r) * N + col] = hh;
            Olo[(size_t)(rw + r) * N + col] = ll;
          } else {
            Ohi[(size_t)(rw + r) * N + col] = bf16_rne(y);
          }
        }
      }
    }
  }
}

// ---------------- V transpose (hi only) ----------------
__global__ __launch_bounds__(256) void vtrans_kernel(
    const u16* __restrict__ qh, u16* __restrict__ vth)
{
  __shared__ u16 Th[64][72];
  int b = blockIdx.z, h = blockIdx.y, n0 = blockIdx.x * 64;
  int t = threadIdx.x;
  int nr = t >> 2, ds = (t & 3) * 16;
  size_t src = ((size_t)(b * N_ + n0 + nr)) * 1536 + 1024 + h * 64 + ds;
  *(uint4*)&Th[nr][ds]     = *(const uint4*)(qh + src);
  *(uint4*)&Th[nr][ds + 8] = *(const uint4*)(qh + src + 8);
  __syncthreads();
  int dr = t >> 2, ns = (t & 3) * 16;
  u16 oh[16];
  #pragma unroll
  for (int j = 0; j < 16; j++) oh[j] = Th[ns + j][dr];
  size_t dst = ((size_t)((b * H_ + h) * 64 + dr)) * N_ + n0 + ns;
  *(uint4*)(vth + dst)     = *(uint4*)(oh);
  *(uint4*)(vth + dst + 8) = *(uint4*)(oh + 8);
}

// ---------------- MFMA flash attention (S-transposed, K/V single bf16) ----------------
__device__ __forceinline__ void stage_tile64(const u16* __restrict__ gbase, size_t rstride,
                                             u16* lds, int wave, int lane)
{
  #pragma unroll
  for (int i = 0; i < 2; i++) {
    int seg = wave * 2 + i;
    int chunk = seg * 64 + lane;            // phys chunk 0..511
    int ch = chunk >> 8;                    // 32-elem half
    int pc = chunk & 255;
    int r = pc >> 2;
    int q = (pc & 3) ^ ((r >> 1) & 3);
    const u16* g = gbase + (size_t)r * rstride + ch * 32 + q * 8;
    __builtin_amdgcn_global_load_lds(GLB_AS(g), LDS_AS((char*)lds + seg * 1024), 16, 0, 0);
  }
}

__device__ __forceinline__ int frag_off(int c, int R, int quad) {
  return c * 2048 + R * 32 + ((quad ^ ((R >> 1) & 3)) * 8);   // u16 units
}

__global__ __launch_bounds__(256) void attn_mfma_kernel(
    const u16* __restrict__ qkh, const u16* __restrict__ qkl,
    const u16* __restrict__ vth,
    const float* __restrict__ e2, float* __restrict__ out)
{
  __shared__ __align__(16) u16 Kh[4096];
  __shared__ __align__(16) u16 Vh[4096];
  __shared__ __align__(16) u16 Pw[4][16][72];

  int b = blockIdx.z, h = blockIdx.y;
  int q0 = blockIdx.x * 64;
  int tid = threadIdx.x;
  int lane = tid & 63, wq = tid >> 6;
  int ln = lane & 15, quad = lane >> 4;

  // ---- stage Q: hi -> Kh, lo -> Vh ----
  const u16* qb_h = qkh + ((size_t)(b * N_ + q0)) * 1536 + h * 64;
  const u16* qb_l = qkl + ((size_t)(b * N_ + q0)) * 1536 + h * 64;
  stage_tile64(qb_h, 1536, Kh, wq, lane);
  stage_tile64(qb_l, 1536, Vh, wq, lane);
  __syncthreads();

  bfrag qfh[2], qfl[2];
  #pragma unroll
  for (int c = 0; c < 2; c++) {
    int off = frag_off(c, wq * 16 + ln, quad);
    qfh[c] = *(const bfrag*)(Kh + off);
    qfl[c] = *(const bfrag*)(Vh + off);
  }
  __syncthreads();

  float e2q = e2[b * N_ + q0 + wq * 16 + ln];
  float m_i = -3.0e38f, l_i = 0.f;
  ffrag O[4] = {};

  const u16* kp = qkh + (size_t)b * N_ * 1536 + 512 + h * 64;
  const u16* vp = vth + (size_t)(b * H_ + h) * 64 * N_;
  const float* ep = e2 + b * N_;

  for (int k0 = 0; k0 < N_; k0 += 64) {
    stage_tile64(kp, 1536, Kh, wq, lane);
    stage_tile64(vp, N_, Vh, wq, lane);
    kp += (size_t)64 * 1536;
    vp += 64;
    __syncthreads();

    // ---- S^T = K (Qh+Ql)^T ----
    ffrag S[4];
    #pragma unroll
    for (int kt = 0; kt < 4; kt++) {
      ffrag s = {0.f, 0.f, 0.f, 0.f};
      #pragma unroll
      for (int c = 0; c < 2; c++) {
        bfrag kf = *(const bfrag*)(Kh + frag_off(c, kt * 16 + ln, quad));
        s = __builtin_amdgcn_mfma_f32_16x16x32_bf16(kf, qfh[c], s, 0, 0, 0);
        s = __builtin_amdgcn_mfma_f32_16x16x32_bf16(kf, qfl[c], s, 0, 0, 0);
      }
      S[kt] = s;
    }

    // ---- bias + online softmax ----
    float4 ek[4];
    #pragma unroll
    for (int kt = 0; kt < 4; kt++)
      ek[kt] = *(const float4*)&ep[k0 + kt * 16 + quad * 4];

    float p[4][4];
    float mx = -3.0e38f;
    #pragma unroll
    for (int kt = 0; kt < 4; kt++) {
      #pragma unroll
      for (int r = 0; r < 4; r++) {
        float d = (&ek[kt].x)[r] - e2q;
        d = fminf(fmaxf(d, 0.f), C2_);
        float sv = S[kt][r] - d;
        p[kt][r] = sv;
        mx = fmaxf(mx, sv);
      }
    }
    mx = fmaxf(mx, __shfl_xor(mx, 16, 64));
    mx = fmaxf(mx, __shfl_xor(mx, 32, 64));
    float mnew = fmaxf(m_i, mx);
    float corr = EXP2(m_i - mnew);
    float ps = 0.f;
    #pragma unroll
    for (int kt = 0; kt < 4; kt++) {
      #pragma unroll
      for (int r = 0; r < 4; r++) {
        float pv = EXP2(p[kt][r] - mnew);
        p[kt][r] = pv;
        ps += pv;
      }
    }
    ps += __shfl_xor(ps, 16, 64);
    ps += __shfl_xor(ps, 32, 64);
    m_i = mnew;
    l_i = l_i * corr + ps;
    #pragma unroll
    for (int dt = 0; dt < 4; dt++) O[dt] *= corr;

    // write P^T bf16 (v_cvt_pk when available)
    #pragma unroll
    for (int kt = 0; kt < 4; kt++) {
      u32 w0 = pk_bf16(p[kt][0], p[kt][1]);
      u32 w1 = pk_bf16(p[kt][2], p[kt][3]);
      *(uint2*)&Pw[wq][ln][kt * 16 + quad * 4] = make_uint2(w0, w1);
    }

    bfrag pf[2];
    #pragma unroll
    for (int c = 0; c < 2; c++)
      pf[c] = *(const bfrag*)&Pw[wq][ln][c * 32 + quad * 8];

    // ---- O^T += Vt P^T ----
    #pragma unroll
    for (int dt = 0; dt < 4; dt++) {
      ffrag o = O[dt];
      #pragma unroll
      for (int c = 0; c < 2; c++) {
        bfrag vf = *(const bfrag*)(Vh + frag_off(c, dt * 16 + ln, quad));
        o = __builtin_amdgcn_mfma_f32_16x16x32_bf16(vf, pf[c], o, 0, 0, 0);
      }
      O[dt] = o;
    }
    __syncthreads();
  }

  float inv = 1.0f / l_i;
  int row = q0 + wq * 16 + ln;
  #pragma unroll
  for (int dt = 0; dt < 4; dt++) {
    float4 v = make_float4(O[dt][0] * inv, O[dt][1] * inv,
                           O[dt][2] * inv, O[dt][3] * inv);
    *(float4*)&out[((size_t)(b * N_ + row)) * D_ + h * 64 + dt * 16 + quad * 4] = v;
  }
}

extern "C" void kernel_launch(void* const* d_in, const int* in_sizes, int n_in,
                              void* d_out, int out_size, void* d_ws, size_t ws_size,
                              hipStream_t stream) {
  const float* x      = (const float*)d_in[0];
  const float* elev   = (const float*)d_in[1];
  const float* ln1_g  = (const float*)d_in[2];
  const float* ln1_b  = (const float*)d_in[3];
  const float* qkv_w  = (const float*)d_in[4];
  const float* alpha  = (const float*)d_in[5];
  const float* proj_w = (const float*)d_in[6];
  const float* proj_b = (const float*)d_in[7];
  const float* ln2_g  = (const float*)d_in[8];
  const float* ln2_b  = (const float*)d_in[9];
  const float* fc1_w  = (const float*)d_in[10];
  const float* fc1_b  = (const float*)d_in[11];
  const float* fc2_w  = (const float*)d_in[12];
  const float* fc2_b  = (const float*)d_in[13];
  float* out = (float*)d_out;

  const size_t HBf   = (size_t)B_ * N_ * D_;        // 4,194,304
  const size_t QKVE  = (size_t)B_ * N_ * 3 * D_;    // 12,582,912
  const size_t MLPE  = (size_t)B_ * N_ * MLP_H_;    // 16,777,216

  char* p = (char*)d_ws;
  float* buf0 = (float*)p;                 p += HBf * 4;
  char* region = p;                        p += QKVE * 4;   // qkvh+qkvl, reused as mlp_hi
  u16* qkvh   = (u16*)region;
  u16* qkvl   = (u16*)(region + QKVE * 2);
  u16* mlp_hi = (u16*)region;
  u16* vth  = (u16*)p;  p += HBf * 2;
  float* xres = (float*)p;                 p += HBf * 4;
  u16* qw_hi = (u16*)p;  p += (size_t)D_ * 3 * D_ * 2;
  u16* qw_lo = (u16*)p;  p += (size_t)D_ * 3 * D_ * 2;
  u16* pw_hi = (u16*)p;  p += (size_t)D_ * D_ * 2;
  u16* f1_hi = (u16*)p;  p += (size_t)D_ * MLP_H_ * 2;
  u16* f2_hi = (u16*)p;  p += (size_t)MLP_H_ * D_ * 2;
  float* e2  = (float*)p; p += (size_t)B_ * N_ * 4;

  const int rows = B_ * N_;   // 8192

  wsplit_kernel<<<dim3(3 * D_ / 64, D_ / 64), 256, 0, stream>>>(qkv_w, qw_hi, qw_lo, D_, 3 * D_);
  wsplit_kernel<<<dim3(D_ / 64, D_ / 64), 256, 0, stream>>>(proj_w, pw_hi, nullptr, D_, D_);
  wsplit_kernel<<<dim3(MLP_H_ / 64, D_ / 64), 256, 0, stream>>>(fc1_w, f1_hi, nullptr, D_, MLP_H_);
  wsplit_kernel<<<dim3(D_ / 64, MLP_H_ / 64), 256, 0, stream>>>(fc2_w, f2_hi, nullptr, MLP_H_, D_);
  e2_kernel<<<rows / 256, 256, 0, stream>>>(elev, alpha, e2);

  // LN1 -> buf0
  ln_kernel<<<rows, 256, 0, stream>>>(x, ln1_g, ln1_b, buf0);
  // qkv = h @ qkv_w : 2-term (A single, W split); Q cols scaled+split, K/V hi-only
  gemm_tpl<128, 128, 2, 2, 2><<<dim3(1536 / 128, rows / 128), 256, 0, stream>>>(
      buf0, nullptr, qw_hi, qw_lo, nullptr, nullptr,
      nullptr, qkvh, qkvl, rows, D_, 1536, 0, D_);
  // V transpose (hi) -> [B,H,HD,N]
  vtrans_kernel<<<dim3(N_ / 64, H_, B_), 256, 0, stream>>>(qkvh, vth);
  // attention -> buf0
  attn_mfma_kernel<<<dim3(N_ / 64, H_, B_), 256, 0, stream>>>(
      qkvh, qkvl, vth, e2, buf0);
  // xres = x + attn @ proj_w + proj_b : single-bf16, 64x128 tile (512 blocks)
  gemm_tpl<64, 128, 1, 4, 1><<<dim3(D_ / 128, rows / 64), 256, 0, stream>>>(
      buf0, nullptr, pw_hi, nullptr, proj_b, x,
      xres, nullptr, nullptr, rows, D_, D_, 0, 0);
  // LN2 -> buf0
  ln_kernel<<<rows, 256, 0, stream>>>(xres, ln2_g, ln2_b, buf0);
  // mlp_hi = bf16(gelu(h2 @ fc1 + b1)) : single-bf16
  gemm_tpl<128, 128, 2, 2, 1><<<dim3(MLP_H_ / 128, rows / 128), 256, 0, stream>>>(
      buf0, nullptr, f1_hi, nullptr, fc1_b, nullptr,
      nullptr, mlp_hi, nullptr, rows, D_, MLP_H_, 1, 0);
  // out = xres + mlp @ fc2 + b2 : single-bf16, 64x128 tile
  gemm_tpl<64, 128, 1, 4, 1><<<dim3(D_ / 128, rows / 64), 256, 0, stream>>>(
      nullptr, mlp_hi, f2_hi, nullptr, fc2_b, xres,
      out, nullptr, nullptr, rows, MLP_H_, D_, 0, 0);
}

// Round 7
// 427.009 us; speedup vs baseline: 3.6937x; 1.0643x over previous
//
#include <hip/hip_runtime.h>
#include <math.h>

typedef unsigned short u16;
typedef unsigned int u32;

#define B_ 4
#define N_ 2048
#define D_ 512
#define H_ 8
#define HD_ 64
#define MLP_H_ 2048
#define EPS_ 1e-5f
#define C2_ 14.426950408889634f          // 10/ln2
#define QSCALE_ 0.1803368801111204f     // 0.125/ln2
#define EL2_ 0.0014426950408889634f     // 1/(1000*ln2)

// ---------- fast exp2 ----------
#if __has_builtin(__builtin_amdgcn_exp2f)
#define EXP2(x) __builtin_amdgcn_exp2f(x)
#else
#define EXP2(x) exp2f(x)
#endif

// ---------- bf16 helpers ----------
__device__ __forceinline__ u16 bf16_rne(float x) {
  u32 u = __float_as_uint(x);
  u32 r = (u + 0x7FFFu + ((u >> 16) & 1u)) >> 16;
  return (u16)r;
}
#if __has_builtin(__builtin_amdgcn_cvt_pk_bf16_f32)
typedef __bf16 bf2_t __attribute__((ext_vector_type(2)));
__device__ __forceinline__ u32 pk_bf16(float a, float b) {
  bf2_t v = __builtin_amdgcn_cvt_pk_bf16_f32(a, b);
  u32 r; __builtin_memcpy(&r, &v, 4); return r;
}
#else
__device__ __forceinline__ u32 pk_bf16(float a, float b) {
  return (u32)bf16_rne(a) | ((u32)bf16_rne(b) << 16);
}
#endif
__device__ __forceinline__ void bf16_split(float x, u16& h, u16& l) {
  h = bf16_rne(x);
  float hf = __uint_as_float(((u32)h) << 16);
  l = bf16_rne(x - hf);
}

typedef __attribute__((ext_vector_type(8))) short bfrag;
typedef __attribute__((ext_vector_type(4))) float ffrag;

#define LDS_AS(p) ((__attribute__((address_space(3))) void*)(p))
#define GLB_AS(p) ((const __attribute__((address_space(1))) void*)(p))

// ---------------- LayerNorm -> bf16 out ----------------
__global__ __launch_bounds__(256) void ln_kernel(
    const float* __restrict__ x, const float* __restrict__ g,
    const float* __restrict__ b, u16* __restrict__ o)
{
  __shared__ float red[8];
  int row = blockIdx.x;
  int tid = threadIdx.x;
  const float* xr = x + (size_t)row * D_;
  float v0 = xr[tid], v1 = xr[tid + 256];
  float s = v0 + v1;
  #pragma unroll
  for (int off = 32; off > 0; off >>= 1) s += __shfl_xor(s, off, 64);
  if ((tid & 63) == 0) red[tid >> 6] = s;
  __syncthreads();
  float mean = (red[0] + red[1] + red[2] + red[3]) * (1.0f / D_);
  float d0 = v0 - mean, d1 = v1 - mean;
  float vs = d0 * d0 + d1 * d1;
  #pragma unroll
  for (int off = 32; off > 0; off >>= 1) vs += __shfl_xor(vs, off, 64);
  if ((tid & 63) == 0) red[4 + (tid >> 6)] = vs;
  __syncthreads();
  float var = (red[4] + red[5] + red[6] + red[7]) * (1.0f / D_);
  float r = rsqrtf(var + EPS_);
  u16* orow = o + (size_t)row * D_;
  orow[tid]       = bf16_rne(d0 * r * g[tid] + b[tid]);
  orow[tid + 256] = bf16_rne(d1 * r * g[tid + 256] + b[tid + 256]);
}

// ---------------- elevation pre-scale ----------------
__global__ __launch_bounds__(256) void e2_kernel(
    const float* __restrict__ elev, const float* __restrict__ alpha,
    float* __restrict__ e2)
{
  int i = blockIdx.x * 256 + threadIdx.x;
  e2[i] = elev[i] * (alpha[0] * EL2_);
}

// ---------------- Weight split+transpose (lo optional) ----------------
__global__ __launch_bounds__(256) void wsplit_kernel(
    const float* __restrict__ W, u16* __restrict__ Thi, u16* __restrict__ Tlo,
    int K, int N)
{
  __shared__ float tile[64][65];
  int n0 = blockIdx.x * 64, k0 = blockIdx.y * 64;
  int c = threadIdx.x & 63, r4 = threadIdx.x >> 6;
  #pragma unroll
  for (int i = 0; i < 16; i++) {
    int r = r4 + i * 4;
    tile[r][c] = W[(size_t)(k0 + r) * N + n0 + c];
  }
  __syncthreads();
  #pragma unroll
  for (int i = 0; i < 16; i++) {
    int rn = r4 + i * 4;
    float v = tile[c][rn];
    size_t o = (size_t)(n0 + rn) * K + k0 + c;
    if (Tlo) {
      u16 h, l; bf16_split(v, h, l);
      Thi[o] = h; Tlo[o] = l;
    } else {
      Thi[o] = bf16_rne(v);
    }
  }
}

// ---------------- MFMA GEMM: BK=64 (two swizzled 32-k sub-tiles) ----------------
// All operands bf16 in global memory, [rows, K] k-contiguous.
template<int ROWS>
__device__ __forceinline__ void stage32(const u16* __restrict__ src, int ld,
                                        int r0, int k0, u16* lds, int lane, int wave)
{
  #pragma unroll
  for (int i = 0; i < ROWS / 64; i++) {
    int seg = wave * (ROWS / 64) + i;
    int chunk = seg * 64 + lane;
    int r = chunk >> 2;
    int c = (chunk & 3) ^ ((r >> 1) & 3);
    const u16* g = src + (size_t)(r0 + r) * ld + k0 + c * 8;
    __builtin_amdgcn_global_load_lds(GLB_AS(g), LDS_AS((char*)lds + seg * 1024), 16, 0, 0);
  }
}

__device__ __forceinline__ int swz_off(int R, int quad) {
  return R * 32 + ((quad ^ ((R >> 1) & 3)) * 8);   // u16 units within a 32-k tile
}

template<int TBM, int TBN, int WR, int WC, int TERMS>
__global__ __launch_bounds__(256) void gemm_tpl(
    const u16* __restrict__ Ahi,
    const u16* __restrict__ Whi, const u16* __restrict__ Wlo,
    const float* __restrict__ bias, const float* __restrict__ res,
    float* __restrict__ Cf, u16* __restrict__ Ohi, u16* __restrict__ Olo,
    int M, int K, int N, int act, int qcols)
{
  constexpr int MF = TBM / (WR * 16);
  constexpr int NF = TBN / (WC * 16);
  __shared__ __align__(16) u16 As[2][TBM * 32];
  __shared__ __align__(16) u16 Bh[2][TBN * 32];
  __shared__ __align__(16) u16 Bl[(TERMS >= 2) ? 2 : 1][(TERMS >= 2) ? TBN * 32 : 8];

  int tid = threadIdx.x;
  int lane = tid & 63, wave = tid >> 6;
  int wr = wave / WC, wc = wave % WC;
  int ln = lane & 15, quad = lane >> 4;
  int m0 = blockIdx.y * TBM, n0 = blockIdx.x * TBN;

  ffrag acc[MF][NF] = {};

  for (int k0 = 0; k0 < K; k0 += 64) {
    stage32<TBM>(Ahi, K, m0, k0,      As[0], lane, wave);
    stage32<TBM>(Ahi, K, m0, k0 + 32, As[1], lane, wave);
    stage32<TBN>(Whi, K, n0, k0,      Bh[0], lane, wave);
    stage32<TBN>(Whi, K, n0, k0 + 32, Bh[1], lane, wave);
    if constexpr (TERMS >= 2) {
      stage32<TBN>(Wlo, K, n0, k0,      Bl[0], lane, wave);
      stage32<TBN>(Wlo, K, n0, k0 + 32, Bl[1], lane, wave);
    }
    __syncthreads();

    #pragma unroll
    for (int hf = 0; hf < 2; hf++) {
      bfrag ah[MF], bh[NF], bl[NF];
      #pragma unroll
      for (int t = 0; t < MF; t++)
        ah[t] = *(const bfrag*)(As[hf] + swz_off(wr * (TBM / WR) + t * 16 + ln, quad));
      #pragma unroll
      for (int u = 0; u < NF; u++) {
        int off = swz_off(wc * (TBN / WC) + u * 16 + ln, quad);
        bh[u] = *(const bfrag*)(Bh[hf] + off);
        if constexpr (TERMS >= 2) bl[u] = *(const bfrag*)(Bl[hf] + off);
      }
      #pragma unroll
      for (int ti = 0; ti < MF; ti++) {
        #pragma unroll
        for (int tj = 0; tj < NF; tj++) {
          acc[ti][tj] = __builtin_amdgcn_mfma_f32_16x16x32_bf16(ah[ti], bh[tj], acc[ti][tj], 0, 0, 0);
          if constexpr (TERMS >= 2)
            acc[ti][tj] = __builtin_amdgcn_mfma_f32_16x16x32_bf16(ah[ti], bl[tj], acc[ti][tj], 0, 0, 0);
        }
      }
    }
    __syncthreads();
  }

  #pragma unroll
  for (int tj = 0; tj < NF; tj++) {
    int col = n0 + wc * (TBN / WC) + tj * 16 + ln;
    float bv = bias ? bias[col] : 0.f;
    float cs = (col < qcols) ? QSCALE_ : 1.0f;
    bool store_lo = (col < qcols);
    #pragma unroll
    for (int ti = 0; ti < MF; ti++) {
      int rw = m0 + wr * (TBM / WR) + ti * 16 + quad * 4;
      #pragma unroll
      for (int r = 0; r < 4; r++) {
        float y = acc[ti][tj][r] + bv;
        if (act) y = 0.5f * y * (1.f + erff(y * 0.70710678118654752f));
        if (res) y += res[(size_t)(rw + r) * N + col];
        if (Cf) Cf[(size_t)(rw + r) * N + col] = y;
        if (Ohi) {
          y *= cs;
          if (Olo && store_lo) {
            u16 hh, ll; bf16_split(y, hh, ll);
            Ohi[(size_t)(rw + r) * N + col] = hh;
            Olo[(size_t)(rw + r) * N + col] = ll;
          } else {
            Ohi[(size_t)(rw + r) * N + col] = bf16_rne(y);
          }
        }
      }
    }
  }
}

// ---------------- V transpose (hi only) ----------------
__global__ __launch_bounds__(256) void vtrans_kernel(
    const u16* __restrict__ qh, u16* __restrict__ vth)
{
  __shared__ u16 Th[64][72];
  int b = blockIdx.z, h = blockIdx.y, n0 = blockIdx.x * 64;
  int t = threadIdx.x;
  int nr = t >> 2, ds = (t & 3) * 16;
  size_t src = ((size_t)(b * N_ + n0 + nr)) * 1536 + 1024 + h * 64 + ds;
  *(uint4*)&Th[nr][ds]     = *(const uint4*)(qh + src);
  *(uint4*)&Th[nr][ds + 8] = *(const uint4*)(qh + src + 8);
  __syncthreads();
  int dr = t >> 2, ns = (t & 3) * 16;
  u16 oh[16];
  #pragma unroll
  for (int j = 0; j < 16; j++) oh[j] = Th[ns + j][dr];
  size_t dst = ((size_t)((b * H_ + h) * 64 + dr)) * N_ + n0 + ns;
  *(uint4*)(vth + dst)     = *(uint4*)(oh);
  *(uint4*)(vth + dst + 8) = *(uint4*)(oh + 8);
}

// ---------------- MFMA flash attention (S-transposed, K/V single bf16) ----------------
__device__ __forceinline__ void stage_tile64(const u16* __restrict__ gbase, size_t rstride,
                                             u16* lds, int wave, int lane)
{
  #pragma unroll
  for (int i = 0; i < 2; i++) {
    int seg = wave * 2 + i;
    int chunk = seg * 64 + lane;            // phys chunk 0..511
    int ch = chunk >> 8;                    // 32-elem half
    int pc = chunk & 255;
    int r = pc >> 2;
    int q = (pc & 3) ^ ((r >> 1) & 3);
    const u16* g = gbase + (size_t)r * rstride + ch * 32 + q * 8;
    __builtin_amdgcn_global_load_lds(GLB_AS(g), LDS_AS((char*)lds + seg * 1024), 16, 0, 0);
  }
}

__device__ __forceinline__ int frag_off(int c, int R, int quad) {
  return c * 2048 + R * 32 + ((quad ^ ((R >> 1) & 3)) * 8);   // u16 units
}

__global__ __launch_bounds__(256) void attn_mfma_kernel(
    const u16* __restrict__ qkh, const u16* __restrict__ qkl,
    const u16* __restrict__ vth,
    const float* __restrict__ e2, u16* __restrict__ outb)
{
  __shared__ __align__(16) u16 Kh[4096];
  __shared__ __align__(16) u16 Vh[4096];
  __shared__ __align__(16) u16 Pw[4][16][72];

  int b = blockIdx.z, h = blockIdx.y;
  int q0 = blockIdx.x * 64;
  int tid = threadIdx.x;
  int lane = tid & 63, wq = tid >> 6;
  int ln = lane & 15, quad = lane >> 4;

  // ---- stage Q: hi -> Kh, lo -> Vh ----
  const u16* qb_h = qkh + ((size_t)(b * N_ + q0)) * 1536 + h * 64;
  const u16* qb_l = qkl + ((size_t)(b * N_ + q0)) * 1536 + h * 64;
  stage_tile64(qb_h, 1536, Kh, wq, lane);
  stage_tile64(qb_l, 1536, Vh, wq, lane);
  __syncthreads();

  bfrag qfh[2], qfl[2];
  #pragma unroll
  for (int c = 0; c < 2; c++) {
    int off = frag_off(c, wq * 16 + ln, quad);
    qfh[c] = *(const bfrag*)(Kh + off);
    qfl[c] = *(const bfrag*)(Vh + off);
  }
  __syncthreads();

  float e2q = e2[b * N_ + q0 + wq * 16 + ln];
  float m_i = -3.0e38f, l_i = 0.f;
  ffrag O[4] = {};

  const u16* kp = qkh + (size_t)b * N_ * 1536 + 512 + h * 64;
  const u16* vp = vth + (size_t)(b * H_ + h) * 64 * N_;
  const float* ep = e2 + b * N_;

  for (int k0 = 0; k0 < N_; k0 += 64) {
    stage_tile64(kp, 1536, Kh, wq, lane);
    stage_tile64(vp, N_, Vh, wq, lane);
    kp += (size_t)64 * 1536;
    vp += 64;
    __syncthreads();

    // ---- S^T = K (Qh+Ql)^T ----
    ffrag S[4];
    #pragma unroll
    for (int kt = 0; kt < 4; kt++) {
      ffrag s = {0.f, 0.f, 0.f, 0.f};
      #pragma unroll
      for (int c = 0; c < 2; c++) {
        bfrag kf = *(const bfrag*)(Kh + frag_off(c, kt * 16 + ln, quad));
        s = __builtin_amdgcn_mfma_f32_16x16x32_bf16(kf, qfh[c], s, 0, 0, 0);
        s = __builtin_amdgcn_mfma_f32_16x16x32_bf16(kf, qfl[c], s, 0, 0, 0);
      }
      S[kt] = s;
    }

    // ---- bias + online softmax ----
    float4 ek[4];
    #pragma unroll
    for (int kt = 0; kt < 4; kt++)
      ek[kt] = *(const float4*)&ep[k0 + kt * 16 + quad * 4];

    float p[4][4];
    float mx = -3.0e38f;
    #pragma unroll
    for (int kt = 0; kt < 4; kt++) {
      #pragma unroll
      for (int r = 0; r < 4; r++) {
        float d = (&ek[kt].x)[r] - e2q;
        d = fminf(fmaxf(d, 0.f), C2_);
        float sv = S[kt][r] - d;
        p[kt][r] = sv;
        mx = fmaxf(mx, sv);
      }
    }
    mx = fmaxf(mx, __shfl_xor(mx, 16, 64));
    mx = fmaxf(mx, __shfl_xor(mx, 32, 64));
    float mnew = fmaxf(m_i, mx);
    float corr = EXP2(m_i - mnew);
    float ps = 0.f;
    #pragma unroll
    for (int kt = 0; kt < 4; kt++) {
      #pragma unroll
      for (int r = 0; r < 4; r++) {
        float pv = EXP2(p[kt][r] - mnew);
        p[kt][r] = pv;
        ps += pv;
      }
    }
    ps += __shfl_xor(ps, 16, 64);
    ps += __shfl_xor(ps, 32, 64);
    m_i = mnew;
    l_i = l_i * corr + ps;
    #pragma unroll
    for (int dt = 0; dt < 4; dt++) O[dt] *= corr;

    // write P^T bf16
    #pragma unroll
    for (int kt = 0; kt < 4; kt++) {
      u32 w0 = pk_bf16(p[kt][0], p[kt][1]);
      u32 w1 = pk_bf16(p[kt][2], p[kt][3]);
      *(uint2*)&Pw[wq][ln][kt * 16 + quad * 4] = make_uint2(w0, w1);
    }

    bfrag pf[2];
    #pragma unroll
    for (int c = 0; c < 2; c++)
      pf[c] = *(const bfrag*)&Pw[wq][ln][c * 32 + quad * 8];

    // ---- O^T += Vt P^T ----
    #pragma unroll
    for (int dt = 0; dt < 4; dt++) {
      ffrag o = O[dt];
      #pragma unroll
      for (int c = 0; c < 2; c++) {
        bfrag vf = *(const bfrag*)(Vh + frag_off(c, dt * 16 + ln, quad));
        o = __builtin_amdgcn_mfma_f32_16x16x32_bf16(vf, pf[c], o, 0, 0, 0);
      }
      O[dt] = o;
    }
    __syncthreads();
  }

  float inv = 1.0f / l_i;
  int row = q0 + wq * 16 + ln;
  #pragma unroll
  for (int dt = 0; dt < 4; dt++) {
    u32 w0 = pk_bf16(O[dt][0] * inv, O[dt][1] * inv);
    u32 w1 = pk_bf16(O[dt][2] * inv, O[dt][3] * inv);
    *(uint2*)&outb[((size_t)(b * N_ + row)) * D_ + h * 64 + dt * 16 + quad * 4] =
        make_uint2(w0, w1);
  }
}

extern "C" void kernel_launch(void* const* d_in, const int* in_sizes, int n_in,
                              void* d_out, int out_size, void* d_ws, size_t ws_size,
                              hipStream_t stream) {
  const float* x      = (const float*)d_in[0];
  const float* elev   = (const float*)d_in[1];
  const float* ln1_g  = (const float*)d_in[2];
  const float* ln1_b  = (const float*)d_in[3];
  const float* qkv_w  = (const float*)d_in[4];
  const float* alpha  = (const float*)d_in[5];
  const float* proj_w = (const float*)d_in[6];
  const float* proj_b = (const float*)d_in[7];
  const float* ln2_g  = (const float*)d_in[8];
  const float* ln2_b  = (const float*)d_in[9];
  const float* fc1_w  = (const float*)d_in[10];
  const float* fc1_b  = (const float*)d_in[11];
  const float* fc2_w  = (const float*)d_in[12];
  const float* fc2_b  = (const float*)d_in[13];
  float* out = (float*)d_out;

  const size_t HBf   = (size_t)B_ * N_ * D_;        // 4,194,304
  const size_t QKVE  = (size_t)B_ * N_ * 3 * D_;    // 12,582,912
  const size_t MLPE  = (size_t)B_ * N_ * MLP_H_;    // 16,777,216

  char* p = (char*)d_ws;
  u16* abuf = (u16*)p;                     p += HBf * 2;    // LN1 out -> attn out -> LN2 out
  char* region = p;                        p += QKVE * 4;   // qkvh+qkvl | mlp_hi
  u16* qkvh   = (u16*)region;
  u16* qkvl   = (u16*)(region + QKVE * 2);
  u16* mlp_hi = (u16*)region;
  u16* vth  = (u16*)p;  p += HBf * 2;
  float* xres = (float*)p;                 p += HBf * 4;
  u16* qw_hi = (u16*)p;  p += (size_t)D_ * 3 * D_ * 2;
  u16* qw_lo = (u16*)p;  p += (size_t)D_ * 3 * D_ * 2;
  u16* pw_hi = (u16*)p;  p += (size_t)D_ * D_ * 2;
  u16* f1_hi = (u16*)p;  p += (size_t)D_ * MLP_H_ * 2;
  u16* f2_hi = (u16*)p;  p += (size_t)MLP_H_ * D_ * 2;
  float* e2  = (float*)p; p += (size_t)B_ * N_ * 4;

  const int rows = B_ * N_;   // 8192

  wsplit_kernel<<<dim3(3 * D_ / 64, D_ / 64), 256, 0, stream>>>(qkv_w, qw_hi, qw_lo, D_, 3 * D_);
  wsplit_kernel<<<dim3(D_ / 64, D_ / 64), 256, 0, stream>>>(proj_w, pw_hi, nullptr, D_, D_);
  wsplit_kernel<<<dim3(MLP_H_ / 64, D_ / 64), 256, 0, stream>>>(fc1_w, f1_hi, nullptr, D_, MLP_H_);
  wsplit_kernel<<<dim3(D_ / 64, MLP_H_ / 64), 256, 0, stream>>>(fc2_w, f2_hi, nullptr, MLP_H_, D_);
  e2_kernel<<<rows / 256, 256, 0, stream>>>(elev, alpha, e2);

  // LN1 -> abuf (bf16)
  ln_kernel<<<rows, 256, 0, stream>>>(x, ln1_g, ln1_b, abuf);
  // qkv = h @ qkv_w : 2-term (W split); Q cols scaled+split, K/V hi-only
  gemm_tpl<128, 128, 2, 2, 2><<<dim3(1536 / 128, rows / 128), 256, 0, stream>>>(
      abuf, qw_hi, qw_lo, nullptr, nullptr,
      nullptr, qkvh, qkvl, rows, D_, 1536, 0, D_);
  // V transpose (hi) -> [B,H,HD,N]
  vtrans_kernel<<<dim3(N_ / 64, H_, B_), 256, 0, stream>>>(qkvh, vth);
  // attention -> abuf (bf16)
  attn_mfma_kernel<<<dim3(N_ / 64, H_, B_), 256, 0, stream>>>(
      qkvh, qkvl, vth, e2, abuf);
  // xres = x + attn @ proj_w + proj_b (f32)
  gemm_tpl<64, 128, 1, 4, 1><<<dim3(D_ / 128, rows / 64), 256, 0, stream>>>(
      abuf, pw_hi, nullptr, proj_b, x,
      xres, nullptr, nullptr, rows, D_, D_, 0, 0);
  // LN2 -> abuf (bf16)
  ln_kernel<<<rows, 256, 0, stream>>>(xres, ln2_g, ln2_b, abuf);
  // mlp_hi = bf16(gelu(h2 @ fc1 + b1))
  gemm_tpl<128, 128, 2, 2, 1><<<dim3(MLP_H_ / 128, rows / 128), 256, 0, stream>>>(
      abuf, f1_hi, nullptr, fc1_b, nullptr,
      nullptr, mlp_hi, nullptr, rows, D_, MLP_H_, 1, 0);
  // out = xres + mlp @ fc2 + b2
  gemm_tpl<64, 128, 1, 4, 1><<<dim3(D_ / 128, rows / 64), 256, 0, stream>>>(
      mlp_hi, f2_hi, nullptr, fc2_b, xres,
      out, nullptr, nullptr, rows, MLP_H_, D_, 0, 0);
}

// Round 8
// 404.201 us; speedup vs baseline: 3.9022x; 1.0564x over previous
//
#include <hip/hip_runtime.h>
#include <math.h>

typedef unsigned short u16;
typedef unsigned int u32;

#define B_ 4
#define N_ 2048
#define D_ 512
#define H_ 8
#define HD_ 64
#define MLP_H_ 2048
#define EPS_ 1e-5f
#define C2_ 14.426950408889634f          // 10/ln2
#define QSCALE_ 0.1803368801111204f     // 0.125/ln2
#define EL2_ 0.0014426950408889634f     // 1/(1000*ln2)

// ---------- fast exp2 ----------
#if __has_builtin(__builtin_amdgcn_exp2f)
#define EXP2(x) __builtin_amdgcn_exp2f(x)
#else
#define EXP2(x) exp2f(x)
#endif

// ---------- bf16 helpers ----------
__device__ __forceinline__ u16 bf16_rne(float x) {
  u32 u = __float_as_uint(x);
  u32 r = (u + 0x7FFFu + ((u >> 16) & 1u)) >> 16;
  return (u16)r;
}
#if __has_builtin(__builtin_amdgcn_cvt_pk_bf16_f32)
typedef __bf16 bf2_t __attribute__((ext_vector_type(2)));
__device__ __forceinline__ u32 pk_bf16(float a, float b) {
  bf2_t v = __builtin_amdgcn_cvt_pk_bf16_f32(a, b);
  u32 r; __builtin_memcpy(&r, &v, 4); return r;
}
#else
__device__ __forceinline__ u32 pk_bf16(float a, float b) {
  return (u32)bf16_rne(a) | ((u32)bf16_rne(b) << 16);
}
#endif
__device__ __forceinline__ void bf16_split(float x, u16& h, u16& l) {
  h = bf16_rne(x);
  float hf = __uint_as_float(((u32)h) << 16);
  l = bf16_rne(x - hf);
}

typedef __attribute__((ext_vector_type(8))) short bfrag;
typedef __attribute__((ext_vector_type(4))) float ffrag;

#define LDS_AS(p) ((__attribute__((address_space(3))) void*)(p))
#define GLB_AS(p) ((const __attribute__((address_space(1))) void*)(p))

// ---------------- LayerNorm -> bf16 out (optionally fuses elevation pre-scale) ----
__global__ __launch_bounds__(256) void ln_kernel(
    const float* __restrict__ x, const float* __restrict__ g,
    const float* __restrict__ b, u16* __restrict__ o,
    const float* __restrict__ elev, const float* __restrict__ alpha,
    float* __restrict__ e2)
{
  __shared__ float red[8];
  int row = blockIdx.x;
  int tid = threadIdx.x;
  if (e2 && tid == 0) e2[row] = elev[row] * (alpha[0] * EL2_);
  const float* xr = x + (size_t)row * D_;
  float v0 = xr[tid], v1 = xr[tid + 256];
  float s = v0 + v1;
  #pragma unroll
  for (int off = 32; off > 0; off >>= 1) s += __shfl_xor(s, off, 64);
  if ((tid & 63) == 0) red[tid >> 6] = s;
  __syncthreads();
  float mean = (red[0] + red[1] + red[2] + red[3]) * (1.0f / D_);
  float d0 = v0 - mean, d1 = v1 - mean;
  float vs = d0 * d0 + d1 * d1;
  #pragma unroll
  for (int off = 32; off > 0; off >>= 1) vs += __shfl_xor(vs, off, 64);
  if ((tid & 63) == 0) red[4 + (tid >> 6)] = vs;
  __syncthreads();
  float var = (red[4] + red[5] + red[6] + red[7]) * (1.0f / D_);
  float r = rsqrtf(var + EPS_);
  u16* orow = o + (size_t)row * D_;
  orow[tid]       = bf16_rne(d0 * r * g[tid] + b[tid]);
  orow[tid + 256] = bf16_rne(d1 * r * g[tid + 256] + b[tid + 256]);
}

// ---------------- fused weight split+transpose (all 4 weights, one launch) ------
// W[K,N] f32 -> T[N,K] bf16 (hi, optional lo)
__device__ __forceinline__ void wsplit_body(
    const float* __restrict__ W, u16* __restrict__ Thi, u16* __restrict__ Tlo,
    int K, int N, int bx, int by, int tid)
{
  __shared__ float tile[64][65];
  int n0 = bx * 64, k0 = by * 64;
  int c = tid & 63, r4 = tid >> 6;
  #pragma unroll
  for (int i = 0; i < 16; i++) {
    int r = r4 + i * 4;
    tile[r][c] = W[(size_t)(k0 + r) * N + n0 + c];
  }
  __syncthreads();
  #pragma unroll
  for (int i = 0; i < 16; i++) {
    int rn = r4 + i * 4;
    float v = tile[c][rn];
    size_t o = (size_t)(n0 + rn) * K + k0 + c;
    if (Tlo) {
      u16 h, l; bf16_split(v, h, l);
      Thi[o] = h; Tlo[o] = l;
    } else {
      Thi[o] = bf16_rne(v);
    }
  }
}

__global__ __launch_bounds__(256) void wsplit_all(
    const float* __restrict__ qkv_w, const float* __restrict__ proj_w,
    const float* __restrict__ fc1_w, const float* __restrict__ fc2_w,
    u16* __restrict__ qw_hi, u16* __restrict__ qw_lo,
    u16* __restrict__ pw_hi, u16* __restrict__ f1_hi, u16* __restrict__ f2_hi)
{
  int id = blockIdx.x;
  int tid = threadIdx.x;
  if (id < 192) {            // qkv_w: 24 x 8 tiles, split hi/lo
    wsplit_body(qkv_w, qw_hi, qw_lo, 512, 1536, id % 24, id / 24, tid);
  } else if (id < 256) {     // proj_w: 8 x 8
    int l = id - 192;
    wsplit_body(proj_w, pw_hi, nullptr, 512, 512, l % 8, l / 8, tid);
  } else if (id < 512) {     // fc1_w: 32 x 8
    int l = id - 256;
    wsplit_body(fc1_w, f1_hi, nullptr, 512, 2048, l % 32, l / 32, tid);
  } else {                   // fc2_w: 8 x 32
    int l = id - 512;
    wsplit_body(fc2_w, f2_hi, nullptr, 2048, 512, l % 8, l / 8, tid);
  }
}

// ---------------- MFMA GEMM: BK=64 (two swizzled 32-k sub-tiles) ----------------
template<int ROWS>
__device__ __forceinline__ void stage32(const u16* __restrict__ src, int ld,
                                        int r0, int k0, u16* lds, int lane, int wave)
{
  #pragma unroll
  for (int i = 0; i < ROWS / 64; i++) {
    int seg = wave * (ROWS / 64) + i;
    int chunk = seg * 64 + lane;
    int r = chunk >> 2;
    int c = (chunk & 3) ^ ((r >> 1) & 3);
    const u16* g = src + (size_t)(r0 + r) * ld + k0 + c * 8;
    __builtin_amdgcn_global_load_lds(GLB_AS(g), LDS_AS((char*)lds + seg * 1024), 16, 0, 0);
  }
}

__device__ __forceinline__ int swz_off(int R, int quad) {
  return R * 32 + ((quad ^ ((R >> 1) & 3)) * 8);   // u16 units within a 32-k tile
}

// VT=1: epilogue writes V^T [B,H,HD,N] bf16 (Ohi = vt base); no bias/act/res.
template<int TBM, int TBN, int WR, int WC, int TERMS, int VT>
__global__ __launch_bounds__(256) void gemm_tpl(
    const u16* __restrict__ Ahi,
    const u16* __restrict__ Whi, const u16* __restrict__ Wlo,
    const float* __restrict__ bias, const float* __restrict__ res,
    float* __restrict__ Cf, u16* __restrict__ Ohi, u16* __restrict__ Olo,
    int M, int K, int N, int act, int qcols)
{
  constexpr int MF = TBM / (WR * 16);
  constexpr int NF = TBN / (WC * 16);
  constexpr int AT = TBM * 32;   // u16 per 32-k subtile
  constexpr int BT = TBN * 32;
  constexpr int SMEMU = 2 * AT + ((TERMS >= 2) ? 4 * BT : 2 * BT);
  __shared__ __align__(16) u16 smem[SMEMU];
  u16* As0 = smem;               u16* As1 = smem + AT;
  u16* Bh0 = smem + 2 * AT;      u16* Bh1 = smem + 2 * AT + BT;
  u16* Bl0 = smem + 2 * AT + 2 * BT;
  u16* Bl1 = smem + 2 * AT + 3 * BT;

  int tid = threadIdx.x;
  int lane = tid & 63, wave = tid >> 6;
  int wr = wave / WC, wc = wave % WC;
  int ln = lane & 15, quad = lane >> 4;
  int m0 = blockIdx.y * TBM, n0 = blockIdx.x * TBN;

  ffrag acc[MF][NF] = {};

  for (int k0 = 0; k0 < K; k0 += 64) {
    stage32<TBM>(Ahi, K, m0, k0,      As0, lane, wave);
    stage32<TBM>(Ahi, K, m0, k0 + 32, As1, lane, wave);
    stage32<TBN>(Whi, K, n0, k0,      Bh0, lane, wave);
    stage32<TBN>(Whi, K, n0, k0 + 32, Bh1, lane, wave);
    if constexpr (TERMS >= 2) {
      stage32<TBN>(Wlo, K, n0, k0,      Bl0, lane, wave);
      stage32<TBN>(Wlo, K, n0, k0 + 32, Bl1, lane, wave);
    }
    __syncthreads();

    #pragma unroll
    for (int hf = 0; hf < 2; hf++) {
      const u16* Asf = hf ? As1 : As0;
      const u16* Bhf = hf ? Bh1 : Bh0;
      const u16* Blf = hf ? Bl1 : Bl0;
      bfrag ah[MF], bh[NF], bl[NF];
      #pragma unroll
      for (int t = 0; t < MF; t++)
        ah[t] = *(const bfrag*)(Asf + swz_off(wr * (TBM / WR) + t * 16 + ln, quad));
      #pragma unroll
      for (int u = 0; u < NF; u++) {
        int off = swz_off(wc * (TBN / WC) + u * 16 + ln, quad);
        bh[u] = *(const bfrag*)(Bhf + off);
        if constexpr (TERMS >= 2) bl[u] = *(const bfrag*)(Blf + off);
      }
      #pragma unroll
      for (int ti = 0; ti < MF; ti++) {
        #pragma unroll
        for (int tj = 0; tj < NF; tj++) {
          acc[ti][tj] = __builtin_amdgcn_mfma_f32_16x16x32_bf16(ah[ti], bh[tj], acc[ti][tj], 0, 0, 0);
          if constexpr (TERMS >= 2)
            acc[ti][tj] = __builtin_amdgcn_mfma_f32_16x16x32_bf16(ah[ti], bl[tj], acc[ti][tj], 0, 0, 0);
        }
      }
    }
    __syncthreads();
  }

  if constexpr (VT) {
    // write V^T: col -> (h, d); row -> (b, n). 4 consecutive n per thread.
    #pragma unroll
    for (int tj = 0; tj < NF; tj++) {
      int col = n0 + wc * (TBN / WC) + tj * 16 + ln;   // 0..511
      int h = col >> 6, d = col & 63;
      #pragma unroll
      for (int ti = 0; ti < MF; ti++) {
        int rw = m0 + wr * (TBM / WR) + ti * 16 + quad * 4;
        int bb = rw >> 11, n = rw & (N_ - 1);
        u32 w0 = pk_bf16(acc[ti][tj][0], acc[ti][tj][1]);
        u32 w1 = pk_bf16(acc[ti][tj][2], acc[ti][tj][3]);
        size_t dst = ((size_t)((bb * H_ + h) * HD_ + d)) * N_ + n;
        *(uint2*)(Ohi + dst) = make_uint2(w0, w1);
      }
    }
    return;
  }

  #pragma unroll
  for (int tj = 0; tj < NF; tj++) {
    int col = n0 + wc * (TBN / WC) + tj * 16 + ln;
    float bv = bias ? bias[col] : 0.f;
    float cs = (col < qcols) ? QSCALE_ : 1.0f;
    bool store_lo = (col < qcols);
    #pragma unroll
    for (int ti = 0; ti < MF; ti++) {
      int rw = m0 + wr * (TBM / WR) + ti * 16 + quad * 4;
      #pragma unroll
      for (int r = 0; r < 4; r++) {
        float y = acc[ti][tj][r] + bv;
        if (act) y = 0.5f * y * (1.f + erff(y * 0.70710678118654752f));
        if (res) y += res[(size_t)(rw + r) * N + col];
        if (Cf) Cf[(size_t)(rw + r) * N + col] = y;
        if (Ohi) {
          y *= cs;
          if (Olo && store_lo) {
            u16 hh, ll; bf16_split(y, hh, ll);
            Ohi[(size_t)(rw + r) * N + col] = hh;
            Olo[(size_t)(rw + r) * N + col] = ll;
          } else {
            Ohi[(size_t)(rw + r) * N + col] = bf16_rne(y);
          }
        }
      }
    }
  }
}

// ---------------- MFMA flash attention (S-transposed, K/V single bf16) ----------
// qk layout now [B, N, 1024] (Q cols 0-511 split, K cols 512-1023 hi-only).
__device__ __forceinline__ void stage_tile64(const u16* __restrict__ gbase, size_t rstride,
                                             u16* lds, int wave, int lane)
{
  #pragma unroll
  for (int i = 0; i < 2; i++) {
    int seg = wave * 2 + i;
    int chunk = seg * 64 + lane;            // phys chunk 0..511
    int ch = chunk >> 8;                    // 32-elem half
    int pc = chunk & 255;
    int r = pc >> 2;
    int q = (pc & 3) ^ ((r >> 1) & 3);
    const u16* g = gbase + (size_t)r * rstride + ch * 32 + q * 8;
    __builtin_amdgcn_global_load_lds(GLB_AS(g), LDS_AS((char*)lds + seg * 1024), 16, 0, 0);
  }
}

__device__ __forceinline__ int frag_off(int c, int R, int quad) {
  return c * 2048 + R * 32 + ((quad ^ ((R >> 1) & 3)) * 8);   // u16 units
}

__global__ __launch_bounds__(256) void attn_mfma_kernel(
    const u16* __restrict__ qkh, const u16* __restrict__ qkl,
    const u16* __restrict__ vth,
    const float* __restrict__ e2, u16* __restrict__ outb)
{
  __shared__ __align__(16) u16 Kh[4096];
  __shared__ __align__(16) u16 Vh[4096];
  __shared__ __align__(16) u16 Pw[4][16][72];

  int b = blockIdx.z, h = blockIdx.y;
  int q0 = blockIdx.x * 64;
  int tid = threadIdx.x;
  int lane = tid & 63, wq = tid >> 6;
  int ln = lane & 15, quad = lane >> 4;

  // ---- stage Q: hi -> Kh, lo -> Vh ----
  const u16* qb_h = qkh + ((size_t)(b * N_ + q0)) * 1024 + h * 64;
  const u16* qb_l = qkl + ((size_t)(b * N_ + q0)) * 1024 + h * 64;
  stage_tile64(qb_h, 1024, Kh, wq, lane);
  stage_tile64(qb_l, 1024, Vh, wq, lane);
  __syncthreads();

  bfrag qfh[2], qfl[2];
  #pragma unroll
  for (int c = 0; c < 2; c++) {
    int off = frag_off(c, wq * 16 + ln, quad);
    qfh[c] = *(const bfrag*)(Kh + off);
    qfl[c] = *(const bfrag*)(Vh + off);
  }
  __syncthreads();

  float e2q = e2[b * N_ + q0 + wq * 16 + ln];
  float m_i = -3.0e38f, l_i = 0.f;
  ffrag O[4] = {};

  const u16* kp = qkh + (size_t)b * N_ * 1024 + 512 + h * 64;
  const u16* vp = vth + (size_t)(b * H_ + h) * HD_ * N_;
  const float* ep = e2 + b * N_;

  for (int k0 = 0; k0 < N_; k0 += 64) {
    stage_tile64(kp, 1024, Kh, wq, lane);
    stage_tile64(vp, N_, Vh, wq, lane);
    kp += (size_t)64 * 1024;
    vp += 64;
    __syncthreads();

    // ---- S^T = K (Qh+Ql)^T ----
    ffrag S[4];
    #pragma unroll
    for (int kt = 0; kt < 4; kt++) {
      ffrag s = {0.f, 0.f, 0.f, 0.f};
      #pragma unroll
      for (int c = 0; c < 2; c++) {
        bfrag kf = *(const bfrag*)(Kh + frag_off(c, kt * 16 + ln, quad));
        s = __builtin_amdgcn_mfma_f32_16x16x32_bf16(kf, qfh[c], s, 0, 0, 0);
        s = __builtin_amdgcn_mfma_f32_16x16x32_bf16(kf, qfl[c], s, 0, 0, 0);
      }
      S[kt] = s;
    }

    // ---- bias + online softmax ----
    float4 ek[4];
    #pragma unroll
    for (int kt = 0; kt < 4; kt++)
      ek[kt] = *(const float4*)&ep[k0 + kt * 16 + quad * 4];

    float p[4][4];
    float mx = -3.0e38f;
    #pragma unroll
    for (int kt = 0; kt < 4; kt++) {
      #pragma unroll
      for (int r = 0; r < 4; r++) {
        float d = (&ek[kt].x)[r] - e2q;
        d = fminf(fmaxf(d, 0.f), C2_);
        float sv = S[kt][r] - d;
        p[kt][r] = sv;
        mx = fmaxf(mx, sv);
      }
    }
    mx = fmaxf(mx, __shfl_xor(mx, 16, 64));
    mx = fmaxf(mx, __shfl_xor(mx, 32, 64));
    float mnew = fmaxf(m_i, mx);
    float corr = EXP2(m_i - mnew);
    float ps = 0.f;
    #pragma unroll
    for (int kt = 0; kt < 4; kt++) {
      #pragma unroll
      for (int r = 0; r < 4; r++) {
        float pv = EXP2(p[kt][r] - mnew);
        p[kt][r] = pv;
        ps += pv;
      }
    }
    ps += __shfl_xor(ps, 16, 64);
    ps += __shfl_xor(ps, 32, 64);
    m_i = mnew;
    l_i = l_i * corr + ps;
    #pragma unroll
    for (int dt = 0; dt < 4; dt++) O[dt] *= corr;

    // write P^T bf16
    #pragma unroll
    for (int kt = 0; kt < 4; kt++) {
      u32 w0 = pk_bf16(p[kt][0], p[kt][1]);
      u32 w1 = pk_bf16(p[kt][2], p[kt][3]);
      *(uint2*)&Pw[wq][ln][kt * 16 + quad * 4] = make_uint2(w0, w1);
    }

    bfrag pf[2];
    #pragma unroll
    for (int c = 0; c < 2; c++)
      pf[c] = *(const bfrag*)&Pw[wq][ln][c * 32 + quad * 8];

    // ---- O^T += Vt P^T ----
    #pragma unroll
    for (int dt = 0; dt < 4; dt++) {
      ffrag o = O[dt];
      #pragma unroll
      for (int c = 0; c < 2; c++) {
        bfrag vf = *(const bfrag*)(Vh + frag_off(c, dt * 16 + ln, quad));
        o = __builtin_amdgcn_mfma_f32_16x16x32_bf16(vf, pf[c], o, 0, 0, 0);
      }
      O[dt] = o;
    }
    __syncthreads();
  }

  float inv = 1.0f / l_i;
  int row = q0 + wq * 16 + ln;
  #pragma unroll
  for (int dt = 0; dt < 4; dt++) {
    u32 w0 = pk_bf16(O[dt][0] * inv, O[dt][1] * inv);
    u32 w1 = pk_bf16(O[dt][2] * inv, O[dt][3] * inv);
    *(uint2*)&outb[((size_t)(b * N_ + row)) * D_ + h * 64 + dt * 16 + quad * 4] =
        make_uint2(w0, w1);
  }
}

extern "C" void kernel_launch(void* const* d_in, const int* in_sizes, int n_in,
                              void* d_out, int out_size, void* d_ws, size_t ws_size,
                              hipStream_t stream) {
  const float* x      = (const float*)d_in[0];
  const float* elev   = (const float*)d_in[1];
  const float* ln1_g  = (const float*)d_in[2];
  const float* ln1_b  = (const float*)d_in[3];
  const float* qkv_w  = (const float*)d_in[4];
  const float* alpha  = (const float*)d_in[5];
  const float* proj_w = (const float*)d_in[6];
  const float* proj_b = (const float*)d_in[7];
  const float* ln2_g  = (const float*)d_in[8];
  const float* ln2_b  = (const float*)d_in[9];
  const float* fc1_w  = (const float*)d_in[10];
  const float* fc1_b  = (const float*)d_in[11];
  const float* fc2_w  = (const float*)d_in[12];
  const float* fc2_b  = (const float*)d_in[13];
  float* out = (float*)d_out;

  const size_t HBf  = (size_t)B_ * N_ * D_;        // 4,194,304
  const size_t QKE  = (size_t)B_ * N_ * 1024;      // 8,388,608 (Q+K region)
  const size_t MLPE = (size_t)B_ * N_ * MLP_H_;    // 16,777,216

  char* p = (char*)d_ws;
  u16* abuf = (u16*)p;                     p += HBf * 2;    // LN1 out -> attn out -> LN2 out
  char* region = p;                        p += MLPE * 2;   // qkh+qkl | mlp_hi (each 33.6 MB)
  u16* qkh    = (u16*)region;
  u16* qkl    = (u16*)(region + QKE * 2);
  u16* mlp_hi = (u16*)region;
  u16* vth  = (u16*)p;  p += HBf * 2;
  float* xres = (float*)p;                 p += HBf * 4;
  u16* qw_hi = (u16*)p;  p += (size_t)D_ * 3 * D_ * 2;
  u16* qw_lo = (u16*)p;  p += (size_t)D_ * 3 * D_ * 2;
  u16* pw_hi = (u16*)p;  p += (size_t)D_ * D_ * 2;
  u16* f1_hi = (u16*)p;  p += (size_t)D_ * MLP_H_ * 2;
  u16* f2_hi = (u16*)p;  p += (size_t)MLP_H_ * D_ * 2;
  float* e2  = (float*)p; p += (size_t)B_ * N_ * 4;

  const int rows = B_ * N_;   // 8192

  // all weight transforms, one launch
  wsplit_all<<<768, 256, 0, stream>>>(qkv_w, proj_w, fc1_w, fc2_w,
                                      qw_hi, qw_lo, pw_hi, f1_hi, f2_hi);
  // LN1 -> abuf (bf16), fused elevation pre-scale
  ln_kernel<<<rows, 256, 0, stream>>>(x, ln1_g, ln1_b, abuf, elev, alpha, e2);
  // QK = h @ qkv_w[:, :1024] : 2-term; Q cols scaled+split, K cols hi-only
  gemm_tpl<128, 128, 2, 2, 2, 0><<<dim3(1024 / 128, rows / 128), 256, 0, stream>>>(
      abuf, qw_hi, qw_lo, nullptr, nullptr,
      nullptr, qkh, qkl, rows, D_, 1024, 0, D_);
  // V = h @ qkv_w[:, 1024:] : 1-term, epilogue writes V^T [B,H,HD,N]
  gemm_tpl<64, 128, 1, 4, 1, 1><<<dim3(512 / 128, rows / 64), 256, 0, stream>>>(
      abuf, qw_hi + (size_t)1024 * D_, nullptr, nullptr, nullptr,
      nullptr, vth, nullptr, rows, D_, 512, 0, 0);
  // attention -> abuf (bf16)
  attn_mfma_kernel<<<dim3(N_ / 64, H_, B_), 256, 0, stream>>>(
      qkh, qkl, vth, e2, abuf);
  // xres = x + attn @ proj_w + proj_b (f32)
  gemm_tpl<64, 128, 1, 4, 1, 0><<<dim3(D_ / 128, rows / 64), 256, 0, stream>>>(
      abuf, pw_hi, nullptr, proj_b, x,
      xres, nullptr, nullptr, rows, D_, D_, 0, 0);
  // LN2 -> abuf (bf16)
  ln_kernel<<<rows, 256, 0, stream>>>(xres, ln2_g, ln2_b, abuf, nullptr, nullptr, nullptr);
  // mlp_hi = bf16(gelu(h2 @ fc1 + b1))
  gemm_tpl<128, 128, 2, 2, 1, 0><<<dim3(MLP_H_ / 128, rows / 128), 256, 0, stream>>>(
      abuf, f1_hi, nullptr, fc1_b, nullptr,
      nullptr, mlp_hi, nullptr, rows, D_, MLP_H_, 1, 0);
  // out = xres + mlp @ fc2 + b2
  gemm_tpl<64, 128, 1, 4, 1, 0><<<dim3(D_ / 128, rows / 64), 256, 0, stream>>>(
      mlp_hi, f2_hi, nullptr, fc2_b, xres,
      out, nullptr, nullptr, rows, MLP_H_, D_, 0, 0);
}

// Round 9
// 350.884 us; speedup vs baseline: 4.4951x; 1.1520x over previous
//
#include <hip/hip_runtime.h>
#include <math.h>

typedef unsigned short u16;
typedef unsigned int u32;

#define B_ 4
#define N_ 2048
#define D_ 512
#define H_ 8
#define HD_ 64
#define MLP_H_ 2048
#define EPS_ 1e-5f
#define C2_ 14.426950408889634f          // 10/ln2
#define QSCALE_ 0.1803368801111204f     // 0.125/ln2
#define EL2_ 0.0014426950408889634f     // 1/(1000*ln2)

// ---------- fast exp2 ----------
#if __has_builtin(__builtin_amdgcn_exp2f)
#define EXP2(x) __builtin_amdgcn_exp2f(x)
#else
#define EXP2(x) exp2f(x)
#endif

// ---------- bf16 helpers ----------
__device__ __forceinline__ u16 bf16_rne(float x) {
  u32 u = __float_as_uint(x);
  u32 r = (u + 0x7FFFu + ((u >> 16) & 1u)) >> 16;
  return (u16)r;
}
#if __has_builtin(__builtin_amdgcn_cvt_pk_bf16_f32)
typedef __bf16 bf2_t __attribute__((ext_vector_type(2)));
__device__ __forceinline__ u32 pk_bf16(float a, float b) {
  bf2_t v = __builtin_amdgcn_cvt_pk_bf16_f32(a, b);
  u32 r; __builtin_memcpy(&r, &v, 4); return r;
}
#else
__device__ __forceinline__ u32 pk_bf16(float a, float b) {
  return (u32)bf16_rne(a) | ((u32)bf16_rne(b) << 16);
}
#endif
__device__ __forceinline__ void bf16_split(float x, u16& h, u16& l) {
  h = bf16_rne(x);
  float hf = __uint_as_float(((u32)h) << 16);
  l = bf16_rne(x - hf);
}

typedef __attribute__((ext_vector_type(8))) short bfrag;
typedef __attribute__((ext_vector_type(4))) float ffrag;

#define LDS_AS(p) ((__attribute__((address_space(3))) void*)(p))
#define GLB_AS(p) ((const __attribute__((address_space(1))) void*)(p))

// ---------------- LayerNorm -> bf16 out (optionally fuses elevation pre-scale) ----
__global__ __launch_bounds__(256) void ln_kernel(
    const float* __restrict__ x, const float* __restrict__ g,
    const float* __restrict__ b, u16* __restrict__ o,
    const float* __restrict__ elev, const float* __restrict__ alpha,
    float* __restrict__ e2)
{
  __shared__ float red[8];
  int row = blockIdx.x;
  int tid = threadIdx.x;
  if (e2 && tid == 0) e2[row] = elev[row] * (alpha[0] * EL2_);
  const float* xr = x + (size_t)row * D_;
  float v0 = xr[tid], v1 = xr[tid + 256];
  float s = v0 + v1;
  #pragma unroll
  for (int off = 32; off > 0; off >>= 1) s += __shfl_xor(s, off, 64);
  if ((tid & 63) == 0) red[tid >> 6] = s;
  __syncthreads();
  float mean = (red[0] + red[1] + red[2] + red[3]) * (1.0f / D_);
  float d0 = v0 - mean, d1 = v1 - mean;
  float vs = d0 * d0 + d1 * d1;
  #pragma unroll
  for (int off = 32; off > 0; off >>= 1) vs += __shfl_xor(vs, off, 64);
  if ((tid & 63) == 0) red[4 + (tid >> 6)] = vs;
  __syncthreads();
  float var = (red[4] + red[5] + red[6] + red[7]) * (1.0f / D_);
  float r = rsqrtf(var + EPS_);
  u16* orow = o + (size_t)row * D_;
  orow[tid]       = bf16_rne(d0 * r * g[tid] + b[tid]);
  orow[tid + 256] = bf16_rne(d1 * r * g[tid + 256] + b[tid + 256]);
}

// ---------------- fused weight split+transpose (all 4 weights, one launch) ------
__device__ __forceinline__ void wsplit_body(
    const float* __restrict__ W, u16* __restrict__ Thi, u16* __restrict__ Tlo,
    int K, int N, int bx, int by, int tid)
{
  __shared__ float tile[64][65];
  int n0 = bx * 64, k0 = by * 64;
  int c = tid & 63, r4 = tid >> 6;
  #pragma unroll
  for (int i = 0; i < 16; i++) {
    int r = r4 + i * 4;
    tile[r][c] = W[(size_t)(k0 + r) * N + n0 + c];
  }
  __syncthreads();
  #pragma unroll
  for (int i = 0; i < 16; i++) {
    int rn = r4 + i * 4;
    float v = tile[c][rn];
    size_t o = (size_t)(n0 + rn) * K + k0 + c;
    if (Tlo) {
      u16 h, l; bf16_split(v, h, l);
      Thi[o] = h; Tlo[o] = l;
    } else {
      Thi[o] = bf16_rne(v);
    }
  }
}

__global__ __launch_bounds__(256) void wsplit_all(
    const float* __restrict__ qkv_w, const float* __restrict__ proj_w,
    const float* __restrict__ fc1_w, const float* __restrict__ fc2_w,
    u16* __restrict__ qw_hi, u16* __restrict__ qw_lo,
    u16* __restrict__ pw_hi, u16* __restrict__ f1_hi, u16* __restrict__ f2_hi)
{
  int id = blockIdx.x;
  int tid = threadIdx.x;
  if (id < 192) {
    wsplit_body(qkv_w, qw_hi, qw_lo, 512, 1536, id % 24, id / 24, tid);
  } else if (id < 256) {
    int l = id - 192;
    wsplit_body(proj_w, pw_hi, nullptr, 512, 512, l % 8, l / 8, tid);
  } else if (id < 512) {
    int l = id - 256;
    wsplit_body(fc1_w, f1_hi, nullptr, 512, 2048, l % 32, l / 32, tid);
  } else {
    int l = id - 512;
    wsplit_body(fc2_w, f2_hi, nullptr, 2048, 512, l % 8, l / 8, tid);
  }
}

// ---------------- MFMA GEMM: BK=64 (two swizzled 32-k sub-tiles) ----------------
template<int ROWS>
__device__ __forceinline__ void stage32(const u16* __restrict__ src, int ld,
                                        int r0, int k0, u16* lds, int lane, int wave)
{
  #pragma unroll
  for (int i = 0; i < ROWS / 64; i++) {
    int seg = wave * (ROWS / 64) + i;
    int chunk = seg * 64 + lane;
    int r = chunk >> 2;
    int c = (chunk & 3) ^ ((r >> 1) & 3);
    const u16* g = src + (size_t)(r0 + r) * ld + k0 + c * 8;
    __builtin_amdgcn_global_load_lds(GLB_AS(g), LDS_AS((char*)lds + seg * 1024), 16, 0, 0);
  }
}

__device__ __forceinline__ int swz_off(int R, int quad) {
  return R * 32 + ((quad ^ ((R >> 1) & 3)) * 8);   // u16 units within a 32-k tile
}

// VT=1: epilogue writes V^T [B,H,HD,N] bf16; no bias/act/res.
template<int TBM, int TBN, int WR, int WC, int TERMS, int VT>
__global__ __launch_bounds__(256) void gemm_tpl(
    const u16* __restrict__ Ahi,
    const u16* __restrict__ Whi, const u16* __restrict__ Wlo,
    const float* __restrict__ bias, const float* __restrict__ res,
    float* __restrict__ Cf, u16* __restrict__ Ohi, u16* __restrict__ Olo,
    int M, int K, int N, int act, int qcols)
{
  constexpr int MF = TBM / (WR * 16);
  constexpr int NF = TBN / (WC * 16);
  constexpr int AT = TBM * 32;   // u16 per 32-k subtile
  constexpr int BT = TBN * 32;
  constexpr int SMEMU = 2 * AT + ((TERMS >= 2) ? 4 * BT : 2 * BT);
  __shared__ __align__(16) u16 smem[SMEMU];
  u16* As0 = smem;               u16* As1 = smem + AT;
  u16* Bh0 = smem + 2 * AT;      u16* Bh1 = smem + 2 * AT + BT;
  u16* Bl0 = smem + 2 * AT + 2 * BT;
  u16* Bl1 = smem + 2 * AT + 3 * BT;

  int tid = threadIdx.x;
  int lane = tid & 63, wave = tid >> 6;
  int wr = wave / WC, wc = wave % WC;
  int ln = lane & 15, quad = lane >> 4;
  int m0 = blockIdx.y * TBM, n0 = blockIdx.x * TBN;

  ffrag acc[MF][NF] = {};

  for (int k0 = 0; k0 < K; k0 += 64) {
    stage32<TBM>(Ahi, K, m0, k0,      As0, lane, wave);
    stage32<TBM>(Ahi, K, m0, k0 + 32, As1, lane, wave);
    stage32<TBN>(Whi, K, n0, k0,      Bh0, lane, wave);
    stage32<TBN>(Whi, K, n0, k0 + 32, Bh1, lane, wave);
    if constexpr (TERMS >= 2) {
      stage32<TBN>(Wlo, K, n0, k0,      Bl0, lane, wave);
      stage32<TBN>(Wlo, K, n0, k0 + 32, Bl1, lane, wave);
    }
    __syncthreads();

    #pragma unroll
    for (int hf = 0; hf < 2; hf++) {
      const u16* Asf = hf ? As1 : As0;
      const u16* Bhf = hf ? Bh1 : Bh0;
      const u16* Blf = hf ? Bl1 : Bl0;
      bfrag ah[MF], bh[NF], bl[NF];
      #pragma unroll
      for (int t = 0; t < MF; t++)
        ah[t] = *(const bfrag*)(Asf + swz_off(wr * (TBM / WR) + t * 16 + ln, quad));
      #pragma unroll
      for (int u = 0; u < NF; u++) {
        int off = swz_off(wc * (TBN / WC) + u * 16 + ln, quad);
        bh[u] = *(const bfrag*)(Bhf + off);
        if constexpr (TERMS >= 2) bl[u] = *(const bfrag*)(Blf + off);
      }
      #pragma unroll
      for (int ti = 0; ti < MF; ti++) {
        #pragma unroll
        for (int tj = 0; tj < NF; tj++) {
          acc[ti][tj] = __builtin_amdgcn_mfma_f32_16x16x32_bf16(ah[ti], bh[tj], acc[ti][tj], 0, 0, 0);
          if constexpr (TERMS >= 2)
            acc[ti][tj] = __builtin_amdgcn_mfma_f32_16x16x32_bf16(ah[ti], bl[tj], acc[ti][tj], 0, 0, 0);
        }
      }
    }
    __syncthreads();
  }

  if constexpr (VT) {
    #pragma unroll
    for (int tj = 0; tj < NF; tj++) {
      int col = n0 + wc * (TBN / WC) + tj * 16 + ln;   // 0..511
      int h = col >> 6, d = col & 63;
      #pragma unroll
      for (int ti = 0; ti < MF; ti++) {
        int rw = m0 + wr * (TBM / WR) + ti * 16 + quad * 4;
        int bb = rw >> 11, n = rw & (N_ - 1);
        u32 w0 = pk_bf16(acc[ti][tj][0], acc[ti][tj][1]);
        u32 w1 = pk_bf16(acc[ti][tj][2], acc[ti][tj][3]);
        size_t dst = ((size_t)((bb * H_ + h) * HD_ + d)) * N_ + n;
        *(uint2*)(Ohi + dst) = make_uint2(w0, w1);
      }
    }
    return;
  }

  #pragma unroll
  for (int tj = 0; tj < NF; tj++) {
    int col = n0 + wc * (TBN / WC) + tj * 16 + ln;
    float bv = bias ? bias[col] : 0.f;
    float cs = (col < qcols) ? QSCALE_ : 1.0f;
    bool store_lo = (col < qcols);
    #pragma unroll
    for (int ti = 0; ti < MF; ti++) {
      int rw = m0 + wr * (TBM / WR) + ti * 16 + quad * 4;
      #pragma unroll
      for (int r = 0; r < 4; r++) {
        float y = acc[ti][tj][r] + bv;
        if (act) y = 0.5f * y * (1.f + erff(y * 0.70710678118654752f));
        if (res) y += res[(size_t)(rw + r) * N + col];
        if (Cf) Cf[(size_t)(rw + r) * N + col] = y;
        if (Ohi) {
          y *= cs;
          if (Olo && store_lo) {
            u16 hh, ll; bf16_split(y, hh, ll);
            Ohi[(size_t)(rw + r) * N + col] = hh;
            Olo[(size_t)(rw + r) * N + col] = ll;
          } else {
            Ohi[(size_t)(rw + r) * N + col] = bf16_rne(y);
          }
        }
      }
    }
  }
}

// ---------------- MFMA flash attention (S-transposed, K/V single bf16) ----------
__device__ __forceinline__ void stage_tile64(const u16* __restrict__ gbase, size_t rstride,
                                             u16* lds, int wave, int lane)
{
  #pragma unroll
  for (int i = 0; i < 2; i++) {
    int seg = wave * 2 + i;
    int chunk = seg * 64 + lane;            // phys chunk 0..511
    int ch = chunk >> 8;                    // 32-elem half
    int pc = chunk & 255;
    int r = pc >> 2;
    int q = (pc & 3) ^ ((r >> 1) & 3);
    const u16* g = gbase + (size_t)r * rstride + ch * 32 + q * 8;
    __builtin_amdgcn_global_load_lds(GLB_AS(g), LDS_AS((char*)lds + seg * 1024), 16, 0, 0);
  }
}

__device__ __forceinline__ int frag_off(int c, int R, int quad) {
  return c * 2048 + R * 32 + ((quad ^ ((R >> 1) & 3)) * 8);   // u16 units
}

__global__ __launch_bounds__(256) void attn_mfma_kernel(
    const u16* __restrict__ qkh, const u16* __restrict__ qkl,
    const u16* __restrict__ vth,
    const float* __restrict__ e2, u16* __restrict__ outb)
{
  __shared__ __align__(16) u16 Kh[4096];
  __shared__ __align__(16) u16 Vh[4096];
  __shared__ __align__(16) u16 Pw[4][16][72];

  int b = blockIdx.z, h = blockIdx.y;
  int q0 = blockIdx.x * 64;
  int tid = threadIdx.x;
  int lane = tid & 63, wq = tid >> 6;
  int ln = lane & 15, quad = lane >> 4;

  // ---- stage Q: hi -> Kh, lo -> Vh ----
  const u16* qb_h = qkh + ((size_t)(b * N_ + q0)) * 1024 + h * 64;
  const u16* qb_l = qkl + ((size_t)(b * N_ + q0)) * 1024 + h * 64;
  stage_tile64(qb_h, 1024, Kh, wq, lane);
  stage_tile64(qb_l, 1024, Vh, wq, lane);
  __syncthreads();

  bfrag qfh[2], qfl[2];
  #pragma unroll
  for (int c = 0; c < 2; c++) {
    int off = frag_off(c, wq * 16 + ln, quad);
    qfh[c] = *(const bfrag*)(Kh + off);
    qfl[c] = *(const bfrag*)(Vh + off);
  }
  __syncthreads();

  float e2q = e2[b * N_ + q0 + wq * 16 + ln];
  float m_i = -3.0e38f, l_i = 0.f;
  ffrag O[4] = {};

  const u16* kp = qkh + (size_t)b * N_ * 1024 + 512 + h * 64;
  const u16* vp = vth + (size_t)(b * H_ + h) * HD_ * N_;
  const float* ep = e2 + b * N_;

  for (int k0 = 0; k0 < N_; k0 += 64) {
    stage_tile64(kp, 1024, Kh, wq, lane);
    stage_tile64(vp, N_, Vh, wq, lane);
    kp += (size_t)64 * 1024;
    vp += 64;
    __syncthreads();

    // ---- S^T = K (Qh+Ql)^T ----
    ffrag S[4];
    #pragma unroll
    for (int kt = 0; kt < 4; kt++) {
      ffrag s = {0.f, 0.f, 0.f, 0.f};
      #pragma unroll
      for (int c = 0; c < 2; c++) {
        bfrag kf = *(const bfrag*)(Kh + frag_off(c, kt * 16 + ln, quad));
        s = __builtin_amdgcn_mfma_f32_16x16x32_bf16(kf, qfh[c], s, 0, 0, 0);
        s = __builtin_amdgcn_mfma_f32_16x16x32_bf16(kf, qfl[c], s, 0, 0, 0);
      }
      S[kt] = s;
    }

    // ---- bias + online softmax ----
    float4 ek[4];
    #pragma unroll
    for (int kt = 0; kt < 4; kt++)
      ek[kt] = *(const float4*)&ep[k0 + kt * 16 + quad * 4];

    float p[4][4];
    float mx = -3.0e38f;
    #pragma unroll
    for (int kt = 0; kt < 4; kt++) {
      #pragma unroll
      for (int r = 0; r < 4; r++) {
        float d = (&ek[kt].x)[r] - e2q;
        d = fminf(fmaxf(d, 0.f), C2_);
        float sv = S[kt][r] - d;
        p[kt][r] = sv;
        mx = fmaxf(mx, sv);
      }
    }
    mx = fmaxf(mx, __shfl_xor(mx, 16, 64));
    mx = fmaxf(mx, __shfl_xor(mx, 32, 64));
    float mnew = fmaxf(m_i, mx);
    float corr = EXP2(m_i - mnew);
    float ps = 0.f;
    #pragma unroll
    for (int kt = 0; kt < 4; kt++) {
      #pragma unroll
      for (int r = 0; r < 4; r++) {
        float pv = EXP2(p[kt][r] - mnew);
        p[kt][r] = pv;
        ps += pv;
      }
    }
    ps += __shfl_xor(ps, 16, 64);
    ps += __shfl_xor(ps, 32, 64);
    m_i = mnew;
    l_i = l_i * corr + ps;
    #pragma unroll
    for (int dt = 0; dt < 4; dt++) O[dt] *= corr;

    // write P^T bf16
    #pragma unroll
    for (int kt = 0; kt < 4; kt++) {
      u32 w0 = pk_bf16(p[kt][0], p[kt][1]);
      u32 w1 = pk_bf16(p[kt][2], p[kt][3]);
      *(uint2*)&Pw[wq][ln][kt * 16 + quad * 4] = make_uint2(w0, w1);
    }

    bfrag pf[2];
    #pragma unroll
    for (int c = 0; c < 2; c++)
      pf[c] = *(const bfrag*)&Pw[wq][ln][c * 32 + quad * 8];

    // ---- O^T += Vt P^T ----
    #pragma unroll
    for (int dt = 0; dt < 4; dt++) {
      ffrag o = O[dt];
      #pragma unroll
      for (int c = 0; c < 2; c++) {
        bfrag vf = *(const bfrag*)(Vh + frag_off(c, dt * 16 + ln, quad));
        o = __builtin_amdgcn_mfma_f32_16x16x32_bf16(vf, pf[c], o, 0, 0, 0);
      }
      O[dt] = o;
    }
    __syncthreads();
  }

  float inv = 1.0f / l_i;
  int row = q0 + wq * 16 + ln;
  #pragma unroll
  for (int dt = 0; dt < 4; dt++) {
    u32 w0 = pk_bf16(O[dt][0] * inv, O[dt][1] * inv);
    u32 w1 = pk_bf16(O[dt][2] * inv, O[dt][3] * inv);
    *(uint2*)&outb[((size_t)(b * N_ + row)) * D_ + h * 64 + dt * 16 + quad * 4] =
        make_uint2(w0, w1);
  }
}

extern "C" void kernel_launch(void* const* d_in, const int* in_sizes, int n_in,
                              void* d_out, int out_size, void* d_ws, size_t ws_size,
                              hipStream_t stream) {
  const float* x      = (const float*)d_in[0];
  const float* elev   = (const float*)d_in[1];
  const float* ln1_g  = (const float*)d_in[2];
  const float* ln1_b  = (const float*)d_in[3];
  const float* qkv_w  = (const float*)d_in[4];
  const float* alpha  = (const float*)d_in[5];
  const float* proj_w = (const float*)d_in[6];
  const float* proj_b = (const float*)d_in[7];
  const float* ln2_g  = (const float*)d_in[8];
  const float* ln2_b  = (const float*)d_in[9];
  const float* fc1_w  = (const float*)d_in[10];
  const float* fc1_b  = (const float*)d_in[11];
  const float* fc2_w  = (const float*)d_in[12];
  const float* fc2_b  = (const float*)d_in[13];
  float* out = (float*)d_out;

  const size_t HBf  = (size_t)B_ * N_ * D_;        // 4,194,304
  const size_t QKE  = (size_t)B_ * N_ * 1024;      // 8,388,608
  const size_t MLPE = (size_t)B_ * N_ * MLP_H_;    // 16,777,216

  char* p = (char*)d_ws;
  u16* abuf = (u16*)p;                     p += HBf * 2;    // LN1 out -> attn out -> LN2 out
  char* region = p;                        p += MLPE * 2;   // qkh+qkl | mlp_hi
  u16* qkh    = (u16*)region;
  u16* qkl    = (u16*)(region + QKE * 2);
  u16* mlp_hi = (u16*)region;
  u16* vth  = (u16*)p;  p += HBf * 2;
  float* xres = (float*)p;                 p += HBf * 4;
  u16* qw_hi = (u16*)p;  p += (size_t)D_ * 3 * D_ * 2;
  u16* qw_lo = (u16*)p;  p += (size_t)D_ * 3 * D_ * 2;
  u16* pw_hi = (u16*)p;  p += (size_t)D_ * D_ * 2;
  u16* f1_hi = (u16*)p;  p += (size_t)D_ * MLP_H_ * 2;
  u16* f2_hi = (u16*)p;  p += (size_t)MLP_H_ * D_ * 2;
  float* e2  = (float*)p; p += (size_t)B_ * N_ * 4;

  const int rows = B_ * N_;   // 8192

  wsplit_all<<<768, 256, 0, stream>>>(qkv_w, proj_w, fc1_w, fc2_w,
                                      qw_hi, qw_lo, pw_hi, f1_hi, f2_hi);
  // LN1 -> abuf (bf16), fused elevation pre-scale
  ln_kernel<<<rows, 256, 0, stream>>>(x, ln1_g, ln1_b, abuf, elev, alpha, e2);
  // QK = h @ qkv_w[:, :1024] : 2-term, 128x64 tile -> 1024 blocks (4/CU)
  gemm_tpl<128, 64, 4, 1, 2, 0><<<dim3(1024 / 64, rows / 128), 256, 0, stream>>>(
      abuf, qw_hi, qw_lo, nullptr, nullptr,
      nullptr, qkh, qkl, rows, D_, 1024, 0, D_);
  // V = h @ qkv_w[:, 1024:] : 1-term, 64x64 tile -> 1024 blocks, writes V^T
  gemm_tpl<64, 64, 2, 2, 1, 1><<<dim3(512 / 64, rows / 64), 256, 0, stream>>>(
      abuf, qw_hi + (size_t)1024 * D_, nullptr, nullptr, nullptr,
      nullptr, vth, nullptr, rows, D_, 512, 0, 0);
  // attention -> abuf (bf16)
  attn_mfma_kernel<<<dim3(N_ / 64, H_, B_), 256, 0, stream>>>(
      qkh, qkl, vth, e2, abuf);
  // xres = x + attn @ proj_w + proj_b : 64x64 tile -> 1024 blocks
  gemm_tpl<64, 64, 2, 2, 1, 0><<<dim3(D_ / 64, rows / 64), 256, 0, stream>>>(
      abuf, pw_hi, nullptr, proj_b, x,
      xres, nullptr, nullptr, rows, D_, D_, 0, 0);
  // LN2 -> abuf (bf16)
  ln_kernel<<<rows, 256, 0, stream>>>(xres, ln2_g, ln2_b, abuf, nullptr, nullptr, nullptr);
  // mlp_hi = bf16(gelu(h2 @ fc1 + b1)) : 64x128 tile -> 2048 blocks (6/CU)
  gemm_tpl<64, 128, 1, 4, 1, 0><<<dim3(MLP_H_ / 128, rows / 64), 256, 0, stream>>>(
      abuf, f1_hi, nullptr, fc1_b, nullptr,
      nullptr, mlp_hi, nullptr, rows, D_, MLP_H_, 1, 0);
  // out = xres + mlp @ fc2 + b2 : 64x64 tile -> 1024 blocks
  gemm_tpl<64, 64, 2, 2, 1, 0><<<dim3(D_ / 64, rows / 64), 256, 0, stream>>>(
      mlp_hi, f2_hi, nullptr, fc2_b, xres,
      out, nullptr, nullptr, rows, MLP_H_, D_, 0, 0);
}